// Round 2
// baseline (8875.328 us; speedup 1.0000x reference)
//
#include <hip/hip_runtime.h>
#include <math.h>

#define TSAMP 32768
#define CCH 128
#define NBATCH 8
#define NEV 32
#define NROWS 256   // NBATCH*NEV
#define NATOMS 512
#define ASIZE 512
#define NTRANS 64
#define TSIZE 8192

// ------------------------------------------------------------------
// K0: zero the atomic accumulators (wet buffer + f64 stat sums).
// NOTE: runs AFTER the conv stack because wet/sums alias the conv ping-pong
// region. Stream ordering makes this safe.
__global__ __launch_bounds__(256) void k_zero(float* __restrict__ wet,
                                              double* __restrict__ sums) {
  int i = blockIdx.x * 256 + threadIdx.x;
  if (i < NBATCH * TSAMP) wet[i] = 0.f;
  if (i < 16) sums[i] = 0.0;
}

// ------------------------------------------------------------------
// K1: front filter bank for ONE batch. h[c,t] = sum_k x[t+k-256] * bank[c,k]
// block: (tchunk of 2048, cgroup of 16); 8 consecutive t per thread,
// rolling register window -> 8 FMA per LDS read.
__global__ __launch_bounds__(256) void k_front(const float* __restrict__ xb,
                                               const float* __restrict__ bank,
                                               float* __restrict__ h) {
  __shared__ float xs[2048 + 512];
  const int t0 = blockIdx.x * 2048;
  const int cg = blockIdx.y;
  for (int i = threadIdx.x; i < 2560; i += 256) {
    const int g = t0 - 256 + i;
    xs[i] = (g >= 0 && g < TSAMP) ? xb[g] : 0.f;
  }
  __syncthreads();
  const int tl = threadIdx.x * 8;
  for (int cc = 0; cc < 16; ++cc) {
    const int c = cg * 16 + cc;
    const float* __restrict__ bk = bank + (size_t)c * 512;
    float a0=0,a1=0,a2=0,a3=0,a4=0,a5=0,a6=0,a7=0;
    float w0=xs[tl+0],w1=xs[tl+1],w2=xs[tl+2],w3=xs[tl+3],
          w4=xs[tl+4],w5=xs[tl+5],w6=xs[tl+6],w7=xs[tl+7];
#pragma unroll 8
    for (int k = 0; k < 512; ++k) {
      const float bv = bk[k];
      a0 += bv*w0; a1 += bv*w1; a2 += bv*w2; a3 += bv*w3;
      a4 += bv*w4; a5 += bv*w5; a6 += bv*w6; a7 += bv*w7;
      w0=w1; w1=w2; w2=w3; w3=w4; w4=w5; w5=w6; w6=w7;
      w7 = xs[tl + k + 8];
    }
    float* hp = h + (size_t)c*TSAMP + t0 + tl;
    hp[0]=a0; hp[1]=a1; hp[2]=a2; hp[3]=a3;
    hp[4]=a4; hp[5]=a5; hp[6]=a6; hp[7]=a7;
  }
}

// ------------------------------------------------------------------
// K2: one residual dilated conv layer, ONE batch.
// hout[o,t] = hin[o,t] + lrelu( sum_{ci,k} hin[ci,t+(k-1)d]*w[o,ci,k] + bias[o] )
// block: 64-t tile x all 128 ci staged in LDS; wave-uniform scalar weights,
// 4-output register blocking (12 FMA per 3 LDS reads).
__global__ __launch_bounds__(256) void k_dilated(const float* __restrict__ hin,
                                                 const float* __restrict__ w,
                                                 const float* __restrict__ bias,
                                                 float* __restrict__ hout,
                                                 const int d) {
  extern __shared__ float hl[];            // [128][64+2d]
  const int twin = 64 + 2*d;
  const int t0 = blockIdx.x * 64;
  const int tc2 = threadIdx.x & 127;
  const int tr2 = threadIdx.x >> 7;
  for (int ci = tr2; ci < CCH; ci += 2) {
    if (tc2 < twin) {
      const int g = t0 - d + tc2;
      hl[ci*twin + tc2] =
          (g >= 0 && g < TSAMP) ? hin[(size_t)ci*TSAMP + g] : 0.f;
    }
  }
  __syncthreads();
  const int lane = threadIdx.x & 63;
  const int wv = __builtin_amdgcn_readfirstlane(threadIdx.x >> 6);
  const int t = t0 + lane;
  const float* hrow = hl + lane;
  for (int og = 0; og < 8; ++og) {
    const int o = wv*32 + og*4;
    const float* wp = w + (size_t)o * 384;   // [o][ci][k], 384 per o-row
    float a0=0,a1=0,a2=0,a3=0;
    for (int ci = 0; ci < CCH; ++ci) {
      const float x0 = hrow[ci*twin];
      const float x1 = hrow[ci*twin + d];
      const float x2 = hrow[ci*twin + 2*d];
      const float* q = wp + ci*3;
      a0 += x0*q[0]    + x1*q[1]    + x2*q[2];
      a1 += x0*q[384]  + x1*q[385]  + x2*q[386];
      a2 += x0*q[768]  + x1*q[769]  + x2*q[770];
      a3 += x0*q[1152] + x1*q[1153] + x2*q[1154];
    }
    const size_t rb = (size_t)o*TSAMP + t;
    float r;
    r = a0 + bias[o+0]; r = r>0.f ? r : 0.2f*r; hout[rb]                  = hin[rb] + r;
    r = a1 + bias[o+1]; r = r>0.f ? r : 0.2f*r; hout[rb + TSAMP]          = hin[rb + TSAMP] + r;
    r = a2 + bias[o+2]; r = r>0.f ? r : 0.2f*r; hout[rb + 2*(size_t)TSAMP] = hin[rb + 2*(size_t)TSAMP] + r;
    r = a3 + bias[o+3]; r = r>0.f ? r : 0.2f*r; hout[rb + 3*(size_t)TSAMP] = hin[rb + 3*(size_t)TSAMP] + r;
  }
}

// ------------------------------------------------------------------
// K3: per-batch sum / sumsq (f64 atomics)
__global__ __launch_bounds__(256) void k_stats(const float* __restrict__ h,
                                               double* __restrict__ sums) {
  const int b = blockIdx.y;
  const float* p = h + (size_t)b*CCH*TSAMP;
  double s = 0.0, s2 = 0.0;
  const size_t n = (size_t)CCH*TSAMP;
  for (size_t i = (size_t)blockIdx.x*256 + threadIdx.x; i < n; i += 64*256) {
    const double v = (double)p[i];
    s += v; s2 += v*v;
  }
  for (int d_ = 32; d_ > 0; d_ >>= 1) { s += __shfl_down(s, d_); s2 += __shfl_down(s2, d_); }
  if ((threadIdx.x & 63) == 0) {
    atomicAdd(&sums[b*2],   s);
    atomicAdd(&sums[b*2+1], s2);
  }
}

// K4: scale[b] = 1/(std_b + 1e-8)
__global__ void k_scale(const double* __restrict__ sums, float* __restrict__ scal) {
  const int b = threadIdx.x;
  if (b < NBATCH) {
    const double n = (double)CCH * (double)TSAMP;
    const double mean = sums[b*2] / n;
    double var = sums[b*2+1] / n - mean*mean;
    if (var < 0.0) var = 0.0;
    scal[b] = (float)(1.0 / (sqrt(var) + 1e-8));
  }
}

// K5: context[b,c] = scale_b * max_t h[b,c,t]
__global__ __launch_bounds__(256) void k_context(const float* __restrict__ h,
                                                 const float* __restrict__ scal,
                                                 float* __restrict__ ctx) {
  const int bc = blockIdx.x;            // b*128 + c
  const float* p = h + (size_t)bc*TSAMP;
  float m = -3.4e38f;
  for (int i = threadIdx.x; i < TSAMP; i += 256) m = fmaxf(m, p[i]);
  for (int d_ = 32; d_ > 0; d_ >>= 1) m = fmaxf(m, __shfl_down(m, d_));
  __shared__ float wm[4];
  if ((threadIdx.x & 63) == 0) wm[threadIdx.x >> 6] = m;
  __syncthreads();
  if (threadIdx.x == 0) {
    m = fmaxf(fmaxf(wm[0], wm[1]), fmaxf(wm[2], wm[3]));
    ctx[bc] = m * scal[bc >> 7];
  }
}

// K6: attn[b,t] = sigmoid(scale_b * sum_c h[b,c,t]*aw[c] + ab)
__global__ __launch_bounds__(256) void k_attn(const float* __restrict__ h,
                                              const float* __restrict__ scal,
                                              const float* __restrict__ aw,
                                              const float* __restrict__ ab,
                                              float* __restrict__ attn) {
  const int b = blockIdx.y;
  const int t = blockIdx.x*1024 + threadIdx.x*4;
  const float* p = h + (size_t)b*CCH*TSAMP + t;
  float a0=0,a1=0,a2=0,a3=0;
  for (int c = 0; c < CCH; ++c) {
    const float wc = aw[c];
    const float4 v = *(const float4*)(p + (size_t)c*TSAMP);
    a0 += wc*v.x; a1 += wc*v.y; a2 += wc*v.z; a3 += wc*v.w;
  }
  const float s = scal[b], bb = ab[0];
  float* o = attn + (size_t)b*TSAMP + t;
  o[0] = 1.f/(1.f+expf(-(a0*s+bb)));
  o[1] = 1.f/(1.f+expf(-(a1*s+bb)));
  o[2] = 1.f/(1.f+expf(-(a2*s+bb)));
  o[3] = 1.f/(1.f+expf(-(a3*s+bb)));
}

// K7: top-32 per batch. Iterative argmax over lexicographic key (v, -i):
// no masking buffer needed; ties break to lowest index (matches lax.top_k set).
__global__ __launch_bounds__(256) void k_topk(const float* __restrict__ attn,
                                              float* __restrict__ vals,
                                              int* __restrict__ idxs) {
  const int b = blockIdx.x;
  const float* a = attn + (size_t)b*TSAMP;
  __shared__ float rv[256];
  __shared__ int   ri[256];
  __shared__ float lastv;
  __shared__ int   lasti;
  if (threadIdx.x == 0) { lastv = 1e30f; lasti = -1; }
  __syncthreads();
  for (int e = 0; e < NEV; ++e) {
    const float lv = lastv; const int li = lasti;
    float bv = -1e30f; int bi = 1 << 30;
    for (int i = threadIdx.x; i < TSAMP; i += 256) {
      const float v = a[i];
      const bool ok = (v < lv) || (v == lv && i > li);
      if (ok && (v > bv || (v == bv && i < bi))) { bv = v; bi = i; }
    }
    rv[threadIdx.x] = bv; ri[threadIdx.x] = bi;
    __syncthreads();
    for (int s = 128; s > 0; s >>= 1) {
      if (threadIdx.x < s) {
        const float ov = rv[threadIdx.x + s]; const int oi = ri[threadIdx.x + s];
        if (ov > rv[threadIdx.x] || (ov == rv[threadIdx.x] && oi < ri[threadIdx.x])) {
          rv[threadIdx.x] = ov; ri[threadIdx.x] = oi;
        }
      }
      __syncthreads();
    }
    if (threadIdx.x == 0) {
      vals[b*NEV + e] = rv[0]; idxs[b*NEV + e] = ri[0];
      lastv = rv[0]; lasti = ri[0];
    }
    __syncthreads();
  }
}

// ------------------------------------------------------------------
// block reductions for 128-thread blocks
__device__ __forceinline__ float blk_max128(float v, float* red) {
  const int tid = threadIdx.x;
  red[tid] = v; __syncthreads();
  for (int s = 64; s > 0; s >>= 1) {
    if (tid < s) red[tid] = fmaxf(red[tid], red[tid + s]);
    __syncthreads();
  }
  const float r = red[0]; __syncthreads();
  return r;
}
__device__ __forceinline__ float blk_sum128(float v, float* red) {
  const int tid = threadIdx.x;
  red[tid] = v; __syncthreads();
  for (int s = 64; s > 0; s >>= 1) {
    if (tid < s) red[tid] += red[tid + s];
    __syncthreads();
  }
  const float r = red[0]; __syncthreads();
  return r;
}
__device__ __forceinline__ float mlp_hidden3(float latv, const float* __restrict__ hw,
                                             const float* __restrict__ hb, float* xa) {
  const int tid = threadIdx.x;
  float cur = latv;
  for (int i = 0; i < 3; ++i) {
    xa[tid] = cur; __syncthreads();
    const float* W = hw + (size_t)i*CCH*CCH;
    float acc = hb[i*CCH + tid];
    for (int c = 0; c < CCH; ++c) acc += xa[c] * W[c*CCH + tid];
    cur = acc > 0.f ? acc : 0.2f*acc;
    __syncthreads();
  }
  return cur;
}

// K8: lat + all three MLPs + softmaxes + amps. One 128-thread block per event row.
__global__ __launch_bounds__(128) void k_mlp(
    const float* __restrict__ h, const float* __restrict__ scal,
    const float* __restrict__ vals, const int* __restrict__ idxs,
    const float* __restrict__ a_hw, const float* __restrict__ a_hb,
    const float* __restrict__ a_ow, const float* __restrict__ a_ob,
    const float* __restrict__ t_hw, const float* __restrict__ t_hb,
    const float* __restrict__ t_ow, const float* __restrict__ t_ob,
    const float* __restrict__ m_hw, const float* __restrict__ m_hb,
    const float* __restrict__ m_ow, const float* __restrict__ m_ob,
    float* __restrict__ p_atoms, float* __restrict__ p_trans, float* __restrict__ amps) {
  const int row = blockIdx.x;
  const int b = row >> 5;
  const int tid = threadIdx.x;
  __shared__ float xa[CCH];
  __shared__ float red[CCH];
  const int t = idxs[row];
  const float latv = h[((size_t)(b*CCH + tid))*TSAMP + t] * scal[b] * vals[row];

  // ---- atoms branch
  {
    const float cur = mlp_hidden3(latv, a_hw, a_hb, xa);
    xa[tid] = cur; __syncthreads();
    float l0 = a_ob[tid], l1 = a_ob[tid+128], l2 = a_ob[tid+256], l3 = a_ob[tid+384];
    for (int c = 0; c < CCH; ++c) {
      const float xv = xa[c];
      const float* W = a_ow + (size_t)c*NATOMS + tid;
      l0 += xv*W[0]; l1 += xv*W[128]; l2 += xv*W[256]; l3 += xv*W[384];
    }
    const float mx = blk_max128(fmaxf(fmaxf(l0,l1), fmaxf(l2,l3)), red);
    const float e0 = expf(l0-mx), e1 = expf(l1-mx), e2 = expf(l2-mx), e3 = expf(l3-mx);
    const float inv = 1.f / blk_sum128(e0+e1+e2+e3, red);
    float* pa = p_atoms + (size_t)row*NATOMS;
    pa[tid] = e0*inv; pa[tid+128] = e1*inv; pa[tid+256] = e2*inv; pa[tid+384] = e3*inv;
  }

  // ---- transfers branch
  {
    const float cur = mlp_hidden3(latv, t_hw, t_hb, xa);
    xa[tid] = cur; __syncthreads();
    float lg = -3.4e38f;
    if (tid < NTRANS) {
      float acc = t_ob[tid];
      for (int c = 0; c < CCH; ++c) acc += xa[c]*t_ow[c*NTRANS + tid];
      lg = acc;
    }
    const float mt = blk_max128(lg, red);
    const float et = (tid < NTRANS) ? expf(lg - mt) : 0.f;
    const float st = blk_sum128(et, red);
    if (tid < NTRANS) p_trans[(size_t)row*NTRANS + tid] = et/st;
  }

  // ---- amp branch
  {
    const float cur = mlp_hidden3(latv, m_hw, m_hb, xa);
    const float s = blk_sum128(cur * m_ow[tid], red);
    if (tid == 0) { const float v = s + m_ob[0]; amps[row] = v*v; }
  }
}

// K9: atoms_vec[row,:] = p_atoms[row] @ atoms_dict (512x512)
__global__ __launch_bounds__(256) void k_atoms_mm(const float* __restrict__ p_atoms,
                                                  const float* __restrict__ dict,
                                                  float* __restrict__ av) {
  const int row = blockIdx.x;
  __shared__ float p[NATOMS];
  for (int i = threadIdx.x; i < NATOMS; i += 256) p[i] = p_atoms[(size_t)row*NATOMS + i];
  __syncthreads();
  const int s0 = threadIdx.x*2;
  float a0=0, a1=0;
  for (int a = 0; a < NATOMS; ++a) {
    const float pa = p[a];
    const float2 dv = *(const float2*)(dict + (size_t)a*ASIZE + s0);
    a0 += pa*dv.x; a1 += pa*dv.y;
  }
  av[(size_t)row*ASIZE + s0] = a0; av[(size_t)row*ASIZE + s0 + 1] = a1;
}

// K10: transfers[row,:] = p_trans[row] @ transfer_dict (64x8192)
__global__ __launch_bounds__(256) void k_trans_mm(const float* __restrict__ p_trans,
                                                   const float* __restrict__ td,
                                                   float* __restrict__ trans) {
  const int row = blockIdx.y;
  const int t = blockIdx.x*2048 + threadIdx.x*8;
  __shared__ float p[NTRANS];
  if (threadIdx.x < NTRANS) p[threadIdx.x] = p_trans[(size_t)row*NTRANS + threadIdx.x];
  __syncthreads();
  float a0=0,a1=0,a2=0,a3=0,a4=0,a5=0,a6=0,a7=0;
  for (int j = 0; j < NTRANS; ++j) {
    const float pj = p[j];
    const float4 v0 = *(const float4*)(td + (size_t)j*TSIZE + t);
    const float4 v1 = *(const float4*)(td + (size_t)j*TSIZE + t + 4);
    a0 += pj*v0.x; a1 += pj*v0.y; a2 += pj*v0.z; a3 += pj*v0.w;
    a4 += pj*v1.x; a5 += pj*v1.y; a6 += pj*v1.z; a7 += pj*v1.w;
  }
  float* o = trans + (size_t)row*TSIZE + t;
  o[0]=a0; o[1]=a1; o[2]=a2; o[3]=a3; o[4]=a4; o[5]=a5; o[6]=a6; o[7]=a7;
}

// K11: ev[row,n] = (sum_{k<512} atoms[row,k]*transfers[row,n-k] + atoms_pad[row,n]) * amp[row]
__global__ __launch_bounds__(256) void k_ev(const float* __restrict__ trans,
                                            const float* __restrict__ av,
                                            const float* __restrict__ amps,
                                            float* __restrict__ ev) {
  const int row = blockIdx.y;
  const int t0 = blockIdx.x * 1024;
  __shared__ float al[512];
  __shared__ float tw[1536];
  for (int i = threadIdx.x; i < 512; i += 256) al[i] = av[(size_t)row*ASIZE + i];
  for (int i = threadIdx.x; i < 1536; i += 256) {
    const int g = t0 - 512 + i;
    tw[i] = (g >= 0) ? trans[(size_t)row*TSIZE + g] : 0.f;
  }
  __syncthreads();
  const int base = threadIdx.x*4 + 512;
  float a0=0,a1=0,a2=0,a3=0;
  float w0=tw[base], w1=tw[base+1], w2=tw[base+2], w3=tw[base+3];
#pragma unroll 8
  for (int k = 0; k < 512; ++k) {
    const float ak = al[k];
    a0 += ak*w0; a1 += ak*w1; a2 += ak*w2; a3 += ak*w3;
    w3 = w2; w2 = w1; w1 = w0; w0 = tw[base - k - 1];
  }
  const int n = t0 + threadIdx.x*4;
  const float amp = amps[row];
  float* e = ev + (size_t)row*TSIZE + n;
  e[0] = (a0 + (n+0 < 512 ? al[n+0] : 0.f)) * amp;
  e[1] = (a1 + (n+1 < 512 ? al[n+1] : 0.f)) * amp;
  e[2] = (a2 + (n+2 < 512 ? al[n+2] : 0.f)) * amp;
  e[3] = (a3 + (n+3 < 512 ? al[n+3] : 0.f)) * amp;
}

// K12: overlap-add gather (deterministic). dry[p] = sum over rows of ev[r, p - idx_r]
__global__ __launch_bounds__(256) void k_dry(const float* __restrict__ ev,
                                             const int* __restrict__ idxs,
                                             float* __restrict__ dry) {
  __shared__ int sidx[NROWS];
  for (int i = threadIdx.x; i < NROWS; i += 256) sidx[i] = idxs[i];
  __syncthreads();
  const int p = blockIdx.x*1024 + threadIdx.x*4;
  float a0=0,a1=0,a2=0,a3=0;
  for (int r = 0; r < NROWS; ++r) {
    const int off = p - sidx[r];
    if (off >= -3 && off < TSIZE) {
      const float* er = ev + (size_t)r*TSIZE;
      if ((unsigned)(off  ) < TSIZE) a0 += er[off];
      if ((unsigned)(off+1) < TSIZE) a1 += er[off+1];
      if ((unsigned)(off+2) < TSIZE) a2 += er[off+2];
      if ((unsigned)(off+3) < TSIZE) a3 += er[off+3];
    }
  }
  dry[p] = a0; dry[p+1] = a1; dry[p+2] = a2; dry[p+3] = a3;
}

// K13: room softmax + wet/dry mix scalars. one block of 64 threads (lane = b*8+r)
__global__ void k_room(const float* __restrict__ ctx, const float* __restrict__ room_w,
                       const float* __restrict__ room_b, const float* __restrict__ mix_w,
                       const float* __restrict__ mix_b, float* __restrict__ roomp,
                       float* __restrict__ mix) {
  const int b = threadIdx.x >> 3;
  const int r = threadIdx.x & 7;
  float acc = room_b[r];
  for (int c = 0; c < CCH; ++c) acc += ctx[b*CCH + c] * room_w[c*8 + r];
  float m = acc;
  for (int s = 1; s < 8; s <<= 1) m = fmaxf(m, __shfl_xor(m, s, 8));
  const float e = expf(acc - m);
  float ssum = e;
  for (int s = 1; s < 8; s <<= 1) ssum += __shfl_xor(ssum, s, 8);
  roomp[b*8 + r] = e / ssum;
  if (r == 0) {
    float a = mix_b[0];
    for (int c = 0; c < CCH; ++c) a += ctx[b*CCH + c] * mix_w[c];
    mix[b] = 1.f/(1.f+expf(-a));
  }
}

// K14: impulse[b,t] = sum_r roomp[b,r]*rooms[r,t]
__global__ __launch_bounds__(256) void k_impulse(const float* __restrict__ roomp,
                                                 const float* __restrict__ rooms,
                                                 float* __restrict__ impulse) {
  const int b = blockIdx.y;
  const int t = blockIdx.x*1024 + threadIdx.x*4;
  float a0=0,a1=0,a2=0,a3=0;
  for (int r = 0; r < 8; ++r) {
    const float pr = roomp[b*8 + r];
    const float4 v = *(const float4*)(rooms + (size_t)r*TSAMP + t);
    a0 += pr*v.x; a1 += pr*v.y; a2 += pr*v.z; a3 += pr*v.w;
  }
  float* o = impulse + (size_t)b*TSAMP + t;
  o[0]=a0; o[1]=a1; o[2]=a2; o[3]=a3;
}

// K15: triangular reverb conv: wet[b,n] = sum_{k<=n} dry[k]*impulse[b,n-k]
// grid (32 t-chunks, 8 k-slabs, 8 b); partial sums atomically accumulated.
__global__ __launch_bounds__(256) void k_wet(const float* __restrict__ dry,
                                             const float* __restrict__ impulse,
                                             float* __restrict__ wet) {
  const int t0 = blockIdx.x * 1024;
  const int kbeg = blockIdx.y * 4096;
  const int b = blockIdx.z;
  if (kbeg > t0 + 1023) return;
  __shared__ float dl[1024];
  __shared__ float il[2048];
  const float* imp = impulse + (size_t)b*TSAMP;
  const int tl = threadIdx.x * 4;
  float a0=0,a1=0,a2=0,a3=0;
  for (int kc = kbeg; kc < kbeg + 4096 && kc <= t0 + 1023; kc += 1024) {
    for (int i = threadIdx.x; i < 1024; i += 256) dl[i] = dry[kc + i];
    const int w0g = t0 - kc - 1024;
    for (int i = threadIdx.x; i < 2048; i += 256) {
      const int g = w0g + i;
      il[i] = (g >= 0) ? imp[g] : 0.f;   // g < TSAMP always holds here
    }
    __syncthreads();
    const int base = tl + 1024;
    float w0=il[base], w1=il[base+1], w2=il[base+2], w3=il[base+3];
#pragma unroll 8
    for (int k = 0; k < 1024; ++k) {
      const float dv = dl[k];
      a0 += dv*w0; a1 += dv*w1; a2 += dv*w2; a3 += dv*w3;
      w3 = w2; w2 = w1; w1 = w0; w0 = il[base - k - 1];
    }
    __syncthreads();
  }
  float* wp = wet + (size_t)b*TSAMP + t0 + tl;
  atomicAdd(wp+0, a0); atomicAdd(wp+1, a1);
  atomicAdd(wp+2, a2); atomicAdd(wp+3, a3);
}

// K16: out = dry*(1-mix) + wet*mix
__global__ __launch_bounds__(256) void k_out(const float* __restrict__ dry,
                                             const float* __restrict__ wet,
                                             const float* __restrict__ mix,
                                             float* __restrict__ out) {
  const int b = blockIdx.y;
  const int t = blockIdx.x*1024 + threadIdx.x*4;
  const float m = mix[b];
  const float4 d = *(const float4*)(dry + t);
  const float4 w = *(const float4*)(wet + (size_t)b*TSAMP + t);
  float* o = out + (size_t)b*TSAMP + t;
  o[0] = d.x*(1.f-m) + w.x*m;
  o[1] = d.y*(1.f-m) + w.y*m;
  o[2] = d.z*(1.f-m) + w.z*m;
  o[3] = d.w*(1.f-m) + w.w*m;
}

// ------------------------------------------------------------------
extern "C" void kernel_launch(void* const* d_in, const int* in_sizes, int n_in,
                              void* d_out, int out_size, void* d_ws, size_t ws_size,
                              hipStream_t stream) {
  (void)in_sizes; (void)n_in; (void)out_size; (void)ws_size;
  const float* x      = (const float*)d_in[0];
  const float* bank   = (const float*)d_in[1];
  const float* w_net  = (const float*)d_in[2];
  const float* b_net  = (const float*)d_in[3];
  const float* attn_w = (const float*)d_in[4];
  const float* attn_b = (const float*)d_in[5];
  const float* a_hw = (const float*)d_in[6];
  const float* a_hb = (const float*)d_in[7];
  const float* a_ow = (const float*)d_in[8];
  const float* a_ob = (const float*)d_in[9];
  const float* t_hw = (const float*)d_in[10];
  const float* t_hb = (const float*)d_in[11];
  const float* t_ow = (const float*)d_in[12];
  const float* t_ob = (const float*)d_in[13];
  const float* m_hw = (const float*)d_in[14];
  const float* m_hb = (const float*)d_in[15];
  const float* m_ow = (const float*)d_in[16];
  const float* m_ob = (const float*)d_in[17];
  const float* atoms_dict    = (const float*)d_in[18];
  const float* transfer_dict = (const float*)d_in[19];
  const float* rooms  = (const float*)d_in[20];
  const float* room_w = (const float*)d_in[21];
  const float* room_b = (const float*)d_in[22];
  const float* mix_w  = (const float*)d_in[23];
  const float* mix_b  = (const float*)d_in[24];
  float* out = (float*)d_out;

  // ---- workspace layout (160 MB total):
  //  H  @ 0        : 33,554,432 floats (final conv-stack activations, [B,C,T])
  //  t1 @ 33.55M   :  4,194,304 floats (per-batch ping)
  //  t2 @ 37.75M   :  4,194,304 floats (per-batch pong)
  //  post-conv scratch aliases t1/t2 (dead after conv stack; stream-ordered).
  float* ws = (float*)d_ws;
  float* H  = ws;
  float* t1 = ws + (size_t)33554432;
  float* t2 = ws + (size_t)37748736;

  size_t off = 33554432;                            // scratch base (aliases t1)
  double* sums = (double*)(ws + off); off += 32;    // 16 doubles (8B-aligned)
  float* attn  = ws + off; off += (size_t)NBATCH*TSAMP;
  float* scal  = ws + off; off += 8;
  float* ctx   = ws + off; off += NBATCH*CCH;
  float* vals  = ws + off; off += NROWS;
  int*   idxs  = (int*)(ws + off); off += NROWS;
  float* p_atoms = ws + off; off += (size_t)NROWS*NATOMS;
  float* p_trans = ws + off; off += (size_t)NROWS*NTRANS;
  float* amps  = ws + off; off += NROWS;
  float* av    = ws + off; off += (size_t)NROWS*ASIZE;
  float* trans = ws + off; off += (size_t)NROWS*TSIZE;
  float* ev    = ws + off; off += (size_t)NROWS*TSIZE;
  float* dry   = ws + off; off += TSAMP;
  float* roomp = ws + off; off += 64;
  float* mix   = ws + off; off += 8;
  float* impulse = ws + off; off += (size_t)NBATCH*TSAMP;
  float* wet   = ws + off; off += (size_t)NBATCH*TSAMP;
  // off ≈ 38.85M floats ≈ 155 MB — all scratch fits inside t1+t2 region.

  const int dil[5] = {1, 3, 9, 27, 1};
  for (int b = 0; b < NBATCH; ++b) {
    float* Hb = H + (size_t)b*CCH*TSAMP;
    // front: x[b] -> t1
    k_front<<<dim3(16, 8), 256, 0, stream>>>(x + (size_t)b*TSAMP, bank, t1);
    // 5 residual dilated layers: t1->t2->t1->t2->t1->Hb
    float* io[6] = {t1, t2, t1, t2, t1, Hb};
    for (int i = 0; i < 5; ++i) {
      const int d = dil[i];
      const size_t smem = (size_t)CCH * (64 + 2*d) * sizeof(float);
      k_dilated<<<512, 256, smem, stream>>>(
          io[i], w_net + (size_t)i*CCH*CCH*3, b_net + i*CCH, io[i+1], d);
    }
  }

  // scratch region (aliasing t1/t2) is free from here on.
  k_zero<<<1024, 256, 0, stream>>>(wet, sums);
  k_stats<<<dim3(64, 8), 256, 0, stream>>>(H, sums);
  k_scale<<<1, 64, 0, stream>>>(sums, scal);
  k_context<<<1024, 256, 0, stream>>>(H, scal, ctx);
  k_attn<<<dim3(32, 8), 256, 0, stream>>>(H, scal, attn_w, attn_b, attn);
  k_topk<<<8, 256, 0, stream>>>(attn, vals, idxs);
  k_mlp<<<256, 128, 0, stream>>>(H, scal, vals, idxs,
                                 a_hw, a_hb, a_ow, a_ob,
                                 t_hw, t_hb, t_ow, t_ob,
                                 m_hw, m_hb, m_ow, m_ob,
                                 p_atoms, p_trans, amps);
  k_atoms_mm<<<256, 256, 0, stream>>>(p_atoms, atoms_dict, av);
  k_trans_mm<<<dim3(4, 256), 256, 0, stream>>>(p_trans, transfer_dict, trans);
  k_ev<<<dim3(8, 256), 256, 0, stream>>>(trans, av, amps, ev);
  k_dry<<<32, 256, 0, stream>>>(ev, idxs, dry);
  k_room<<<1, 64, 0, stream>>>(ctx, room_w, room_b, mix_w, mix_b, roomp, mix);
  k_impulse<<<dim3(32, 8), 256, 0, stream>>>(roomp, rooms, impulse);
  k_wet<<<dim3(32, 8, 8), 256, 0, stream>>>(dry, impulse, wet);
  k_out<<<dim3(32, 8), 256, 0, stream>>>(dry, wet, mix, out);
}

// Round 3
// 3343.862 us; speedup vs baseline: 2.6542x; 2.6542x over previous
//
#include <hip/hip_runtime.h>
#include <math.h>

#define TSAMP 32768
#define CCH 128
#define NBATCH 8
#define NEV 32
#define NROWS 256   // NBATCH*NEV
#define NATOMS 512
#define ASIZE 512
#define NTRANS 64
#define TSIZE 8192

typedef _Float16 f16x8 __attribute__((ext_vector_type(8)));
typedef float f32x4 __attribute__((ext_vector_type(4)));

// ------------------------------------------------------------------
// K0: zero the atomic accumulators (wet buffer + f64 stat sums).
// Runs AFTER the conv stack (wet/sums alias the conv ping-pong region).
__global__ __launch_bounds__(256) void k_zero(float* __restrict__ wet,
                                              double* __restrict__ sums) {
  int i = blockIdx.x * 256 + threadIdx.x;
  if (i < NBATCH * TSAMP) wet[i] = 0.f;
  if (i < 16) sums[i] = 0.0;
}

// ------------------------------------------------------------------
// Kw: split conv weights into f16 hi/lo in layout [layer][k][o][ci]
__global__ __launch_bounds__(256) void k_wsplit(const float* __restrict__ wn,
                                                _Float16* __restrict__ whi,
                                                _Float16* __restrict__ wlo) {
  const int i = blockIdx.x * 256 + threadIdx.x;   // 5*3*128*128 = 245760
  if (i >= 245760) return;
  const int ci = i & 127;
  int r = i >> 7;
  const int o = r & 127;
  r >>= 7;
  const int k = r % 3;
  const int l = r / 3;
  const float w = wn[(((size_t)l*128 + o)*128 + ci)*3 + k];
  const _Float16 hi = (_Float16)w;
  whi[i] = hi;
  wlo[i] = (_Float16)(w - (float)hi);
}

// ------------------------------------------------------------------
// K1: front filter bank, ALL batches. h[b,c,t] = sum_k x[b,t+k-256]*bank[c,k]
__global__ __launch_bounds__(256) void k_front(const float* __restrict__ x,
                                               const float* __restrict__ bank,
                                               float* __restrict__ h) {
  __shared__ float xs[2048 + 512];
  const int t0 = blockIdx.x * 2048;
  const int cg = blockIdx.y;
  const int b  = blockIdx.z;
  const float* xb = x + (size_t)b * TSAMP;
  for (int i = threadIdx.x; i < 2560; i += 256) {
    const int g = t0 - 256 + i;
    xs[i] = (g >= 0 && g < TSAMP) ? xb[g] : 0.f;
  }
  __syncthreads();
  const int tl = threadIdx.x * 8;
  for (int cc = 0; cc < 16; ++cc) {
    const int c = cg * 16 + cc;
    const float* __restrict__ bk = bank + (size_t)c * 512;
    float a0=0,a1=0,a2=0,a3=0,a4=0,a5=0,a6=0,a7=0;
    float w0=xs[tl+0],w1=xs[tl+1],w2=xs[tl+2],w3=xs[tl+3],
          w4=xs[tl+4],w5=xs[tl+5],w6=xs[tl+6],w7=xs[tl+7];
#pragma unroll 8
    for (int k = 0; k < 512; ++k) {
      const float bv = bk[k];
      a0 += bv*w0; a1 += bv*w1; a2 += bv*w2; a3 += bv*w3;
      a4 += bv*w4; a5 += bv*w5; a6 += bv*w6; a7 += bv*w7;
      w0=w1; w1=w2; w2=w3; w3=w4; w4=w5; w5=w6; w6=w7;
      w7 = xs[tl + k + 8];
    }
    float* hp = h + ((size_t)b*CCH + c)*TSAMP + t0 + tl;
    hp[0]=a0; hp[1]=a1; hp[2]=a2; hp[3]=a3;
    hp[4]=a4; hp[5]=a5; hp[6]=a6; hp[7]=a7;
  }
}

// ------------------------------------------------------------------
// K2: one residual dilated conv layer, ONE batch — split-f16 MFMA GEMM.
// hout[o,t] = hin[o,t] + lrelu( sum_{ci,k} hin[ci,t+(k-1)d]*w[o,ci,k] + b[o] )
// Block: 128o x 64t. 4 waves, each 32o x 64t = 8 mfma_16x16x32 tiles.
// X staged transposed in LDS [tw][ci] f16 (hi,lo), rows padded to 136 f16
// (272 B -> b128 reads land 2-way/bank = free). Weights pre-split [k][o][ci].
// 3 passes per K-chunk: Ahi*Bhi + Alo*Bhi + Ahi*Blo (~22-bit mantissa).
__global__ __launch_bounds__(256) void k_dil_mfma(
    const float* __restrict__ hin, const _Float16* __restrict__ whi,
    const _Float16* __restrict__ wlo, const float* __restrict__ bias,
    float* __restrict__ hout, const int d) {
  extern __shared__ _Float16 sh[];          // xhi[twin][136] then xlo[twin][136]
  const int twin = 64 + 2*d;
  _Float16* shi = sh;
  _Float16* slo = sh + twin*136;
  const int t0 = blockIdx.x * 64;
  const int tid = threadIdx.x;

  // stage: lanes ci-major (coalesced-in-ci LDS writes, byte-merged; global
  // reads scattered 4B but each 64B line reused 16x across iterations via L1)
  for (int flat = tid; flat < 128*twin; flat += 256) {
    const int ci = flat & 127;
    const int tw = flat >> 7;
    const int g = t0 - d + tw;
    const float v = (g >= 0 && g < TSAMP) ? hin[(size_t)ci*TSAMP + g] : 0.f;
    const _Float16 hi = (_Float16)v;
    shi[tw*136 + ci] = hi;
    slo[tw*136 + ci] = (_Float16)(v - (float)hi);
  }
  __syncthreads();

  const int wv = tid >> 6;
  const int lane = tid & 63;
  const int n = lane & 15;        // t within 16-tile (also A's m=o index)
  const int quad = lane >> 4;     // K-subchunk selector / D row group
  const int o0 = wv * 32;

  f32x4 acc[2][4];
#pragma unroll
  for (int i = 0; i < 2; ++i)
#pragma unroll
    for (int j = 0; j < 4; ++j) acc[i][j] = (f32x4){0.f,0.f,0.f,0.f};

  for (int k = 0; k < 3; ++k) {
    for (int kc = 0; kc < 4; ++kc) {
      const int cib = kc*32 + quad*8;
      f16x8 ahi[2], alo[2];
#pragma unroll
      for (int os = 0; os < 2; ++os) {
        const size_t wo = ((size_t)k*128 + (o0 + os*16 + n))*128 + cib;
        ahi[os] = *(const f16x8*)(whi + wo);
        alo[os] = *(const f16x8*)(wlo + wo);
      }
      f16x8 bhi[4], blo[4];
#pragma unroll
      for (int ts = 0; ts < 4; ++ts) {
        const int a = (ts*16 + n + k*d)*136 + cib;
        bhi[ts] = *(const f16x8*)(shi + a);
        blo[ts] = *(const f16x8*)(slo + a);
      }
#pragma unroll
      for (int os = 0; os < 2; ++os)
#pragma unroll
        for (int ts = 0; ts < 4; ++ts) {
          acc[os][ts] = __builtin_amdgcn_mfma_f32_16x16x32_f16(ahi[os], bhi[ts], acc[os][ts], 0, 0, 0);
          acc[os][ts] = __builtin_amdgcn_mfma_f32_16x16x32_f16(alo[os], bhi[ts], acc[os][ts], 0, 0, 0);
          acc[os][ts] = __builtin_amdgcn_mfma_f32_16x16x32_f16(ahi[os], blo[ts], acc[os][ts], 0, 0, 0);
        }
    }
  }

  // epilogue: D layout col=lane&15 (t), row=quad*4+reg (o)
#pragma unroll
  for (int os = 0; os < 2; ++os) {
    const int ob = o0 + os*16 + quad*4;
#pragma unroll
    for (int ts = 0; ts < 4; ++ts) {
      const int t = t0 + ts*16 + n;
#pragma unroll
      for (int r = 0; r < 4; ++r) {
        const int o = ob + r;
        float v = acc[os][ts][r] + bias[o];
        v = v > 0.f ? v : 0.2f*v;
        const size_t gi = (size_t)o*TSAMP + t;
        hout[gi] = hin[gi] + v;
      }
    }
  }
}

// ------------------------------------------------------------------
// K3: per-batch sum / sumsq (f64 atomics)
__global__ __launch_bounds__(256) void k_stats(const float* __restrict__ h,
                                               double* __restrict__ sums) {
  const int b = blockIdx.y;
  const float* p = h + (size_t)b*CCH*TSAMP;
  double s = 0.0, s2 = 0.0;
  const size_t n = (size_t)CCH*TSAMP;
  for (size_t i = (size_t)blockIdx.x*256 + threadIdx.x; i < n; i += 64*256) {
    const double v = (double)p[i];
    s += v; s2 += v*v;
  }
  for (int d_ = 32; d_ > 0; d_ >>= 1) { s += __shfl_down(s, d_); s2 += __shfl_down(s2, d_); }
  if ((threadIdx.x & 63) == 0) {
    atomicAdd(&sums[b*2],   s);
    atomicAdd(&sums[b*2+1], s2);
  }
}

// K4: scale[b] = 1/(std_b + 1e-8)
__global__ void k_scale(const double* __restrict__ sums, float* __restrict__ scal) {
  const int b = threadIdx.x;
  if (b < NBATCH) {
    const double n = (double)CCH * (double)TSAMP;
    const double mean = sums[b*2] / n;
    double var = sums[b*2+1] / n - mean*mean;
    if (var < 0.0) var = 0.0;
    scal[b] = (float)(1.0 / (sqrt(var) + 1e-8));
  }
}

// K5: context[b,c] = scale_b * max_t h[b,c,t]
__global__ __launch_bounds__(256) void k_context(const float* __restrict__ h,
                                                 const float* __restrict__ scal,
                                                 float* __restrict__ ctx) {
  const int bc = blockIdx.x;
  const float* p = h + (size_t)bc*TSAMP;
  float m = -3.4e38f;
  for (int i = threadIdx.x; i < TSAMP; i += 256) m = fmaxf(m, p[i]);
  for (int d_ = 32; d_ > 0; d_ >>= 1) m = fmaxf(m, __shfl_down(m, d_));
  __shared__ float wm[4];
  if ((threadIdx.x & 63) == 0) wm[threadIdx.x >> 6] = m;
  __syncthreads();
  if (threadIdx.x == 0) {
    m = fmaxf(fmaxf(wm[0], wm[1]), fmaxf(wm[2], wm[3]));
    ctx[bc] = m * scal[bc >> 7];
  }
}

// K6: attn[b,t] = sigmoid(scale_b * sum_c h[b,c,t]*aw[c] + ab)
__global__ __launch_bounds__(256) void k_attn(const float* __restrict__ h,
                                              const float* __restrict__ scal,
                                              const float* __restrict__ aw,
                                              const float* __restrict__ ab,
                                              float* __restrict__ attn) {
  const int b = blockIdx.y;
  const int t = blockIdx.x*1024 + threadIdx.x*4;
  const float* p = h + (size_t)b*CCH*TSAMP + t;
  float a0=0,a1=0,a2=0,a3=0;
  for (int c = 0; c < CCH; ++c) {
    const float wc = aw[c];
    const float4 v = *(const float4*)(p + (size_t)c*TSAMP);
    a0 += wc*v.x; a1 += wc*v.y; a2 += wc*v.z; a3 += wc*v.w;
  }
  const float s = scal[b], bb = ab[0];
  float* o = attn + (size_t)b*TSAMP + t;
  o[0] = 1.f/(1.f+expf(-(a0*s+bb)));
  o[1] = 1.f/(1.f+expf(-(a1*s+bb)));
  o[2] = 1.f/(1.f+expf(-(a2*s+bb)));
  o[3] = 1.f/(1.f+expf(-(a3*s+bb)));
}

// ------------------------------------------------------------------
// K7a: per-4096-chunk top-32 (LDS-resident, masking argmax).
// Any global top-32 element is in its chunk's top-32 => union is sufficient.
__global__ __launch_bounds__(256) void k_topk1(const float* __restrict__ attn,
                                               float* __restrict__ cv,
                                               int* __restrict__ cidx) {
  const int ch = blockIdx.x, b = blockIdx.y;
  const float* a = attn + (size_t)b*TSAMP + ch*4096;
  __shared__ float v[4096];
  __shared__ float rv[4]; __shared__ int ri[4];
  const int tid = threadIdx.x;
  for (int i = tid; i < 4096; i += 256) v[i] = a[i];
  __syncthreads();
  for (int e = 0; e < NEV; ++e) {
    float bv = -1e30f; int bi = 0;
    for (int i = tid; i < 4096; i += 256) {
      const float x = v[i];
      if (x > bv) { bv = x; bi = i; }        // ascending i: ties -> lowest i
    }
    for (int s = 32; s; s >>= 1) {
      const float ov = __shfl_down(bv, s); const int oi = __shfl_down(bi, s);
      if (ov > bv || (ov == bv && oi < bi)) { bv = ov; bi = oi; }
    }
    if ((tid & 63) == 0) { rv[tid >> 6] = bv; ri[tid >> 6] = bi; }
    __syncthreads();
    if (tid == 0) {
      int bb = 0;
      for (int w2 = 1; w2 < 4; ++w2)
        if (rv[w2] > rv[bb] || (rv[w2] == rv[bb] && ri[w2] < ri[bb])) bb = w2;
      cv[(b*8 + ch)*NEV + e] = rv[bb];
      cidx[(b*8 + ch)*NEV + e] = ch*4096 + ri[bb];
      v[ri[bb]] = -1e30f;                    // mask the chosen position
    }
    __syncthreads();
  }
}

// K7b: final top-32 over 256 candidates (lex tie: value desc, idx asc)
__global__ __launch_bounds__(256) void k_topk2(const float* __restrict__ cv,
                                               const int* __restrict__ ci_,
                                               float* __restrict__ vals,
                                               int* __restrict__ idxs) {
  const int b = blockIdx.x;
  const int tid = threadIdx.x;
  float my = cv[b*256 + tid];
  int   mi = ci_[b*256 + tid];
  __shared__ float rv[4]; __shared__ int ri[4];
  __shared__ float bvs; __shared__ int bis;
  for (int e = 0; e < NEV; ++e) {
    float bv = my; int bi = mi;
    for (int s = 32; s; s >>= 1) {
      const float ov = __shfl_down(bv, s); const int oi = __shfl_down(bi, s);
      if (ov > bv || (ov == bv && oi < bi)) { bv = ov; bi = oi; }
    }
    if ((tid & 63) == 0) { rv[tid >> 6] = bv; ri[tid >> 6] = bi; }
    __syncthreads();
    if (tid == 0) {
      int bb = 0;
      for (int w2 = 1; w2 < 4; ++w2)
        if (rv[w2] > rv[bb] || (rv[w2] == rv[bb] && ri[w2] < ri[bb])) bb = w2;
      vals[b*NEV + e] = rv[bb]; idxs[b*NEV + e] = ri[bb];
      bvs = rv[bb]; bis = ri[bb];
    }
    __syncthreads();
    if (mi == bis && my == bvs) my = -1e30f;   // positions unique
    __syncthreads();
  }
}

// ------------------------------------------------------------------
__device__ __forceinline__ float blk_max128(float v, float* red) {
  const int tid = threadIdx.x;
  red[tid] = v; __syncthreads();
  for (int s = 64; s > 0; s >>= 1) {
    if (tid < s) red[tid] = fmaxf(red[tid], red[tid + s]);
    __syncthreads();
  }
  const float r = red[0]; __syncthreads();
  return r;
}
__device__ __forceinline__ float blk_sum128(float v, float* red) {
  const int tid = threadIdx.x;
  red[tid] = v; __syncthreads();
  for (int s = 64; s > 0; s >>= 1) {
    if (tid < s) red[tid] += red[tid + s];
    __syncthreads();
  }
  const float r = red[0]; __syncthreads();
  return r;
}
__device__ __forceinline__ float mlp_hidden3(float latv, const float* __restrict__ hw,
                                             const float* __restrict__ hb, float* xa) {
  const int tid = threadIdx.x;
  float cur = latv;
  for (int i = 0; i < 3; ++i) {
    xa[tid] = cur; __syncthreads();
    const float* W = hw + (size_t)i*CCH*CCH;
    float acc = hb[i*CCH + tid];
    for (int c = 0; c < CCH; ++c) acc += xa[c] * W[c*CCH + tid];
    cur = acc > 0.f ? acc : 0.2f*acc;
    __syncthreads();
  }
  return cur;
}

// K8: lat + all three MLPs + softmaxes + amps. One 128-thread block per event.
__global__ __launch_bounds__(128) void k_mlp(
    const float* __restrict__ h, const float* __restrict__ scal,
    const float* __restrict__ vals, const int* __restrict__ idxs,
    const float* __restrict__ a_hw, const float* __restrict__ a_hb,
    const float* __restrict__ a_ow, const float* __restrict__ a_ob,
    const float* __restrict__ t_hw, const float* __restrict__ t_hb,
    const float* __restrict__ t_ow, const float* __restrict__ t_ob,
    const float* __restrict__ m_hw, const float* __restrict__ m_hb,
    const float* __restrict__ m_ow, const float* __restrict__ m_ob,
    float* __restrict__ p_atoms, float* __restrict__ p_trans, float* __restrict__ amps) {
  const int row = blockIdx.x;
  const int b = row >> 5;
  const int tid = threadIdx.x;
  __shared__ float xa[CCH];
  __shared__ float red[CCH];
  const int t = idxs[row];
  const float latv = h[((size_t)(b*CCH + tid))*TSAMP + t] * scal[b] * vals[row];

  {
    const float cur = mlp_hidden3(latv, a_hw, a_hb, xa);
    xa[tid] = cur; __syncthreads();
    float l0 = a_ob[tid], l1 = a_ob[tid+128], l2 = a_ob[tid+256], l3 = a_ob[tid+384];
    for (int c = 0; c < CCH; ++c) {
      const float xv = xa[c];
      const float* W = a_ow + (size_t)c*NATOMS + tid;
      l0 += xv*W[0]; l1 += xv*W[128]; l2 += xv*W[256]; l3 += xv*W[384];
    }
    const float mx = blk_max128(fmaxf(fmaxf(l0,l1), fmaxf(l2,l3)), red);
    const float e0 = expf(l0-mx), e1 = expf(l1-mx), e2 = expf(l2-mx), e3 = expf(l3-mx);
    const float inv = 1.f / blk_sum128(e0+e1+e2+e3, red);
    float* pa = p_atoms + (size_t)row*NATOMS;
    pa[tid] = e0*inv; pa[tid+128] = e1*inv; pa[tid+256] = e2*inv; pa[tid+384] = e3*inv;
  }
  {
    const float cur = mlp_hidden3(latv, t_hw, t_hb, xa);
    xa[tid] = cur; __syncthreads();
    float lg = -3.4e38f;
    if (tid < NTRANS) {
      float acc = t_ob[tid];
      for (int c = 0; c < CCH; ++c) acc += xa[c]*t_ow[c*NTRANS + tid];
      lg = acc;
    }
    const float mt = blk_max128(lg, red);
    const float et = (tid < NTRANS) ? expf(lg - mt) : 0.f;
    const float st = blk_sum128(et, red);
    if (tid < NTRANS) p_trans[(size_t)row*NTRANS + tid] = et/st;
  }
  {
    const float cur = mlp_hidden3(latv, m_hw, m_hb, xa);
    const float s = blk_sum128(cur * m_ow[tid], red);
    if (tid == 0) { const float v = s + m_ob[0]; amps[row] = v*v; }
  }
}

// K9: atoms_vec[row,:] = p_atoms[row] @ atoms_dict (512x512)
__global__ __launch_bounds__(256) void k_atoms_mm(const float* __restrict__ p_atoms,
                                                  const float* __restrict__ dict,
                                                  float* __restrict__ av) {
  const int row = blockIdx.x;
  __shared__ float p[NATOMS];
  for (int i = threadIdx.x; i < NATOMS; i += 256) p[i] = p_atoms[(size_t)row*NATOMS + i];
  __syncthreads();
  const int s0 = threadIdx.x*2;
  float a0=0, a1=0;
  for (int a = 0; a < NATOMS; ++a) {
    const float pa = p[a];
    const float2 dv = *(const float2*)(dict + (size_t)a*ASIZE + s0);
    a0 += pa*dv.x; a1 += pa*dv.y;
  }
  av[(size_t)row*ASIZE + s0] = a0; av[(size_t)row*ASIZE + s0 + 1] = a1;
}

// K10: transfers[row,:] = p_trans[row] @ transfer_dict (64x8192)
__global__ __launch_bounds__(256) void k_trans_mm(const float* __restrict__ p_trans,
                                                   const float* __restrict__ td,
                                                   float* __restrict__ trans) {
  const int row = blockIdx.y;
  const int t = blockIdx.x*2048 + threadIdx.x*8;
  __shared__ float p[NTRANS];
  if (threadIdx.x < NTRANS) p[threadIdx.x] = p_trans[(size_t)row*NTRANS + threadIdx.x];
  __syncthreads();
  float a0=0,a1=0,a2=0,a3=0,a4=0,a5=0,a6=0,a7=0;
  for (int j = 0; j < NTRANS; ++j) {
    const float pj = p[j];
    const float4 v0 = *(const float4*)(td + (size_t)j*TSIZE + t);
    const float4 v1 = *(const float4*)(td + (size_t)j*TSIZE + t + 4);
    a0 += pj*v0.x; a1 += pj*v0.y; a2 += pj*v0.z; a3 += pj*v0.w;
    a4 += pj*v1.x; a5 += pj*v1.y; a6 += pj*v1.z; a7 += pj*v1.w;
  }
  float* o = trans + (size_t)row*TSIZE + t;
  o[0]=a0; o[1]=a1; o[2]=a2; o[3]=a3; o[4]=a4; o[5]=a5; o[6]=a6; o[7]=a7;
}

// K11: ev[row,n] = (sum_{k<512} atoms[row,k]*transfers[row,n-k] + atoms_pad) * amp
__global__ __launch_bounds__(256) void k_ev(const float* __restrict__ trans,
                                            const float* __restrict__ av,
                                            const float* __restrict__ amps,
                                            float* __restrict__ ev) {
  const int row = blockIdx.y;
  const int t0 = blockIdx.x * 1024;
  __shared__ float al[512];
  __shared__ float tw[1536];
  for (int i = threadIdx.x; i < 512; i += 256) al[i] = av[(size_t)row*ASIZE + i];
  for (int i = threadIdx.x; i < 1536; i += 256) {
    const int g = t0 - 512 + i;
    tw[i] = (g >= 0) ? trans[(size_t)row*TSIZE + g] : 0.f;
  }
  __syncthreads();
  const int base = threadIdx.x*4 + 512;
  float a0=0,a1=0,a2=0,a3=0;
  float w0=tw[base], w1=tw[base+1], w2=tw[base+2], w3=tw[base+3];
#pragma unroll 8
  for (int k = 0; k < 512; ++k) {
    const float ak = al[k];
    a0 += ak*w0; a1 += ak*w1; a2 += ak*w2; a3 += ak*w3;
    w3 = w2; w2 = w1; w1 = w0; w0 = tw[base - k - 1];
  }
  const int n = t0 + threadIdx.x*4;
  const float amp = amps[row];
  float* e = ev + (size_t)row*TSIZE + n;
  e[0] = (a0 + (n+0 < 512 ? al[n+0] : 0.f)) * amp;
  e[1] = (a1 + (n+1 < 512 ? al[n+1] : 0.f)) * amp;
  e[2] = (a2 + (n+2 < 512 ? al[n+2] : 0.f)) * amp;
  e[3] = (a3 + (n+3 < 512 ? al[n+3] : 0.f)) * amp;
}

// K12: overlap-add gather (deterministic).
__global__ __launch_bounds__(256) void k_dry(const float* __restrict__ ev,
                                             const int* __restrict__ idxs,
                                             float* __restrict__ dry) {
  __shared__ int sidx[NROWS];
  for (int i = threadIdx.x; i < NROWS; i += 256) sidx[i] = idxs[i];
  __syncthreads();
  const int p = blockIdx.x*1024 + threadIdx.x*4;
  float a0=0,a1=0,a2=0,a3=0;
  for (int r = 0; r < NROWS; ++r) {
    const int off = p - sidx[r];
    if (off >= -3 && off < TSIZE) {
      const float* er = ev + (size_t)r*TSIZE;
      if ((unsigned)(off  ) < TSIZE) a0 += er[off];
      if ((unsigned)(off+1) < TSIZE) a1 += er[off+1];
      if ((unsigned)(off+2) < TSIZE) a2 += er[off+2];
      if ((unsigned)(off+3) < TSIZE) a3 += er[off+3];
    }
  }
  dry[p] = a0; dry[p+1] = a1; dry[p+2] = a2; dry[p+3] = a3;
}

// K13: room softmax + wet/dry mix scalars
__global__ void k_room(const float* __restrict__ ctx, const float* __restrict__ room_w,
                       const float* __restrict__ room_b, const float* __restrict__ mix_w,
                       const float* __restrict__ mix_b, float* __restrict__ roomp,
                       float* __restrict__ mix) {
  const int b = threadIdx.x >> 3;
  const int r = threadIdx.x & 7;
  float acc = room_b[r];
  for (int c = 0; c < CCH; ++c) acc += ctx[b*CCH + c] * room_w[c*8 + r];
  float m = acc;
  for (int s = 1; s < 8; s <<= 1) m = fmaxf(m, __shfl_xor(m, s, 8));
  const float e = expf(acc - m);
  float ssum = e;
  for (int s = 1; s < 8; s <<= 1) ssum += __shfl_xor(ssum, s, 8);
  roomp[b*8 + r] = e / ssum;
  if (r == 0) {
    float a = mix_b[0];
    for (int c = 0; c < CCH; ++c) a += ctx[b*CCH + c] * mix_w[c];
    mix[b] = 1.f/(1.f+expf(-a));
  }
}

// K14: impulse[b,t] = sum_r roomp[b,r]*rooms[r,t]
__global__ __launch_bounds__(256) void k_impulse(const float* __restrict__ roomp,
                                                 const float* __restrict__ rooms,
                                                 float* __restrict__ impulse) {
  const int b = blockIdx.y;
  const int t = blockIdx.x*1024 + threadIdx.x*4;
  float a0=0,a1=0,a2=0,a3=0;
  for (int r = 0; r < 8; ++r) {
    const float pr = roomp[b*8 + r];
    const float4 v = *(const float4*)(rooms + (size_t)r*TSAMP + t);
    a0 += pr*v.x; a1 += pr*v.y; a2 += pr*v.z; a3 += pr*v.w;
  }
  float* o = impulse + (size_t)b*TSAMP + t;
  o[0]=a0; o[1]=a1; o[2]=a2; o[3]=a3;
}

// K15: triangular reverb conv
__global__ __launch_bounds__(256) void k_wet(const float* __restrict__ dry,
                                             const float* __restrict__ impulse,
                                             float* __restrict__ wet) {
  const int t0 = blockIdx.x * 1024;
  const int kbeg = blockIdx.y * 4096;
  const int b = blockIdx.z;
  if (kbeg > t0 + 1023) return;
  __shared__ float dl[1024];
  __shared__ float il[2048];
  const float* imp = impulse + (size_t)b*TSAMP;
  const int tl = threadIdx.x * 4;
  float a0=0,a1=0,a2=0,a3=0;
  for (int kc = kbeg; kc < kbeg + 4096 && kc <= t0 + 1023; kc += 1024) {
    for (int i = threadIdx.x; i < 1024; i += 256) dl[i] = dry[kc + i];
    const int w0g = t0 - kc - 1024;
    for (int i = threadIdx.x; i < 2048; i += 256) {
      const int g = w0g + i;
      il[i] = (g >= 0) ? imp[g] : 0.f;
    }
    __syncthreads();
    const int base = tl + 1024;
    float w0=il[base], w1=il[base+1], w2=il[base+2], w3=il[base+3];
#pragma unroll 8
    for (int k = 0; k < 1024; ++k) {
      const float dv = dl[k];
      a0 += dv*w0; a1 += dv*w1; a2 += dv*w2; a3 += dv*w3;
      w3 = w2; w2 = w1; w1 = w0; w0 = il[base - k - 1];
    }
    __syncthreads();
  }
  float* wp = wet + (size_t)b*TSAMP + t0 + tl;
  atomicAdd(wp+0, a0); atomicAdd(wp+1, a1);
  atomicAdd(wp+2, a2); atomicAdd(wp+3, a3);
}

// K16: out = dry*(1-mix) + wet*mix
__global__ __launch_bounds__(256) void k_out(const float* __restrict__ dry,
                                             const float* __restrict__ wet,
                                             const float* __restrict__ mix,
                                             float* __restrict__ out) {
  const int b = blockIdx.y;
  const int t = blockIdx.x*1024 + threadIdx.x*4;
  const float m = mix[b];
  const float4 d = *(const float4*)(dry + t);
  const float4 w = *(const float4*)(wet + (size_t)b*TSAMP + t);
  float* o = out + (size_t)b*TSAMP + t;
  o[0] = d.x*(1.f-m) + w.x*m;
  o[1] = d.y*(1.f-m) + w.y*m;
  o[2] = d.z*(1.f-m) + w.z*m;
  o[3] = d.w*(1.f-m) + w.w*m;
}

// ------------------------------------------------------------------
extern "C" void kernel_launch(void* const* d_in, const int* in_sizes, int n_in,
                              void* d_out, int out_size, void* d_ws, size_t ws_size,
                              hipStream_t stream) {
  (void)in_sizes; (void)n_in; (void)out_size; (void)ws_size;
  const float* x      = (const float*)d_in[0];
  const float* bank   = (const float*)d_in[1];
  const float* w_net  = (const float*)d_in[2];
  const float* b_net  = (const float*)d_in[3];
  const float* attn_w = (const float*)d_in[4];
  const float* attn_b = (const float*)d_in[5];
  const float* a_hw = (const float*)d_in[6];
  const float* a_hb = (const float*)d_in[7];
  const float* a_ow = (const float*)d_in[8];
  const float* a_ob = (const float*)d_in[9];
  const float* t_hw = (const float*)d_in[10];
  const float* t_hb = (const float*)d_in[11];
  const float* t_ow = (const float*)d_in[12];
  const float* t_ob = (const float*)d_in[13];
  const float* m_hw = (const float*)d_in[14];
  const float* m_hb = (const float*)d_in[15];
  const float* m_ow = (const float*)d_in[16];
  const float* m_ob = (const float*)d_in[17];
  const float* atoms_dict    = (const float*)d_in[18];
  const float* transfer_dict = (const float*)d_in[19];
  const float* rooms  = (const float*)d_in[20];
  const float* room_w = (const float*)d_in[21];
  const float* room_b = (const float*)d_in[22];
  const float* mix_w  = (const float*)d_in[23];
  const float* mix_b  = (const float*)d_in[24];
  float* out = (float*)d_out;

  // ---- workspace layout (~169 MB):
  //  H   @ 0         : 33,554,432 floats  [B,C,T] (front out + final acts)
  //  t1  @ 33.55M    :  4,194,304 floats  per-batch ping
  //  t2  @ 37.75M    :  4,194,304 floats  per-batch pong
  //  whi @ 41.94M    :  245,760 f16 (122,880 floats)  split weights hi
  //  wlo @ 42.07M    :  245,760 f16                   split weights lo
  //  post-conv scratch aliases t1/t2 (dead after conv; stream-ordered).
  float* ws = (float*)d_ws;
  float* H  = ws;
  float* t1 = ws + (size_t)33554432;
  float* t2 = ws + (size_t)37748736;
  _Float16* whi = (_Float16*)(ws + (size_t)41943040);
  _Float16* wlo = (_Float16*)(ws + (size_t)42065920);

  size_t off = 33554432;                            // scratch base (aliases t1)
  double* sums = (double*)(ws + off); off += 32;
  float* attn  = ws + off; off += (size_t)NBATCH*TSAMP;
  float* scal  = ws + off; off += 8;
  float* ctx   = ws + off; off += NBATCH*CCH;
  float* vals  = ws + off; off += NROWS;
  int*   idxs  = (int*)(ws + off); off += NROWS;
  float* p_atoms = ws + off; off += (size_t)NROWS*NATOMS;
  float* p_trans = ws + off; off += (size_t)NROWS*NTRANS;
  float* amps  = ws + off; off += NROWS;
  float* av    = ws + off; off += (size_t)NROWS*ASIZE;
  float* trans = ws + off; off += (size_t)NROWS*TSIZE;
  float* ev    = ws + off; off += (size_t)NROWS*TSIZE;
  float* dry   = ws + off; off += TSAMP;
  float* roomp = ws + off; off += 64;
  float* mix   = ws + off; off += 8;
  float* impulse = ws + off; off += (size_t)NBATCH*TSAMP;
  float* wet   = ws + off; off += (size_t)NBATCH*TSAMP;
  float* cand_v = ws + off; off += 2048;
  int*   cand_i = (int*)(ws + off); off += 2048;
  // scratch ends ~38.86M floats < 41.94M (whi) — disjoint from weights.

  k_wsplit<<<960, 256, 0, stream>>>(w_net, whi, wlo);
  k_front<<<dim3(16, 8, 8), 256, 0, stream>>>(x, bank, H);

  const int dil[5] = {1, 3, 9, 27, 1};
  for (int b = 0; b < NBATCH; ++b) {
    float* Hb = H + (size_t)b*CCH*TSAMP;
    float* io[6] = {Hb, t1, t2, t1, t2, Hb};
    for (int i = 0; i < 5; ++i) {
      const int d = dil[i];
      const size_t smem = (size_t)(64 + 2*d) * 544;   // 2 arrays x [twin][136] f16
      k_dil_mfma<<<512, 256, smem, stream>>>(
          io[i], whi + (size_t)i*49152, wlo + (size_t)i*49152, b_net + i*CCH,
          io[i+1], d);
    }
  }

  k_zero<<<1024, 256, 0, stream>>>(wet, sums);
  k_stats<<<dim3(64, 8), 256, 0, stream>>>(H, sums);
  k_scale<<<1, 64, 0, stream>>>(sums, scal);
  k_context<<<1024, 256, 0, stream>>>(H, scal, ctx);
  k_attn<<<dim3(32, 8), 256, 0, stream>>>(H, scal, attn_w, attn_b, attn);
  k_topk1<<<dim3(8, 8), 256, 0, stream>>>(attn, cand_v, cand_i);
  k_topk2<<<8, 256, 0, stream>>>(cand_v, cand_i, vals, idxs);
  k_mlp<<<256, 128, 0, stream>>>(H, scal, vals, idxs,
                                 a_hw, a_hb, a_ow, a_ob,
                                 t_hw, t_hb, t_ow, t_ob,
                                 m_hw, m_hb, m_ow, m_ob,
                                 p_atoms, p_trans, amps);
  k_atoms_mm<<<256, 256, 0, stream>>>(p_atoms, atoms_dict, av);
  k_trans_mm<<<dim3(4, 256), 256, 0, stream>>>(p_trans, transfer_dict, trans);
  k_ev<<<dim3(8, 256), 256, 0, stream>>>(trans, av, amps, ev);
  k_dry<<<32, 256, 0, stream>>>(ev, idxs, dry);
  k_room<<<1, 64, 0, stream>>>(ctx, room_w, room_b, mix_w, mix_b, roomp, mix);
  k_impulse<<<dim3(32, 8), 256, 0, stream>>>(roomp, rooms, impulse);
  k_wet<<<dim3(32, 8, 8), 256, 0, stream>>>(dry, impulse, wet);
  k_out<<<dim3(32, 8), 256, 0, stream>>>(dry, wet, mix, out);
}

// Round 4
// 3113.309 us; speedup vs baseline: 2.8508x; 1.0741x over previous
//
#include <hip/hip_runtime.h>
#include <math.h>

#define TSAMP 32768
#define CCH 128
#define NBATCH 8
#define NEV 32
#define NROWS 256   // NBATCH*NEV
#define NATOMS 512
#define ASIZE 512
#define NTRANS 64
#define TSIZE 8192

typedef _Float16 f16x8 __attribute__((ext_vector_type(8)));
typedef float f32x4 __attribute__((ext_vector_type(4)));

// skewed LDS index: +1 pad float every 32 -> stride-8 lane pattern becomes
// a 2-cover of all 32 banks (2-way = free, m136)
#define XPAD(p) ((p) + ((p) >> 5))

// ------------------------------------------------------------------
// K0: zero the atomic accumulators (wet buffer + f64 stat sums).
__global__ __launch_bounds__(256) void k_zero(float* __restrict__ wet,
                                              double* __restrict__ sums) {
  int i = blockIdx.x * 256 + threadIdx.x;
  if (i < NBATCH * TSAMP) wet[i] = 0.f;
  if (i < 16) sums[i] = 0.0;
}

// ------------------------------------------------------------------
// Kw: split conv weights into f16 hi/lo in layout [layer][k][o][ci]
__global__ __launch_bounds__(256) void k_wsplit(const float* __restrict__ wn,
                                                _Float16* __restrict__ whi,
                                                _Float16* __restrict__ wlo) {
  const int i = blockIdx.x * 256 + threadIdx.x;   // 5*3*128*128 = 245760
  if (i >= 245760) return;
  const int ci = i & 127;
  int r = i >> 7;
  const int o = r & 127;
  r >>= 7;
  const int k = r % 3;
  const int l = r / 3;
  const float w = wn[(((size_t)l*128 + o)*128 + ci)*3 + k];
  const _Float16 hi = (_Float16)w;
  whi[i] = hi;
  wlo[i] = (_Float16)(w - (float)hi);
}

// ------------------------------------------------------------------
// K1: front filter bank, ALL batches. h[b,c,t] = sum_k x[b,t+k-256]*bank[c,k]
// Skewed LDS (XPAD) kills the 16-way stride-8 bank conflicts.
__global__ __launch_bounds__(256) void k_front(const float* __restrict__ x,
                                               const float* __restrict__ bank,
                                               float* __restrict__ h) {
  __shared__ float xs[2640];                 // 2560 + 80 pad
  const int t0 = blockIdx.x * 2048;
  const int cg = blockIdx.y;
  const int b  = blockIdx.z;
  const float* xb = x + (size_t)b * TSAMP;
  for (int i = threadIdx.x; i < 2560; i += 256) {
    const int g = t0 - 256 + i;
    xs[XPAD(i)] = (g >= 0 && g < TSAMP) ? xb[g] : 0.f;
  }
  __syncthreads();
  const int tl = threadIdx.x * 8;
  for (int cc = 0; cc < 16; ++cc) {
    const int c = cg * 16 + cc;
    const float* __restrict__ bk = bank + (size_t)c * 512;
    float a0=0,a1=0,a2=0,a3=0,a4=0,a5=0,a6=0,a7=0;
    float w0=xs[XPAD(tl+0)],w1=xs[XPAD(tl+1)],w2=xs[XPAD(tl+2)],w3=xs[XPAD(tl+3)],
          w4=xs[XPAD(tl+4)],w5=xs[XPAD(tl+5)],w6=xs[XPAD(tl+6)],w7=xs[XPAD(tl+7)];
#pragma unroll 8
    for (int k = 0; k < 512; ++k) {
      const float bv = bk[k];
      a0 += bv*w0; a1 += bv*w1; a2 += bv*w2; a3 += bv*w3;
      a4 += bv*w4; a5 += bv*w5; a6 += bv*w6; a7 += bv*w7;
      w0=w1; w1=w2; w2=w3; w3=w4; w4=w5; w5=w6; w6=w7;
      const int p = tl + k + 8;
      w7 = xs[XPAD(p)];
    }
    float* hp = h + ((size_t)b*CCH + c)*TSAMP + t0 + tl;
    hp[0]=a0; hp[1]=a1; hp[2]=a2; hp[3]=a3;
    hp[4]=a4; hp[5]=a5; hp[6]=a6; hp[7]=a7;
  }
}

// ------------------------------------------------------------------
// K2: one residual dilated conv layer, TWO batches per dispatch (blockIdx.y).
// hout[o,t] = hin[o,t] + lrelu( sum_{ci,k} hin[ci,t+(k-1)d]*w[o,ci,k] + b[o] )
// Block: 128o x 64t, 4 waves each 32o x 64t = 8 mfma_16x16x32 tiles.
// X staged transposed in LDS [tw][ci] f16 (hi,lo), rows padded to 136 f16.
// 3 passes per K-chunk: Ahi*Bhi + Alo*Bhi + Ahi*Blo (~22-bit mantissa).
__global__ __launch_bounds__(256) void k_dil_mfma(
    const float* __restrict__ hin0, const _Float16* __restrict__ whi,
    const _Float16* __restrict__ wlo, const float* __restrict__ bias,
    float* __restrict__ hout0, const int d) {
  extern __shared__ _Float16 sh[];          // xhi[twin][136] then xlo[twin][136]
  const int twin = 64 + 2*d;
  _Float16* shi = sh;
  _Float16* slo = sh + twin*136;
  const int t0 = blockIdx.x * 64;
  const size_t bs = (size_t)blockIdx.y * CCH * TSAMP;
  const float* __restrict__ hin = hin0 + bs;
  float* __restrict__ hout = hout0 + bs;
  const int tid = threadIdx.x;

  for (int flat = tid; flat < 128*twin; flat += 256) {
    const int ci = flat & 127;
    const int tw = flat >> 7;
    const int g = t0 - d + tw;
    const float v = (g >= 0 && g < TSAMP) ? hin[(size_t)ci*TSAMP + g] : 0.f;
    const _Float16 hi = (_Float16)v;
    shi[tw*136 + ci] = hi;
    slo[tw*136 + ci] = (_Float16)(v - (float)hi);
  }
  __syncthreads();

  const int wv = tid >> 6;
  const int lane = tid & 63;
  const int n = lane & 15;
  const int quad = lane >> 4;
  const int o0 = wv * 32;

  f32x4 acc[2][4];
#pragma unroll
  for (int i = 0; i < 2; ++i)
#pragma unroll
    for (int j = 0; j < 4; ++j) acc[i][j] = (f32x4){0.f,0.f,0.f,0.f};

  for (int k = 0; k < 3; ++k) {
    for (int kc = 0; kc < 4; ++kc) {
      const int cib = kc*32 + quad*8;
      f16x8 ahi[2], alo[2];
#pragma unroll
      for (int os = 0; os < 2; ++os) {
        const size_t wo = ((size_t)k*128 + (o0 + os*16 + n))*128 + cib;
        ahi[os] = *(const f16x8*)(whi + wo);
        alo[os] = *(const f16x8*)(wlo + wo);
      }
      f16x8 bhi[4], blo[4];
#pragma unroll
      for (int ts = 0; ts < 4; ++ts) {
        const int a = (ts*16 + n + k*d)*136 + cib;
        bhi[ts] = *(const f16x8*)(shi + a);
        blo[ts] = *(const f16x8*)(slo + a);
      }
#pragma unroll
      for (int os = 0; os < 2; ++os)
#pragma unroll
        for (int ts = 0; ts < 4; ++ts) {
          acc[os][ts] = __builtin_amdgcn_mfma_f32_16x16x32_f16(ahi[os], bhi[ts], acc[os][ts], 0, 0, 0);
          acc[os][ts] = __builtin_amdgcn_mfma_f32_16x16x32_f16(alo[os], bhi[ts], acc[os][ts], 0, 0, 0);
          acc[os][ts] = __builtin_amdgcn_mfma_f32_16x16x32_f16(ahi[os], blo[ts], acc[os][ts], 0, 0, 0);
        }
    }
  }

#pragma unroll
  for (int os = 0; os < 2; ++os) {
    const int ob = o0 + os*16 + quad*4;
#pragma unroll
    for (int ts = 0; ts < 4; ++ts) {
      const int t = t0 + ts*16 + n;
#pragma unroll
      for (int r = 0; r < 4; ++r) {
        const int o = ob + r;
        float v = acc[os][ts][r] + bias[o];
        v = v > 0.f ? v : 0.2f*v;
        const size_t gi = (size_t)o*TSAMP + t;
        hout[gi] = hin[gi] + v;
      }
    }
  }
}

// ------------------------------------------------------------------
// K3: per-batch sum / sumsq (f64 atomics)
__global__ __launch_bounds__(256) void k_stats(const float* __restrict__ h,
                                               double* __restrict__ sums) {
  const int b = blockIdx.y;
  const float* p = h + (size_t)b*CCH*TSAMP;
  double s = 0.0, s2 = 0.0;
  const size_t n = (size_t)CCH*TSAMP;
  for (size_t i = (size_t)blockIdx.x*256 + threadIdx.x; i < n; i += 64*256) {
    const double v = (double)p[i];
    s += v; s2 += v*v;
  }
  for (int d_ = 32; d_ > 0; d_ >>= 1) { s += __shfl_down(s, d_); s2 += __shfl_down(s2, d_); }
  if ((threadIdx.x & 63) == 0) {
    atomicAdd(&sums[b*2],   s);
    atomicAdd(&sums[b*2+1], s2);
  }
}

// K4: scale[b] = 1/(std_b + 1e-8)
__global__ void k_scale(const double* __restrict__ sums, float* __restrict__ scal) {
  const int b = threadIdx.x;
  if (b < NBATCH) {
    const double n = (double)CCH * (double)TSAMP;
    const double mean = sums[b*2] / n;
    double var = sums[b*2+1] / n - mean*mean;
    if (var < 0.0) var = 0.0;
    scal[b] = (float)(1.0 / (sqrt(var) + 1e-8));
  }
}

// K5: context[b,c] = scale_b * max_t h[b,c,t]
__global__ __launch_bounds__(256) void k_context(const float* __restrict__ h,
                                                 const float* __restrict__ scal,
                                                 float* __restrict__ ctx) {
  const int bc = blockIdx.x;
  const float* p = h + (size_t)bc*TSAMP;
  float m = -3.4e38f;
  for (int i = threadIdx.x; i < TSAMP; i += 256) m = fmaxf(m, p[i]);
  for (int d_ = 32; d_ > 0; d_ >>= 1) m = fmaxf(m, __shfl_down(m, d_));
  __shared__ float wm[4];
  if ((threadIdx.x & 63) == 0) wm[threadIdx.x >> 6] = m;
  __syncthreads();
  if (threadIdx.x == 0) {
    m = fmaxf(fmaxf(wm[0], wm[1]), fmaxf(wm[2], wm[3]));
    ctx[bc] = m * scal[bc >> 7];
  }
}

// K6: attn[b,t] = sigmoid(scale_b * sum_c h[b,c,t]*aw[c] + ab)
__global__ __launch_bounds__(256) void k_attn(const float* __restrict__ h,
                                              const float* __restrict__ scal,
                                              const float* __restrict__ aw,
                                              const float* __restrict__ ab,
                                              float* __restrict__ attn) {
  const int b = blockIdx.y;
  const int t = blockIdx.x*1024 + threadIdx.x*4;
  const float* p = h + (size_t)b*CCH*TSAMP + t;
  float a0=0,a1=0,a2=0,a3=0;
  for (int c = 0; c < CCH; ++c) {
    const float wc = aw[c];
    const float4 v = *(const float4*)(p + (size_t)c*TSAMP);
    a0 += wc*v.x; a1 += wc*v.y; a2 += wc*v.z; a3 += wc*v.w;
  }
  const float s = scal[b], bb = ab[0];
  float* o = attn + (size_t)b*TSAMP + t;
  o[0] = 1.f/(1.f+expf(-(a0*s+bb)));
  o[1] = 1.f/(1.f+expf(-(a1*s+bb)));
  o[2] = 1.f/(1.f+expf(-(a2*s+bb)));
  o[3] = 1.f/(1.f+expf(-(a3*s+bb)));
}

// ------------------------------------------------------------------
// K7a: per-4096-chunk top-32 (LDS-resident, masking argmax).
__global__ __launch_bounds__(256) void k_topk1(const float* __restrict__ attn,
                                               float* __restrict__ cv,
                                               int* __restrict__ cidx) {
  const int ch = blockIdx.x, b = blockIdx.y;
  const float* a = attn + (size_t)b*TSAMP + ch*4096;
  __shared__ float v[4096];
  __shared__ float rv[4]; __shared__ int ri[4];
  const int tid = threadIdx.x;
  for (int i = tid; i < 4096; i += 256) v[i] = a[i];
  __syncthreads();
  for (int e = 0; e < NEV; ++e) {
    float bv = -1e30f; int bi = 0;
    for (int i = tid; i < 4096; i += 256) {
      const float x = v[i];
      if (x > bv) { bv = x; bi = i; }
    }
    for (int s = 32; s; s >>= 1) {
      const float ov = __shfl_down(bv, s); const int oi = __shfl_down(bi, s);
      if (ov > bv || (ov == bv && oi < bi)) { bv = ov; bi = oi; }
    }
    if ((tid & 63) == 0) { rv[tid >> 6] = bv; ri[tid >> 6] = bi; }
    __syncthreads();
    if (tid == 0) {
      int bb = 0;
      for (int w2 = 1; w2 < 4; ++w2)
        if (rv[w2] > rv[bb] || (rv[w2] == rv[bb] && ri[w2] < ri[bb])) bb = w2;
      cv[(b*8 + ch)*NEV + e] = rv[bb];
      cidx[(b*8 + ch)*NEV + e] = ch*4096 + ri[bb];
      v[ri[bb]] = -1e30f;
    }
    __syncthreads();
  }
}

// K7b: final top-32 over 256 candidates
__global__ __launch_bounds__(256) void k_topk2(const float* __restrict__ cv,
                                               const int* __restrict__ ci_,
                                               float* __restrict__ vals,
                                               int* __restrict__ idxs) {
  const int b = blockIdx.x;
  const int tid = threadIdx.x;
  float my = cv[b*256 + tid];
  int   mi = ci_[b*256 + tid];
  __shared__ float rv[4]; __shared__ int ri[4];
  __shared__ float bvs; __shared__ int bis;
  for (int e = 0; e < NEV; ++e) {
    float bv = my; int bi = mi;
    for (int s = 32; s; s >>= 1) {
      const float ov = __shfl_down(bv, s); const int oi = __shfl_down(bi, s);
      if (ov > bv || (ov == bv && oi < bi)) { bv = ov; bi = oi; }
    }
    if ((tid & 63) == 0) { rv[tid >> 6] = bv; ri[tid >> 6] = bi; }
    __syncthreads();
    if (tid == 0) {
      int bb = 0;
      for (int w2 = 1; w2 < 4; ++w2)
        if (rv[w2] > rv[bb] || (rv[w2] == rv[bb] && ri[w2] < ri[bb])) bb = w2;
      vals[b*NEV + e] = rv[bb]; idxs[b*NEV + e] = ri[bb];
      bvs = rv[bb]; bis = ri[bb];
    }
    __syncthreads();
    if (mi == bis && my == bvs) my = -1e30f;
    __syncthreads();
  }
}

// ------------------------------------------------------------------
__device__ __forceinline__ float blk_max128(float v, float* red) {
  const int tid = threadIdx.x;
  red[tid] = v; __syncthreads();
  for (int s = 64; s > 0; s >>= 1) {
    if (tid < s) red[tid] = fmaxf(red[tid], red[tid + s]);
    __syncthreads();
  }
  const float r = red[0]; __syncthreads();
  return r;
}
__device__ __forceinline__ float blk_sum128(float v, float* red) {
  const int tid = threadIdx.x;
  red[tid] = v; __syncthreads();
  for (int s = 64; s > 0; s >>= 1) {
    if (tid < s) red[tid] += red[tid + s];
    __syncthreads();
  }
  const float r = red[0]; __syncthreads();
  return r;
}
__device__ __forceinline__ float mlp_hidden3(float latv, const float* __restrict__ hw,
                                             const float* __restrict__ hb, float* xa) {
  const int tid = threadIdx.x;
  float cur = latv;
  for (int i = 0; i < 3; ++i) {
    xa[tid] = cur; __syncthreads();
    const float* W = hw + (size_t)i*CCH*CCH;
    float acc = hb[i*CCH + tid];
    for (int c = 0; c < CCH; ++c) acc += xa[c] * W[c*CCH + tid];
    cur = acc > 0.f ? acc : 0.2f*acc;
    __syncthreads();
  }
  return cur;
}

// K8: lat + all three MLPs + softmaxes + amps. One 128-thread block per event.
__global__ __launch_bounds__(128) void k_mlp(
    const float* __restrict__ h, const float* __restrict__ scal,
    const float* __restrict__ vals, const int* __restrict__ idxs,
    const float* __restrict__ a_hw, const float* __restrict__ a_hb,
    const float* __restrict__ a_ow, const float* __restrict__ a_ob,
    const float* __restrict__ t_hw, const float* __restrict__ t_hb,
    const float* __restrict__ t_ow, const float* __restrict__ t_ob,
    const float* __restrict__ m_hw, const float* __restrict__ m_hb,
    const float* __restrict__ m_ow, const float* __restrict__ m_ob,
    float* __restrict__ p_atoms, float* __restrict__ p_trans, float* __restrict__ amps) {
  const int row = blockIdx.x;
  const int b = row >> 5;
  const int tid = threadIdx.x;
  __shared__ float xa[CCH];
  __shared__ float red[CCH];
  const int t = idxs[row];
  const float latv = h[((size_t)(b*CCH + tid))*TSAMP + t] * scal[b] * vals[row];

  {
    const float cur = mlp_hidden3(latv, a_hw, a_hb, xa);
    xa[tid] = cur; __syncthreads();
    float l0 = a_ob[tid], l1 = a_ob[tid+128], l2 = a_ob[tid+256], l3 = a_ob[tid+384];
    for (int c = 0; c < CCH; ++c) {
      const float xv = xa[c];
      const float* W = a_ow + (size_t)c*NATOMS + tid;
      l0 += xv*W[0]; l1 += xv*W[128]; l2 += xv*W[256]; l3 += xv*W[384];
    }
    const float mx = blk_max128(fmaxf(fmaxf(l0,l1), fmaxf(l2,l3)), red);
    const float e0 = expf(l0-mx), e1 = expf(l1-mx), e2 = expf(l2-mx), e3 = expf(l3-mx);
    const float inv = 1.f / blk_sum128(e0+e1+e2+e3, red);
    float* pa = p_atoms + (size_t)row*NATOMS;
    pa[tid] = e0*inv; pa[tid+128] = e1*inv; pa[tid+256] = e2*inv; pa[tid+384] = e3*inv;
  }
  {
    const float cur = mlp_hidden3(latv, t_hw, t_hb, xa);
    xa[tid] = cur; __syncthreads();
    float lg = -3.4e38f;
    if (tid < NTRANS) {
      float acc = t_ob[tid];
      for (int c = 0; c < CCH; ++c) acc += xa[c]*t_ow[c*NTRANS + tid];
      lg = acc;
    }
    const float mt = blk_max128(lg, red);
    const float et = (tid < NTRANS) ? expf(lg - mt) : 0.f;
    const float st = blk_sum128(et, red);
    if (tid < NTRANS) p_trans[(size_t)row*NTRANS + tid] = et/st;
  }
  {
    const float cur = mlp_hidden3(latv, m_hw, m_hb, xa);
    const float s = blk_sum128(cur * m_ow[tid], red);
    if (tid == 0) { const float v = s + m_ob[0]; amps[row] = v*v; }
  }
}

// K9: atoms_vec[row,:] = p_atoms[row] @ atoms_dict (512x512)
__global__ __launch_bounds__(256) void k_atoms_mm(const float* __restrict__ p_atoms,
                                                  const float* __restrict__ dict,
                                                  float* __restrict__ av) {
  const int row = blockIdx.x;
  __shared__ float p[NATOMS];
  for (int i = threadIdx.x; i < NATOMS; i += 256) p[i] = p_atoms[(size_t)row*NATOMS + i];
  __syncthreads();
  const int s0 = threadIdx.x*2;
  float a0=0, a1=0;
  for (int a = 0; a < NATOMS; ++a) {
    const float pa = p[a];
    const float2 dv = *(const float2*)(dict + (size_t)a*ASIZE + s0);
    a0 += pa*dv.x; a1 += pa*dv.y;
  }
  av[(size_t)row*ASIZE + s0] = a0; av[(size_t)row*ASIZE + s0 + 1] = a1;
}

// K10: transfers[row,:] = p_trans[row] @ transfer_dict (64x8192)
__global__ __launch_bounds__(256) void k_trans_mm(const float* __restrict__ p_trans,
                                                   const float* __restrict__ td,
                                                   float* __restrict__ trans) {
  const int row = blockIdx.y;
  const int t = blockIdx.x*2048 + threadIdx.x*8;
  __shared__ float p[NTRANS];
  if (threadIdx.x < NTRANS) p[threadIdx.x] = p_trans[(size_t)row*NTRANS + threadIdx.x];
  __syncthreads();
  float a0=0,a1=0,a2=0,a3=0,a4=0,a5=0,a6=0,a7=0;
  for (int j = 0; j < NTRANS; ++j) {
    const float pj = p[j];
    const float4 v0 = *(const float4*)(td + (size_t)j*TSIZE + t);
    const float4 v1 = *(const float4*)(td + (size_t)j*TSIZE + t + 4);
    a0 += pj*v0.x; a1 += pj*v0.y; a2 += pj*v0.z; a3 += pj*v0.w;
    a4 += pj*v1.x; a5 += pj*v1.y; a6 += pj*v1.z; a7 += pj*v1.w;
  }
  float* o = trans + (size_t)row*TSIZE + t;
  o[0]=a0; o[1]=a1; o[2]=a2; o[3]=a3; o[4]=a4; o[5]=a5; o[6]=a6; o[7]=a7;
}

// K11: ev[row,n] = (sum_{k<512} atoms[row,k]*transfers[row,n-k] + atoms_pad) * amp
__global__ __launch_bounds__(256) void k_ev(const float* __restrict__ trans,
                                            const float* __restrict__ av,
                                            const float* __restrict__ amps,
                                            float* __restrict__ ev) {
  const int row = blockIdx.y;
  const int t0 = blockIdx.x * 1024;
  __shared__ float al[512];
  __shared__ float tw[1536];
  for (int i = threadIdx.x; i < 512; i += 256) al[i] = av[(size_t)row*ASIZE + i];
  for (int i = threadIdx.x; i < 1536; i += 256) {
    const int g = t0 - 512 + i;
    tw[i] = (g >= 0) ? trans[(size_t)row*TSIZE + g] : 0.f;
  }
  __syncthreads();
  const int base = threadIdx.x*4 + 512;
  float a0=0,a1=0,a2=0,a3=0;
  float w0=tw[base], w1=tw[base+1], w2=tw[base+2], w3=tw[base+3];
#pragma unroll 8
  for (int k = 0; k < 512; ++k) {
    const float ak = al[k];
    a0 += ak*w0; a1 += ak*w1; a2 += ak*w2; a3 += ak*w3;
    w3 = w2; w2 = w1; w1 = w0; w0 = tw[base - k - 1];
  }
  const int n = t0 + threadIdx.x*4;
  const float amp = amps[row];
  float* e = ev + (size_t)row*TSIZE + n;
  e[0] = (a0 + (n+0 < 512 ? al[n+0] : 0.f)) * amp;
  e[1] = (a1 + (n+1 < 512 ? al[n+1] : 0.f)) * amp;
  e[2] = (a2 + (n+2 < 512 ? al[n+2] : 0.f)) * amp;
  e[3] = (a3 + (n+3 < 512 ? al[n+3] : 0.f)) * amp;
}

// K12: overlap-add gather (deterministic).
__global__ __launch_bounds__(256) void k_dry(const float* __restrict__ ev,
                                             const int* __restrict__ idxs,
                                             float* __restrict__ dry) {
  __shared__ int sidx[NROWS];
  for (int i = threadIdx.x; i < NROWS; i += 256) sidx[i] = idxs[i];
  __syncthreads();
  const int p = blockIdx.x*1024 + threadIdx.x*4;
  float a0=0,a1=0,a2=0,a3=0;
  for (int r = 0; r < NROWS; ++r) {
    const int off = p - sidx[r];
    if (off >= -3 && off < TSIZE) {
      const float* er = ev + (size_t)r*TSIZE;
      if ((unsigned)(off  ) < TSIZE) a0 += er[off];
      if ((unsigned)(off+1) < TSIZE) a1 += er[off+1];
      if ((unsigned)(off+2) < TSIZE) a2 += er[off+2];
      if ((unsigned)(off+3) < TSIZE) a3 += er[off+3];
    }
  }
  dry[p] = a0; dry[p+1] = a1; dry[p+2] = a2; dry[p+3] = a3;
}

// K13: room softmax + wet/dry mix scalars
__global__ void k_room(const float* __restrict__ ctx, const float* __restrict__ room_w,
                       const float* __restrict__ room_b, const float* __restrict__ mix_w,
                       const float* __restrict__ mix_b, float* __restrict__ roomp,
                       float* __restrict__ mix) {
  const int b = threadIdx.x >> 3;
  const int r = threadIdx.x & 7;
  float acc = room_b[r];
  for (int c = 0; c < CCH; ++c) acc += ctx[b*CCH + c] * room_w[c*8 + r];
  float m = acc;
  for (int s = 1; s < 8; s <<= 1) m = fmaxf(m, __shfl_xor(m, s, 8));
  const float e = expf(acc - m);
  float ssum = e;
  for (int s = 1; s < 8; s <<= 1) ssum += __shfl_xor(ssum, s, 8);
  roomp[b*8 + r] = e / ssum;
  if (r == 0) {
    float a = mix_b[0];
    for (int c = 0; c < CCH; ++c) a += ctx[b*CCH + c] * mix_w[c];
    mix[b] = 1.f/(1.f+expf(-a));
  }
}

// K14: impulse[b,t] = sum_r roomp[b,r]*rooms[r,t]
__global__ __launch_bounds__(256) void k_impulse(const float* __restrict__ roomp,
                                                 const float* __restrict__ rooms,
                                                 float* __restrict__ impulse) {
  const int b = blockIdx.y;
  const int t = blockIdx.x*1024 + threadIdx.x*4;
  float a0=0,a1=0,a2=0,a3=0;
  for (int r = 0; r < 8; ++r) {
    const float pr = roomp[b*8 + r];
    const float4 v = *(const float4*)(rooms + (size_t)r*TSAMP + t);
    a0 += pr*v.x; a1 += pr*v.y; a2 += pr*v.z; a3 += pr*v.w;
  }
  float* o = impulse + (size_t)b*TSAMP + t;
  o[0]=a0; o[1]=a1; o[2]=a2; o[3]=a3;
}

// K15: triangular reverb conv
__global__ __launch_bounds__(256) void k_wet(const float* __restrict__ dry,
                                             const float* __restrict__ impulse,
                                             float* __restrict__ wet) {
  const int t0 = blockIdx.x * 1024;
  const int kbeg = blockIdx.y * 4096;
  const int b = blockIdx.z;
  if (kbeg > t0 + 1023) return;
  __shared__ float dl[1024];
  __shared__ float il[2048];
  const float* imp = impulse + (size_t)b*TSAMP;
  const int tl = threadIdx.x * 4;
  float a0=0,a1=0,a2=0,a3=0;
  for (int kc = kbeg; kc < kbeg + 4096 && kc <= t0 + 1023; kc += 1024) {
    for (int i = threadIdx.x; i < 1024; i += 256) dl[i] = dry[kc + i];
    const int w0g = t0 - kc - 1024;
    for (int i = threadIdx.x; i < 2048; i += 256) {
      const int g = w0g + i;
      il[i] = (g >= 0) ? imp[g] : 0.f;
    }
    __syncthreads();
    const int base = tl + 1024;
    float w0=il[base], w1=il[base+1], w2=il[base+2], w3=il[base+3];
#pragma unroll 8
    for (int k = 0; k < 1024; ++k) {
      const float dv = dl[k];
      a0 += dv*w0; a1 += dv*w1; a2 += dv*w2; a3 += dv*w3;
      w3 = w2; w2 = w1; w1 = w0; w0 = il[base - k - 1];
    }
    __syncthreads();
  }
  float* wp = wet + (size_t)b*TSAMP + t0 + tl;
  atomicAdd(wp+0, a0); atomicAdd(wp+1, a1);
  atomicAdd(wp+2, a2); atomicAdd(wp+3, a3);
}

// K16: out = dry*(1-mix) + wet*mix
__global__ __launch_bounds__(256) void k_out(const float* __restrict__ dry,
                                             const float* __restrict__ wet,
                                             const float* __restrict__ mix,
                                             float* __restrict__ out) {
  const int b = blockIdx.y;
  const int t = blockIdx.x*1024 + threadIdx.x*4;
  const float m = mix[b];
  const float4 d = *(const float4*)(dry + t);
  const float4 w = *(const float4*)(wet + (size_t)b*TSAMP + t);
  float* o = out + (size_t)b*TSAMP + t;
  o[0] = d.x*(1.f-m) + w.x*m;
  o[1] = d.y*(1.f-m) + w.y*m;
  o[2] = d.z*(1.f-m) + w.z*m;
  o[3] = d.w*(1.f-m) + w.w*m;
}

// ------------------------------------------------------------------
extern "C" void kernel_launch(void* const* d_in, const int* in_sizes, int n_in,
                              void* d_out, int out_size, void* d_ws, size_t ws_size,
                              hipStream_t stream) {
  (void)in_sizes; (void)n_in; (void)out_size; (void)ws_size;
  const float* x      = (const float*)d_in[0];
  const float* bank   = (const float*)d_in[1];
  const float* w_net  = (const float*)d_in[2];
  const float* b_net  = (const float*)d_in[3];
  const float* attn_w = (const float*)d_in[4];
  const float* attn_b = (const float*)d_in[5];
  const float* a_hw = (const float*)d_in[6];
  const float* a_hb = (const float*)d_in[7];
  const float* a_ow = (const float*)d_in[8];
  const float* a_ob = (const float*)d_in[9];
  const float* t_hw = (const float*)d_in[10];
  const float* t_hb = (const float*)d_in[11];
  const float* t_ow = (const float*)d_in[12];
  const float* t_ob = (const float*)d_in[13];
  const float* m_hw = (const float*)d_in[14];
  const float* m_hb = (const float*)d_in[15];
  const float* m_ow = (const float*)d_in[16];
  const float* m_ob = (const float*)d_in[17];
  const float* atoms_dict    = (const float*)d_in[18];
  const float* transfer_dict = (const float*)d_in[19];
  const float* rooms  = (const float*)d_in[20];
  const float* room_w = (const float*)d_in[21];
  const float* room_b = (const float*)d_in[22];
  const float* mix_w  = (const float*)d_in[23];
  const float* mix_b  = (const float*)d_in[24];
  float* out = (float*)d_out;

  // ---- workspace layout (~202 MB):
  //  H   @ 0          : 33,554,432 floats  [B,C,T] (front out + final acts)
  //  t1  @ 33,554,432 :  8,388,608 floats  2-batch ping
  //  t2  @ 41,943,040 :  8,388,608 floats  2-batch pong
  //  whi @ 50,331,648 :  245,760 f16 (122,880 floats)
  //  wlo @ 50,454,528 :  245,760 f16
  //  post-conv scratch aliases t1/t2 (dead after conv; stream-ordered).
  float* ws = (float*)d_ws;
  float* H  = ws;
  float* t1 = ws + (size_t)33554432;
  float* t2 = ws + (size_t)41943040;
  _Float16* whi = (_Float16*)(ws + (size_t)50331648);
  _Float16* wlo = (_Float16*)(ws + (size_t)50454528);

  size_t off = 33554432;                            // scratch base (aliases t1)
  double* sums = (double*)(ws + off); off += 32;
  float* attn  = ws + off; off += (size_t)NBATCH*TSAMP;
  float* scal  = ws + off; off += 8;
  float* ctx   = ws + off; off += NBATCH*CCH;
  float* vals  = ws + off; off += NROWS;
  int*   idxs  = (int*)(ws + off); off += NROWS;
  float* p_atoms = ws + off; off += (size_t)NROWS*NATOMS;
  float* p_trans = ws + off; off += (size_t)NROWS*NTRANS;
  float* amps  = ws + off; off += NROWS;
  float* av    = ws + off; off += (size_t)NROWS*ASIZE;
  float* trans = ws + off; off += (size_t)NROWS*TSIZE;
  float* ev    = ws + off; off += (size_t)NROWS*TSIZE;
  float* dry   = ws + off; off += TSAMP;
  float* roomp = ws + off; off += 64;
  float* mix   = ws + off; off += 8;
  float* impulse = ws + off; off += (size_t)NBATCH*TSAMP;
  float* wet   = ws + off; off += (size_t)NBATCH*TSAMP;
  float* cand_v = ws + off; off += 2048;
  int*   cand_i = (int*)(ws + off); off += 2048;
  // scratch ends ~38.9M floats < 50.33M (whi) — disjoint from weights.

  k_wsplit<<<960, 256, 0, stream>>>(w_net, whi, wlo);
  k_front<<<dim3(16, 8, 8), 256, 0, stream>>>(x, bank, H);

  const int dil[5] = {1, 3, 9, 27, 1};
  const size_t S = (size_t)CCH * TSAMP;
  for (int p = 0; p < 4; ++p) {            // 2 batches per dispatch
    float* Hp = H + (size_t)(2*p) * S;
    float* io[6] = {Hp, t1, t2, t1, t2, Hp};
    for (int i = 0; i < 5; ++i) {
      const int d = dil[i];
      const size_t smem = (size_t)(64 + 2*d) * 544;  // 2 arrays x [twin][136] f16
      k_dil_mfma<<<dim3(512, 2), 256, smem, stream>>>(
          io[i], whi + (size_t)i*49152, wlo + (size_t)i*49152, b_net + i*CCH,
          io[i+1], d);
    }
  }

  k_zero<<<1024, 256, 0, stream>>>(wet, sums);
  k_stats<<<dim3(64, 8), 256, 0, stream>>>(H, sums);
  k_scale<<<1, 64, 0, stream>>>(sums, scal);
  k_context<<<1024, 256, 0, stream>>>(H, scal, ctx);
  k_attn<<<dim3(32, 8), 256, 0, stream>>>(H, scal, attn_w, attn_b, attn);
  k_topk1<<<dim3(8, 8), 256, 0, stream>>>(attn, cand_v, cand_i);
  k_topk2<<<8, 256, 0, stream>>>(cand_v, cand_i, vals, idxs);
  k_mlp<<<256, 128, 0, stream>>>(H, scal, vals, idxs,
                                 a_hw, a_hb, a_ow, a_ob,
                                 t_hw, t_hb, t_ow, t_ob,
                                 m_hw, m_hb, m_ow, m_ob,
                                 p_atoms, p_trans, amps);
  k_atoms_mm<<<256, 256, 0, stream>>>(p_atoms, atoms_dict, av);
  k_trans_mm<<<dim3(4, 256), 256, 0, stream>>>(p_trans, transfer_dict, trans);
  k_ev<<<dim3(8, 256), 256, 0, stream>>>(trans, av, amps, ev);
  k_dry<<<32, 256, 0, stream>>>(ev, idxs, dry);
  k_room<<<1, 64, 0, stream>>>(ctx, room_w, room_b, mix_w, mix_b, roomp, mix);
  k_impulse<<<dim3(32, 8), 256, 0, stream>>>(roomp, rooms, impulse);
  k_wet<<<dim3(32, 8, 8), 256, 0, stream>>>(dry, impulse, wet);
  k_out<<<dim3(32, 8), 256, 0, stream>>>(dry, wet, mix, out);
}

// Round 5
// 2624.398 us; speedup vs baseline: 3.3819x; 1.1863x over previous
//
#include <hip/hip_runtime.h>
#include <math.h>

#define TSAMP 32768
#define CCH 128
#define NBATCH 8
#define NEV 32
#define NROWS 256   // NBATCH*NEV
#define NATOMS 512
#define ASIZE 512
#define NTRANS 64
#define TSIZE 8192

typedef _Float16 f16x8 __attribute__((ext_vector_type(8)));
typedef float f32x4 __attribute__((ext_vector_type(4)));

// ------------------------------------------------------------------
// K0: zero the atomic accumulators (wet buffer + f64 stat sums).
__global__ __launch_bounds__(256) void k_zero(float* __restrict__ wet,
                                              double* __restrict__ sums) {
  int i = blockIdx.x * 256 + threadIdx.x;
  if (i < NBATCH * TSAMP) wet[i] = 0.f;
  if (i < 16) sums[i] = 0.0;
}

// ------------------------------------------------------------------
// Kw: split conv weights into f16 hi/lo in layout [layer][k][o][ci]
__global__ __launch_bounds__(256) void k_wsplit(const float* __restrict__ wn,
                                                _Float16* __restrict__ whi,
                                                _Float16* __restrict__ wlo) {
  const int i = blockIdx.x * 256 + threadIdx.x;   // 5*3*128*128 = 245760
  if (i >= 245760) return;
  const int ci = i & 127;
  int r = i >> 7;
  const int o = r & 127;
  r >>= 7;
  const int k = r % 3;
  const int l = r / 3;
  const float w = wn[(((size_t)l*128 + o)*128 + ci)*3 + k];
  const _Float16 hi = (_Float16)w;
  whi[i] = hi;
  wlo[i] = (_Float16)(w - (float)hi);
}

// Kb: split filter bank into f16 hi/lo, layout [c][k] (unchanged, frag-ready)
__global__ __launch_bounds__(256) void k_bsplit(const float* __restrict__ bank,
                                                _Float16* __restrict__ bhi,
                                                _Float16* __restrict__ blo) {
  const int i = blockIdx.x * 256 + threadIdx.x;   // 128*512 = 65536
  if (i < 65536) {
    const float w = bank[i];
    const _Float16 hi = (_Float16)w;
    bhi[i] = hi;
    blo[i] = (_Float16)(w - (float)hi);
  }
}

// ------------------------------------------------------------------
// K1: front filter bank via split-f16 MFMA.
// h[c,t] = sum_{k<512} x[t+k-256]*bank[c,k]  == GEMM M=c(128) N=t K=512 with
// Toeplitz B[k][n] = xwin[n+k]. B-fragment alignment solved by staging the
// 576-sample x window in 8 phase-shifted LDS copies (copy p: xwin[w] at w-p);
// lane n reads copy n&7 at 16B-aligned offsets. Copy stride 600 f16 -> phase
// bases tile all 32 banks (2-way over 16 lanes = free).
// Block: 128c x 64t, 4 waves, each 32c x 64t = 8 mfma_16x16x32 tiles.
__global__ __launch_bounds__(256) void k_front_mfma(
    const float* __restrict__ x, const _Float16* __restrict__ bhi,
    const _Float16* __restrict__ blo, float* __restrict__ h) {
  __shared__ _Float16 shi[8*600];
  __shared__ _Float16 slo[8*600];
  const int t0 = blockIdx.x * 64;
  const int b  = blockIdx.y;
  const float* xb = x + (size_t)b*TSAMP;
  const int tid = threadIdx.x;

  // stage: flat = p*576 + q ; copy p holds xwin[q+p] at position q
  for (int flat = tid; flat < 8*576; flat += 256) {
    const int p = flat / 576;
    const int q = flat - p*576;
    const int g = t0 - 256 + q + p;
    const float v = (g >= 0 && g < TSAMP) ? xb[g] : 0.f;
    const _Float16 hi = (_Float16)v;
    shi[p*600 + q] = hi;
    slo[p*600 + q] = (_Float16)(v - (float)hi);
  }
  __syncthreads();

  const int wv = tid >> 6;
  const int lane = tid & 63;
  const int n = lane & 15;
  const int quad = lane >> 4;
  const int c0 = wv * 32;
  const int ph = n & 7;           // phase copy
  const int nb = n & 8;           // aligned part of n

  f32x4 acc[2][4];
#pragma unroll
  for (int i = 0; i < 2; ++i)
#pragma unroll
    for (int j = 0; j < 4; ++j) acc[i][j] = (f32x4){0.f,0.f,0.f,0.f};

  for (int kc = 0; kc < 16; ++kc) {
    const int kb = kc*32 + quad*8;
    f16x8 ahi[2], alo[2];
#pragma unroll
    for (int os = 0; os < 2; ++os) {
      const size_t ao = (size_t)(c0 + os*16 + n)*512 + kb;
      ahi[os] = *(const f16x8*)(bhi + ao);
      alo[os] = *(const f16x8*)(blo + ao);
    }
    f16x8 xh[4], xl[4];
#pragma unroll
    for (int ts = 0; ts < 4; ++ts) {
      const int a = ph*600 + ts*16 + nb + kb;   // 16B-aligned (all terms %8==0)
      xh[ts] = *(const f16x8*)(shi + a);
      xl[ts] = *(const f16x8*)(slo + a);
    }
#pragma unroll
    for (int os = 0; os < 2; ++os)
#pragma unroll
      for (int ts = 0; ts < 4; ++ts) {
        acc[os][ts] = __builtin_amdgcn_mfma_f32_16x16x32_f16(ahi[os], xh[ts], acc[os][ts], 0, 0, 0);
        acc[os][ts] = __builtin_amdgcn_mfma_f32_16x16x32_f16(alo[os], xh[ts], acc[os][ts], 0, 0, 0);
        acc[os][ts] = __builtin_amdgcn_mfma_f32_16x16x32_f16(ahi[os], xl[ts], acc[os][ts], 0, 0, 0);
      }
  }

  // epilogue: D col=lane&15 (t), row=quad*4+reg (c)
  float* hb = h + (size_t)b*CCH*TSAMP;
#pragma unroll
  for (int os = 0; os < 2; ++os) {
    const int cb = c0 + os*16 + quad*4;
#pragma unroll
    for (int ts = 0; ts < 4; ++ts) {
      const int t = t0 + ts*16 + n;
#pragma unroll
      for (int r = 0; r < 4; ++r)
        hb[(size_t)(cb + r)*TSAMP + t] = acc[os][ts][r];
    }
  }
}

// ------------------------------------------------------------------
// K2: one residual dilated conv layer, TWO batches per dispatch (blockIdx.y).
__global__ __launch_bounds__(256) void k_dil_mfma(
    const float* __restrict__ hin0, const _Float16* __restrict__ whi,
    const _Float16* __restrict__ wlo, const float* __restrict__ bias,
    float* __restrict__ hout0, const int d) {
  extern __shared__ _Float16 sh[];          // xhi[twin][136] then xlo[twin][136]
  const int twin = 64 + 2*d;
  _Float16* shi = sh;
  _Float16* slo = sh + twin*136;
  const int t0 = blockIdx.x * 64;
  const size_t bs = (size_t)blockIdx.y * CCH * TSAMP;
  const float* __restrict__ hin = hin0 + bs;
  float* __restrict__ hout = hout0 + bs;
  const int tid = threadIdx.x;

  for (int flat = tid; flat < 128*twin; flat += 256) {
    const int ci = flat & 127;
    const int tw = flat >> 7;
    const int g = t0 - d + tw;
    const float v = (g >= 0 && g < TSAMP) ? hin[(size_t)ci*TSAMP + g] : 0.f;
    const _Float16 hi = (_Float16)v;
    shi[tw*136 + ci] = hi;
    slo[tw*136 + ci] = (_Float16)(v - (float)hi);
  }
  __syncthreads();

  const int wv = tid >> 6;
  const int lane = tid & 63;
  const int n = lane & 15;
  const int quad = lane >> 4;
  const int o0 = wv * 32;

  f32x4 acc[2][4];
#pragma unroll
  for (int i = 0; i < 2; ++i)
#pragma unroll
    for (int j = 0; j < 4; ++j) acc[i][j] = (f32x4){0.f,0.f,0.f,0.f};

  for (int k = 0; k < 3; ++k) {
    for (int kc = 0; kc < 4; ++kc) {
      const int cib = kc*32 + quad*8;
      f16x8 ahi[2], alo[2];
#pragma unroll
      for (int os = 0; os < 2; ++os) {
        const size_t wo = ((size_t)k*128 + (o0 + os*16 + n))*128 + cib;
        ahi[os] = *(const f16x8*)(whi + wo);
        alo[os] = *(const f16x8*)(wlo + wo);
      }
      f16x8 bhi[4], blo[4];
#pragma unroll
      for (int ts = 0; ts < 4; ++ts) {
        const int a = (ts*16 + n + k*d)*136 + cib;
        bhi[ts] = *(const f16x8*)(shi + a);
        blo[ts] = *(const f16x8*)(slo + a);
      }
#pragma unroll
      for (int os = 0; os < 2; ++os)
#pragma unroll
        for (int ts = 0; ts < 4; ++ts) {
          acc[os][ts] = __builtin_amdgcn_mfma_f32_16x16x32_f16(ahi[os], bhi[ts], acc[os][ts], 0, 0, 0);
          acc[os][ts] = __builtin_amdgcn_mfma_f32_16x16x32_f16(alo[os], bhi[ts], acc[os][ts], 0, 0, 0);
          acc[os][ts] = __builtin_amdgcn_mfma_f32_16x16x32_f16(ahi[os], blo[ts], acc[os][ts], 0, 0, 0);
        }
    }
  }

#pragma unroll
  for (int os = 0; os < 2; ++os) {
    const int ob = o0 + os*16 + quad*4;
#pragma unroll
    for (int ts = 0; ts < 4; ++ts) {
      const int t = t0 + ts*16 + n;
#pragma unroll
      for (int r = 0; r < 4; ++r) {
        const int o = ob + r;
        float v = acc[os][ts][r] + bias[o];
        v = v > 0.f ? v : 0.2f*v;
        const size_t gi = (size_t)o*TSAMP + t;
        hout[gi] = hin[gi] + v;
      }
    }
  }
}

// ------------------------------------------------------------------
// K3: per-batch sum / sumsq (f64 atomics)
__global__ __launch_bounds__(256) void k_stats(const float* __restrict__ h,
                                               double* __restrict__ sums) {
  const int b = blockIdx.y;
  const float* p = h + (size_t)b*CCH*TSAMP;
  double s = 0.0, s2 = 0.0;
  const size_t n = (size_t)CCH*TSAMP;
  for (size_t i = (size_t)blockIdx.x*256 + threadIdx.x; i < n; i += 64*256) {
    const double v = (double)p[i];
    s += v; s2 += v*v;
  }
  for (int d_ = 32; d_ > 0; d_ >>= 1) { s += __shfl_down(s, d_); s2 += __shfl_down(s2, d_); }
  if ((threadIdx.x & 63) == 0) {
    atomicAdd(&sums[b*2],   s);
    atomicAdd(&sums[b*2+1], s2);
  }
}

// K4: scale[b] = 1/(std_b + 1e-8)
__global__ void k_scale(const double* __restrict__ sums, float* __restrict__ scal) {
  const int b = threadIdx.x;
  if (b < NBATCH) {
    const double n = (double)CCH * (double)TSAMP;
    const double mean = sums[b*2] / n;
    double var = sums[b*2+1] / n - mean*mean;
    if (var < 0.0) var = 0.0;
    scal[b] = (float)(1.0 / (sqrt(var) + 1e-8));
  }
}

// K5: context[b,c] = scale_b * max_t h[b,c,t]
__global__ __launch_bounds__(256) void k_context(const float* __restrict__ h,
                                                 const float* __restrict__ scal,
                                                 float* __restrict__ ctx) {
  const int bc = blockIdx.x;
  const float* p = h + (size_t)bc*TSAMP;
  float m = -3.4e38f;
  for (int i = threadIdx.x; i < TSAMP; i += 256) m = fmaxf(m, p[i]);
  for (int d_ = 32; d_ > 0; d_ >>= 1) m = fmaxf(m, __shfl_down(m, d_));
  __shared__ float wm[4];
  if ((threadIdx.x & 63) == 0) wm[threadIdx.x >> 6] = m;
  __syncthreads();
  if (threadIdx.x == 0) {
    m = fmaxf(fmaxf(wm[0], wm[1]), fmaxf(wm[2], wm[3]));
    ctx[bc] = m * scal[bc >> 7];
  }
}

// K6: attn[b,t] = sigmoid(scale_b * sum_c h[b,c,t]*aw[c] + ab)
__global__ __launch_bounds__(256) void k_attn(const float* __restrict__ h,
                                              const float* __restrict__ scal,
                                              const float* __restrict__ aw,
                                              const float* __restrict__ ab,
                                              float* __restrict__ attn) {
  const int b = blockIdx.y;
  const int t = blockIdx.x*1024 + threadIdx.x*4;
  const float* p = h + (size_t)b*CCH*TSAMP + t;
  float a0=0,a1=0,a2=0,a3=0;
  for (int c = 0; c < CCH; ++c) {
    const float wc = aw[c];
    const float4 v = *(const float4*)(p + (size_t)c*TSAMP);
    a0 += wc*v.x; a1 += wc*v.y; a2 += wc*v.z; a3 += wc*v.w;
  }
  const float s = scal[b], bb = ab[0];
  float* o = attn + (size_t)b*TSAMP + t;
  o[0] = 1.f/(1.f+expf(-(a0*s+bb)));
  o[1] = 1.f/(1.f+expf(-(a1*s+bb)));
  o[2] = 1.f/(1.f+expf(-(a2*s+bb)));
  o[3] = 1.f/(1.f+expf(-(a3*s+bb)));
}

// ------------------------------------------------------------------
// K7a: per-4096-chunk top-32 (LDS-resident, masking argmax).
__global__ __launch_bounds__(256) void k_topk1(const float* __restrict__ attn,
                                               float* __restrict__ cv,
                                               int* __restrict__ cidx) {
  const int ch = blockIdx.x, b = blockIdx.y;
  const float* a = attn + (size_t)b*TSAMP + ch*4096;
  __shared__ float v[4096];
  __shared__ float rv[4]; __shared__ int ri[4];
  const int tid = threadIdx.x;
  for (int i = tid; i < 4096; i += 256) v[i] = a[i];
  __syncthreads();
  for (int e = 0; e < NEV; ++e) {
    float bv = -1e30f; int bi = 0;
    for (int i = tid; i < 4096; i += 256) {
      const float x = v[i];
      if (x > bv) { bv = x; bi = i; }
    }
    for (int s = 32; s; s >>= 1) {
      const float ov = __shfl_down(bv, s); const int oi = __shfl_down(bi, s);
      if (ov > bv || (ov == bv && oi < bi)) { bv = ov; bi = oi; }
    }
    if ((tid & 63) == 0) { rv[tid >> 6] = bv; ri[tid >> 6] = bi; }
    __syncthreads();
    if (tid == 0) {
      int bb = 0;
      for (int w2 = 1; w2 < 4; ++w2)
        if (rv[w2] > rv[bb] || (rv[w2] == rv[bb] && ri[w2] < ri[bb])) bb = w2;
      cv[(b*8 + ch)*NEV + e] = rv[bb];
      cidx[(b*8 + ch)*NEV + e] = ch*4096 + ri[bb];
      v[ri[bb]] = -1e30f;
    }
    __syncthreads();
  }
}

// K7b: final top-32 over 256 candidates
__global__ __launch_bounds__(256) void k_topk2(const float* __restrict__ cv,
                                               const int* __restrict__ ci_,
                                               float* __restrict__ vals,
                                               int* __restrict__ idxs) {
  const int b = blockIdx.x;
  const int tid = threadIdx.x;
  float my = cv[b*256 + tid];
  int   mi = ci_[b*256 + tid];
  __shared__ float rv[4]; __shared__ int ri[4];
  __shared__ float bvs; __shared__ int bis;
  for (int e = 0; e < NEV; ++e) {
    float bv = my; int bi = mi;
    for (int s = 32; s; s >>= 1) {
      const float ov = __shfl_down(bv, s); const int oi = __shfl_down(bi, s);
      if (ov > bv || (ov == bv && oi < bi)) { bv = ov; bi = oi; }
    }
    if ((tid & 63) == 0) { rv[tid >> 6] = bv; ri[tid >> 6] = bi; }
    __syncthreads();
    if (tid == 0) {
      int bb = 0;
      for (int w2 = 1; w2 < 4; ++w2)
        if (rv[w2] > rv[bb] || (rv[w2] == rv[bb] && ri[w2] < ri[bb])) bb = w2;
      vals[b*NEV + e] = rv[bb]; idxs[b*NEV + e] = ri[bb];
      bvs = rv[bb]; bis = ri[bb];
    }
    __syncthreads();
    if (mi == bis && my == bvs) my = -1e30f;
    __syncthreads();
  }
}

// ------------------------------------------------------------------
__device__ __forceinline__ float blk_max128(float v, float* red) {
  const int tid = threadIdx.x;
  red[tid] = v; __syncthreads();
  for (int s = 64; s > 0; s >>= 1) {
    if (tid < s) red[tid] = fmaxf(red[tid], red[tid + s]);
    __syncthreads();
  }
  const float r = red[0]; __syncthreads();
  return r;
}
__device__ __forceinline__ float blk_sum128(float v, float* red) {
  const int tid = threadIdx.x;
  red[tid] = v; __syncthreads();
  for (int s = 64; s > 0; s >>= 1) {
    if (tid < s) red[tid] += red[tid + s];
    __syncthreads();
  }
  const float r = red[0]; __syncthreads();
  return r;
}
__device__ __forceinline__ float mlp_hidden3(float latv, const float* __restrict__ hw,
                                             const float* __restrict__ hb, float* xa) {
  const int tid = threadIdx.x;
  float cur = latv;
  for (int i = 0; i < 3; ++i) {
    xa[tid] = cur; __syncthreads();
    const float* W = hw + (size_t)i*CCH*CCH;
    float acc = hb[i*CCH + tid];
    for (int c = 0; c < CCH; ++c) acc += xa[c] * W[c*CCH + tid];
    cur = acc > 0.f ? acc : 0.2f*acc;
    __syncthreads();
  }
  return cur;
}

// K8: lat + all three MLPs + softmaxes + amps. One 128-thread block per event.
__global__ __launch_bounds__(128) void k_mlp(
    const float* __restrict__ h, const float* __restrict__ scal,
    const float* __restrict__ vals, const int* __restrict__ idxs,
    const float* __restrict__ a_hw, const float* __restrict__ a_hb,
    const float* __restrict__ a_ow, const float* __restrict__ a_ob,
    const float* __restrict__ t_hw, const float* __restrict__ t_hb,
    const float* __restrict__ t_ow, const float* __restrict__ t_ob,
    const float* __restrict__ m_hw, const float* __restrict__ m_hb,
    const float* __restrict__ m_ow, const float* __restrict__ m_ob,
    float* __restrict__ p_atoms, float* __restrict__ p_trans, float* __restrict__ amps) {
  const int row = blockIdx.x;
  const int b = row >> 5;
  const int tid = threadIdx.x;
  __shared__ float xa[CCH];
  __shared__ float red[CCH];
  const int t = idxs[row];
  const float latv = h[((size_t)(b*CCH + tid))*TSAMP + t] * scal[b] * vals[row];

  {
    const float cur = mlp_hidden3(latv, a_hw, a_hb, xa);
    xa[tid] = cur; __syncthreads();
    float l0 = a_ob[tid], l1 = a_ob[tid+128], l2 = a_ob[tid+256], l3 = a_ob[tid+384];
    for (int c = 0; c < CCH; ++c) {
      const float xv = xa[c];
      const float* W = a_ow + (size_t)c*NATOMS + tid;
      l0 += xv*W[0]; l1 += xv*W[128]; l2 += xv*W[256]; l3 += xv*W[384];
    }
    const float mx = blk_max128(fmaxf(fmaxf(l0,l1), fmaxf(l2,l3)), red);
    const float e0 = expf(l0-mx), e1 = expf(l1-mx), e2 = expf(l2-mx), e3 = expf(l3-mx);
    const float inv = 1.f / blk_sum128(e0+e1+e2+e3, red);
    float* pa = p_atoms + (size_t)row*NATOMS;
    pa[tid] = e0*inv; pa[tid+128] = e1*inv; pa[tid+256] = e2*inv; pa[tid+384] = e3*inv;
  }
  {
    const float cur = mlp_hidden3(latv, t_hw, t_hb, xa);
    xa[tid] = cur; __syncthreads();
    float lg = -3.4e38f;
    if (tid < NTRANS) {
      float acc = t_ob[tid];
      for (int c = 0; c < CCH; ++c) acc += xa[c]*t_ow[c*NTRANS + tid];
      lg = acc;
    }
    const float mt = blk_max128(lg, red);
    const float et = (tid < NTRANS) ? expf(lg - mt) : 0.f;
    const float st = blk_sum128(et, red);
    if (tid < NTRANS) p_trans[(size_t)row*NTRANS + tid] = et/st;
  }
  {
    const float cur = mlp_hidden3(latv, m_hw, m_hb, xa);
    const float s = blk_sum128(cur * m_ow[tid], red);
    if (tid == 0) { const float v = s + m_ob[0]; amps[row] = v*v; }
  }
}

// K9: atoms_vec[row,:] = p_atoms[row] @ atoms_dict (512x512)
__global__ __launch_bounds__(256) void k_atoms_mm(const float* __restrict__ p_atoms,
                                                  const float* __restrict__ dict,
                                                  float* __restrict__ av) {
  const int row = blockIdx.x;
  __shared__ float p[NATOMS];
  for (int i = threadIdx.x; i < NATOMS; i += 256) p[i] = p_atoms[(size_t)row*NATOMS + i];
  __syncthreads();
  const int s0 = threadIdx.x*2;
  float a0=0, a1=0;
  for (int a = 0; a < NATOMS; ++a) {
    const float pa = p[a];
    const float2 dv = *(const float2*)(dict + (size_t)a*ASIZE + s0);
    a0 += pa*dv.x; a1 += pa*dv.y;
  }
  av[(size_t)row*ASIZE + s0] = a0; av[(size_t)row*ASIZE + s0 + 1] = a1;
}

// K10: transfers[row,:] = p_trans[row] @ transfer_dict (64x8192)
__global__ __launch_bounds__(256) void k_trans_mm(const float* __restrict__ p_trans,
                                                   const float* __restrict__ td,
                                                   float* __restrict__ trans) {
  const int row = blockIdx.y;
  const int t = blockIdx.x*2048 + threadIdx.x*8;
  __shared__ float p[NTRANS];
  if (threadIdx.x < NTRANS) p[threadIdx.x] = p_trans[(size_t)row*NTRANS + threadIdx.x];
  __syncthreads();
  float a0=0,a1=0,a2=0,a3=0,a4=0,a5=0,a6=0,a7=0;
  for (int j = 0; j < NTRANS; ++j) {
    const float pj = p[j];
    const float4 v0 = *(const float4*)(td + (size_t)j*TSIZE + t);
    const float4 v1 = *(const float4*)(td + (size_t)j*TSIZE + t + 4);
    a0 += pj*v0.x; a1 += pj*v0.y; a2 += pj*v0.z; a3 += pj*v0.w;
    a4 += pj*v1.x; a5 += pj*v1.y; a6 += pj*v1.z; a7 += pj*v1.w;
  }
  float* o = trans + (size_t)row*TSIZE + t;
  o[0]=a0; o[1]=a1; o[2]=a2; o[3]=a3; o[4]=a4; o[5]=a5; o[6]=a6; o[7]=a7;
}

// K11: ev[row,n] = (sum_{k<512} atoms[row,k]*transfers[row,n-k] + atoms_pad) * amp
__global__ __launch_bounds__(256) void k_ev(const float* __restrict__ trans,
                                            const float* __restrict__ av,
                                            const float* __restrict__ amps,
                                            float* __restrict__ ev) {
  const int row = blockIdx.y;
  const int t0 = blockIdx.x * 1024;
  __shared__ float al[512];
  __shared__ float tw[1536];
  for (int i = threadIdx.x; i < 512; i += 256) al[i] = av[(size_t)row*ASIZE + i];
  for (int i = threadIdx.x; i < 1536; i += 256) {
    const int g = t0 - 512 + i;
    tw[i] = (g >= 0) ? trans[(size_t)row*TSIZE + g] : 0.f;
  }
  __syncthreads();
  const int base = threadIdx.x*4 + 512;
  float a0=0,a1=0,a2=0,a3=0;
  float w0=tw[base], w1=tw[base+1], w2=tw[base+2], w3=tw[base+3];
#pragma unroll 8
  for (int k = 0; k < 512; ++k) {
    const float ak = al[k];
    a0 += ak*w0; a1 += ak*w1; a2 += ak*w2; a3 += ak*w3;
    w3 = w2; w2 = w1; w1 = w0; w0 = tw[base - k - 1];
  }
  const int n = t0 + threadIdx.x*4;
  const float amp = amps[row];
  float* e = ev + (size_t)row*TSIZE + n;
  e[0] = (a0 + (n+0 < 512 ? al[n+0] : 0.f)) * amp;
  e[1] = (a1 + (n+1 < 512 ? al[n+1] : 0.f)) * amp;
  e[2] = (a2 + (n+2 < 512 ? al[n+2] : 0.f)) * amp;
  e[3] = (a3 + (n+3 < 512 ? al[n+3] : 0.f)) * amp;
}

// K12: overlap-add gather (deterministic).
__global__ __launch_bounds__(256) void k_dry(const float* __restrict__ ev,
                                             const int* __restrict__ idxs,
                                             float* __restrict__ dry) {
  __shared__ int sidx[NROWS];
  for (int i = threadIdx.x; i < NROWS; i += 256) sidx[i] = idxs[i];
  __syncthreads();
  const int p = blockIdx.x*1024 + threadIdx.x*4;
  float a0=0,a1=0,a2=0,a3=0;
  for (int r = 0; r < NROWS; ++r) {
    const int off = p - sidx[r];
    if (off >= -3 && off < TSIZE) {
      const float* er = ev + (size_t)r*TSIZE;
      if ((unsigned)(off  ) < TSIZE) a0 += er[off];
      if ((unsigned)(off+1) < TSIZE) a1 += er[off+1];
      if ((unsigned)(off+2) < TSIZE) a2 += er[off+2];
      if ((unsigned)(off+3) < TSIZE) a3 += er[off+3];
    }
  }
  dry[p] = a0; dry[p+1] = a1; dry[p+2] = a2; dry[p+3] = a3;
}

// K13: room softmax + wet/dry mix scalars
__global__ void k_room(const float* __restrict__ ctx, const float* __restrict__ room_w,
                       const float* __restrict__ room_b, const float* __restrict__ mix_w,
                       const float* __restrict__ mix_b, float* __restrict__ roomp,
                       float* __restrict__ mix) {
  const int b = threadIdx.x >> 3;
  const int r = threadIdx.x & 7;
  float acc = room_b[r];
  for (int c = 0; c < CCH; ++c) acc += ctx[b*CCH + c] * room_w[c*8 + r];
  float m = acc;
  for (int s = 1; s < 8; s <<= 1) m = fmaxf(m, __shfl_xor(m, s, 8));
  const float e = expf(acc - m);
  float ssum = e;
  for (int s = 1; s < 8; s <<= 1) ssum += __shfl_xor(ssum, s, 8);
  roomp[b*8 + r] = e / ssum;
  if (r == 0) {
    float a = mix_b[0];
    for (int c = 0; c < CCH; ++c) a += ctx[b*CCH + c] * mix_w[c];
    mix[b] = 1.f/(1.f+expf(-a));
  }
}

// K14: impulse[b,t] = sum_r roomp[b,r]*rooms[r,t]
__global__ __launch_bounds__(256) void k_impulse(const float* __restrict__ roomp,
                                                 const float* __restrict__ rooms,
                                                 float* __restrict__ impulse) {
  const int b = blockIdx.y;
  const int t = blockIdx.x*1024 + threadIdx.x*4;
  float a0=0,a1=0,a2=0,a3=0;
  for (int r = 0; r < 8; ++r) {
    const float pr = roomp[b*8 + r];
    const float4 v = *(const float4*)(rooms + (size_t)r*TSAMP + t);
    a0 += pr*v.x; a1 += pr*v.y; a2 += pr*v.z; a3 += pr*v.w;
  }
  float* o = impulse + (size_t)b*TSAMP + t;
  o[0]=a0; o[1]=a1; o[2]=a2; o[3]=a3;
}

// K15: triangular reverb conv
__global__ __launch_bounds__(256) void k_wet(const float* __restrict__ dry,
                                             const float* __restrict__ impulse,
                                             float* __restrict__ wet) {
  const int t0 = blockIdx.x * 1024;
  const int kbeg = blockIdx.y * 4096;
  const int b = blockIdx.z;
  if (kbeg > t0 + 1023) return;
  __shared__ float dl[1024];
  __shared__ float il[2048];
  const float* imp = impulse + (size_t)b*TSAMP;
  const int tl = threadIdx.x * 4;
  float a0=0,a1=0,a2=0,a3=0;
  for (int kc = kbeg; kc < kbeg + 4096 && kc <= t0 + 1023; kc += 1024) {
    for (int i = threadIdx.x; i < 1024; i += 256) dl[i] = dry[kc + i];
    const int w0g = t0 - kc - 1024;
    for (int i = threadIdx.x; i < 2048; i += 256) {
      const int g = w0g + i;
      il[i] = (g >= 0) ? imp[g] : 0.f;
    }
    __syncthreads();
    const int base = tl + 1024;
    float w0=il[base], w1=il[base+1], w2=il[base+2], w3=il[base+3];
#pragma unroll 8
    for (int k = 0; k < 1024; ++k) {
      const float dv = dl[k];
      a0 += dv*w0; a1 += dv*w1; a2 += dv*w2; a3 += dv*w3;
      w3 = w2; w2 = w1; w1 = w0; w0 = il[base - k - 1];
    }
    __syncthreads();
  }
  float* wp = wet + (size_t)b*TSAMP + t0 + tl;
  atomicAdd(wp+0, a0); atomicAdd(wp+1, a1);
  atomicAdd(wp+2, a2); atomicAdd(wp+3, a3);
}

// K16: out = dry*(1-mix) + wet*mix
__global__ __launch_bounds__(256) void k_out(const float* __restrict__ dry,
                                             const float* __restrict__ wet,
                                             const float* __restrict__ mix,
                                             float* __restrict__ out) {
  const int b = blockIdx.y;
  const int t = blockIdx.x*1024 + threadIdx.x*4;
  const float m = mix[b];
  const float4 d = *(const float4*)(dry + t);
  const float4 w = *(const float4*)(wet + (size_t)b*TSAMP + t);
  float* o = out + (size_t)b*TSAMP + t;
  o[0] = d.x*(1.f-m) + w.x*m;
  o[1] = d.y*(1.f-m) + w.y*m;
  o[2] = d.z*(1.f-m) + w.z*m;
  o[3] = d.w*(1.f-m) + w.w*m;
}

// ------------------------------------------------------------------
extern "C" void kernel_launch(void* const* d_in, const int* in_sizes, int n_in,
                              void* d_out, int out_size, void* d_ws, size_t ws_size,
                              hipStream_t stream) {
  (void)in_sizes; (void)n_in; (void)out_size; (void)ws_size;
  const float* x      = (const float*)d_in[0];
  const float* bank   = (const float*)d_in[1];
  const float* w_net  = (const float*)d_in[2];
  const float* b_net  = (const float*)d_in[3];
  const float* attn_w = (const float*)d_in[4];
  const float* attn_b = (const float*)d_in[5];
  const float* a_hw = (const float*)d_in[6];
  const float* a_hb = (const float*)d_in[7];
  const float* a_ow = (const float*)d_in[8];
  const float* a_ob = (const float*)d_in[9];
  const float* t_hw = (const float*)d_in[10];
  const float* t_hb = (const float*)d_in[11];
  const float* t_ow = (const float*)d_in[12];
  const float* t_ob = (const float*)d_in[13];
  const float* m_hw = (const float*)d_in[14];
  const float* m_hb = (const float*)d_in[15];
  const float* m_ow = (const float*)d_in[16];
  const float* m_ob = (const float*)d_in[17];
  const float* atoms_dict    = (const float*)d_in[18];
  const float* transfer_dict = (const float*)d_in[19];
  const float* rooms  = (const float*)d_in[20];
  const float* room_w = (const float*)d_in[21];
  const float* room_b = (const float*)d_in[22];
  const float* mix_w  = (const float*)d_in[23];
  const float* mix_b  = (const float*)d_in[24];
  float* out = (float*)d_out;

  // ---- workspace layout (~203 MB):
  //  H   @ 0          : 33,554,432 floats  [B,C,T]
  //  t1  @ 33,554,432 :  8,388,608 floats  2-batch ping
  //  t2  @ 41,943,040 :  8,388,608 floats  2-batch pong
  //  whi @ 50,331,648 : 245,760 f16 ; wlo @ +122,880 floats
  //  bhi @ 50,577,408 :  65,536 f16 ; blo @ +32,768 floats
  //  post-conv scratch aliases t1/t2 (dead after conv; stream-ordered).
  float* ws = (float*)d_ws;
  float* H  = ws;
  float* t1 = ws + (size_t)33554432;
  float* t2 = ws + (size_t)41943040;
  _Float16* whi = (_Float16*)(ws + (size_t)50331648);
  _Float16* wlo = (_Float16*)(ws + (size_t)50454528);
  _Float16* bhi = (_Float16*)(ws + (size_t)50577408);
  _Float16* blo = (_Float16*)(ws + (size_t)50610176);

  size_t off = 33554432;                            // scratch base (aliases t1)
  double* sums = (double*)(ws + off); off += 32;
  float* attn  = ws + off; off += (size_t)NBATCH*TSAMP;
  float* scal  = ws + off; off += 8;
  float* ctx   = ws + off; off += NBATCH*CCH;
  float* vals  = ws + off; off += NROWS;
  int*   idxs  = (int*)(ws + off); off += NROWS;
  float* p_atoms = ws + off; off += (size_t)NROWS*NATOMS;
  float* p_trans = ws + off; off += (size_t)NROWS*NTRANS;
  float* amps  = ws + off; off += NROWS;
  float* av    = ws + off; off += (size_t)NROWS*ASIZE;
  float* trans = ws + off; off += (size_t)NROWS*TSIZE;
  float* ev    = ws + off; off += (size_t)NROWS*TSIZE;
  float* dry   = ws + off; off += TSAMP;
  float* roomp = ws + off; off += 64;
  float* mix   = ws + off; off += 8;
  float* impulse = ws + off; off += (size_t)NBATCH*TSAMP;
  float* wet   = ws + off; off += (size_t)NBATCH*TSAMP;
  float* cand_v = ws + off; off += 2048;
  int*   cand_i = (int*)(ws + off); off += 2048;
  // scratch ends ~38.9M floats < 50.33M (whi) — disjoint from weights.

  k_wsplit<<<960, 256, 0, stream>>>(w_net, whi, wlo);
  k_bsplit<<<256, 256, 0, stream>>>(bank, bhi, blo);
  k_front_mfma<<<dim3(512, 8), 256, 0, stream>>>(x, bhi, blo, H);

  const int dil[5] = {1, 3, 9, 27, 1};
  const size_t S = (size_t)CCH * TSAMP;
  for (int p = 0; p < 4; ++p) {            // 2 batches per dispatch
    float* Hp = H + (size_t)(2*p) * S;
    float* io[6] = {Hp, t1, t2, t1, t2, Hp};
    for (int i = 0; i < 5; ++i) {
      const int d = dil[i];
      const size_t smem = (size_t)(64 + 2*d) * 544;  // 2 arrays x [twin][136] f16
      k_dil_mfma<<<dim3(512, 2), 256, smem, stream>>>(
          io[i], whi + (size_t)i*49152, wlo + (size_t)i*49152, b_net + i*CCH,
          io[i+1], d);
    }
  }

  k_zero<<<1024, 256, 0, stream>>>(wet, sums);
  k_stats<<<dim3(64, 8), 256, 0, stream>>>(H, sums);
  k_scale<<<1, 64, 0, stream>>>(sums, scal);
  k_context<<<1024, 256, 0, stream>>>(H, scal, ctx);
  k_attn<<<dim3(32, 8), 256, 0, stream>>>(H, scal, attn_w, attn_b, attn);
  k_topk1<<<dim3(8, 8), 256, 0, stream>>>(attn, cand_v, cand_i);
  k_topk2<<<8, 256, 0, stream>>>(cand_v, cand_i, vals, idxs);
  k_mlp<<<256, 128, 0, stream>>>(H, scal, vals, idxs,
                                 a_hw, a_hb, a_ow, a_ob,
                                 t_hw, t_hb, t_ow, t_ob,
                                 m_hw, m_hb, m_ow, m_ob,
                                 p_atoms, p_trans, amps);
  k_atoms_mm<<<256, 256, 0, stream>>>(p_atoms, atoms_dict, av);
  k_trans_mm<<<dim3(4, 256), 256, 0, stream>>>(p_trans, transfer_dict, trans);
  k_ev<<<dim3(8, 256), 256, 0, stream>>>(trans, av, amps, ev);
  k_dry<<<32, 256, 0, stream>>>(ev, idxs, dry);
  k_room<<<1, 64, 0, stream>>>(ctx, room_w, room_b, mix_w, mix_b, roomp, mix);
  k_impulse<<<dim3(32, 8), 256, 0, stream>>>(roomp, rooms, impulse);
  k_wet<<<dim3(32, 8, 8), 256, 0, stream>>>(dry, impulse, wet);
  k_out<<<dim3(32, 8), 256, 0, stream>>>(dry, wet, mix, out);
}

// Round 7
// 2212.532 us; speedup vs baseline: 4.0114x; 1.1862x over previous
//
#include <hip/hip_runtime.h>
#include <math.h>

#define TSAMP 32768
#define CCH 128
#define NBATCH 8
#define NEV 32
#define NROWS 256   // NBATCH*NEV
#define NATOMS 512
#define ASIZE 512
#define NTRANS 64
#define TSIZE 8192

// f16-range scaling for the reverb GEMM: dry ~1e-7 is f16-subnormal, so
// pre-scale dry by 2^24 and impulse by 2^6 (exact), descale acc by 2^-30.
#define DRY_SCALE 16777216.0f            // 2^24
#define IMP_SCALE 64.0f                  // 2^6
#define WET_DESCALE 9.313225746154785e-10f  // 2^-30

typedef _Float16 f16x8 __attribute__((ext_vector_type(8)));
typedef float f32x4 __attribute__((ext_vector_type(4)));

// ------------------------------------------------------------------
// K0: zero the atomic accumulators (wet + dry + f64 stat sums).
__global__ __launch_bounds__(256) void k_zero(float* __restrict__ wet,
                                              float* __restrict__ dry,
                                              double* __restrict__ sums) {
  int i = blockIdx.x * 256 + threadIdx.x;
  if (i < NBATCH * TSAMP) wet[i] = 0.f;
  if (i < TSAMP) dry[i] = 0.f;
  if (i < 16) sums[i] = 0.0;
}

// ------------------------------------------------------------------
// Kw: split conv weights into f16 hi/lo in layout [layer][k][o][ci]
__global__ __launch_bounds__(256) void k_wsplit(const float* __restrict__ wn,
                                                _Float16* __restrict__ whi,
                                                _Float16* __restrict__ wlo) {
  const int i = blockIdx.x * 256 + threadIdx.x;   // 5*3*128*128 = 245760
  if (i >= 245760) return;
  const int ci = i & 127;
  int r = i >> 7;
  const int o = r & 127;
  r >>= 7;
  const int k = r % 3;
  const int l = r / 3;
  const float w = wn[(((size_t)l*128 + o)*128 + ci)*3 + k];
  const _Float16 hi = (_Float16)w;
  whi[i] = hi;
  wlo[i] = (_Float16)(w - (float)hi);
}

// Kb: split filter bank into f16 hi/lo, layout [c][k]
__global__ __launch_bounds__(256) void k_bsplit(const float* __restrict__ bank,
                                                _Float16* __restrict__ bhi,
                                                _Float16* __restrict__ blo) {
  const int i = blockIdx.x * 256 + threadIdx.x;   // 128*512 = 65536
  if (i < 65536) {
    const float w = bank[i];
    const _Float16 hi = (_Float16)w;
    bhi[i] = hi;
    blo[i] = (_Float16)(w - (float)hi);
  }
}

// ------------------------------------------------------------------
// K1: front filter bank via split-f16 MFMA (phase-copy Toeplitz staging).
__global__ __launch_bounds__(256) void k_front_mfma(
    const float* __restrict__ x, const _Float16* __restrict__ bhi,
    const _Float16* __restrict__ blo, float* __restrict__ h) {
  __shared__ _Float16 shi[8*600];
  __shared__ _Float16 slo[8*600];
  const int t0 = blockIdx.x * 64;
  const int b  = blockIdx.y;
  const float* xb = x + (size_t)b*TSAMP;
  const int tid = threadIdx.x;

  for (int flat = tid; flat < 8*576; flat += 256) {
    const int p = flat / 576;
    const int q = flat - p*576;
    const int g = t0 - 256 + q + p;
    const float v = (g >= 0 && g < TSAMP) ? xb[g] : 0.f;
    const _Float16 hi = (_Float16)v;
    shi[p*600 + q] = hi;
    slo[p*600 + q] = (_Float16)(v - (float)hi);
  }
  __syncthreads();

  const int wv = tid >> 6;
  const int lane = tid & 63;
  const int n = lane & 15;
  const int quad = lane >> 4;
  const int c0 = wv * 32;
  const int ph = n & 7;
  const int nb = n & 8;

  f32x4 acc[2][4];
#pragma unroll
  for (int i = 0; i < 2; ++i)
#pragma unroll
    for (int j = 0; j < 4; ++j) acc[i][j] = (f32x4){0.f,0.f,0.f,0.f};

  for (int kc = 0; kc < 16; ++kc) {
    const int kb = kc*32 + quad*8;
    f16x8 ahi[2], alo[2];
#pragma unroll
    for (int os = 0; os < 2; ++os) {
      const size_t ao = (size_t)(c0 + os*16 + n)*512 + kb;
      ahi[os] = *(const f16x8*)(bhi + ao);
      alo[os] = *(const f16x8*)(blo + ao);
    }
    f16x8 xh[4], xl[4];
#pragma unroll
    for (int ts = 0; ts < 4; ++ts) {
      const int a = ph*600 + ts*16 + nb + kb;
      xh[ts] = *(const f16x8*)(shi + a);
      xl[ts] = *(const f16x8*)(slo + a);
    }
#pragma unroll
    for (int os = 0; os < 2; ++os)
#pragma unroll
      for (int ts = 0; ts < 4; ++ts) {
        acc[os][ts] = __builtin_amdgcn_mfma_f32_16x16x32_f16(ahi[os], xh[ts], acc[os][ts], 0, 0, 0);
        acc[os][ts] = __builtin_amdgcn_mfma_f32_16x16x32_f16(alo[os], xh[ts], acc[os][ts], 0, 0, 0);
        acc[os][ts] = __builtin_amdgcn_mfma_f32_16x16x32_f16(ahi[os], xl[ts], acc[os][ts], 0, 0, 0);
      }
  }

  float* hb = h + (size_t)b*CCH*TSAMP;
#pragma unroll
  for (int os = 0; os < 2; ++os) {
    const int cb = c0 + os*16 + quad*4;
#pragma unroll
    for (int ts = 0; ts < 4; ++ts) {
      const int t = t0 + ts*16 + n;
#pragma unroll
      for (int r = 0; r < 4; ++r)
        hb[(size_t)(cb + r)*TSAMP + t] = acc[os][ts][r];
    }
  }
}

// ------------------------------------------------------------------
// K2: one residual dilated conv layer, TWO batches per dispatch (blockIdx.y).
__global__ __launch_bounds__(256) void k_dil_mfma(
    const float* __restrict__ hin0, const _Float16* __restrict__ whi,
    const _Float16* __restrict__ wlo, const float* __restrict__ bias,
    float* __restrict__ hout0, const int d) {
  extern __shared__ _Float16 sh[];          // xhi[twin][136] then xlo[twin][136]
  const int twin = 64 + 2*d;
  _Float16* shi = sh;
  _Float16* slo = sh + twin*136;
  const int t0 = blockIdx.x * 64;
  const size_t bs = (size_t)blockIdx.y * CCH * TSAMP;
  const float* __restrict__ hin = hin0 + bs;
  float* __restrict__ hout = hout0 + bs;
  const int tid = threadIdx.x;

  for (int flat = tid; flat < 128*twin; flat += 256) {
    const int ci = flat & 127;
    const int tw = flat >> 7;
    const int g = t0 - d + tw;
    const float v = (g >= 0 && g < TSAMP) ? hin[(size_t)ci*TSAMP + g] : 0.f;
    const _Float16 hi = (_Float16)v;
    shi[tw*136 + ci] = hi;
    slo[tw*136 + ci] = (_Float16)(v - (float)hi);
  }
  __syncthreads();

  const int wv = tid >> 6;
  const int lane = tid & 63;
  const int n = lane & 15;
  const int quad = lane >> 4;
  const int o0 = wv * 32;

  f32x4 acc[2][4];
#pragma unroll
  for (int i = 0; i < 2; ++i)
#pragma unroll
    for (int j = 0; j < 4; ++j) acc[i][j] = (f32x4){0.f,0.f,0.f,0.f};

  for (int k = 0; k < 3; ++k) {
    for (int kc = 0; kc < 4; ++kc) {
      const int cib = kc*32 + quad*8;
      f16x8 ahi[2], alo[2];
#pragma unroll
      for (int os = 0; os < 2; ++os) {
        const size_t wo = ((size_t)k*128 + (o0 + os*16 + n))*128 + cib;
        ahi[os] = *(const f16x8*)(whi + wo);
        alo[os] = *(const f16x8*)(wlo + wo);
      }
      f16x8 bhi[4], blo[4];
#pragma unroll
      for (int ts = 0; ts < 4; ++ts) {
        const int a = (ts*16 + n + k*d)*136 + cib;
        bhi[ts] = *(const f16x8*)(shi + a);
        blo[ts] = *(const f16x8*)(slo + a);
      }
#pragma unroll
      for (int os = 0; os < 2; ++os)
#pragma unroll
        for (int ts = 0; ts < 4; ++ts) {
          acc[os][ts] = __builtin_amdgcn_mfma_f32_16x16x32_f16(ahi[os], bhi[ts], acc[os][ts], 0, 0, 0);
          acc[os][ts] = __builtin_amdgcn_mfma_f32_16x16x32_f16(alo[os], bhi[ts], acc[os][ts], 0, 0, 0);
          acc[os][ts] = __builtin_amdgcn_mfma_f32_16x16x32_f16(ahi[os], blo[ts], acc[os][ts], 0, 0, 0);
        }
    }
  }

#pragma unroll
  for (int os = 0; os < 2; ++os) {
    const int ob = o0 + os*16 + quad*4;
#pragma unroll
    for (int ts = 0; ts < 4; ++ts) {
      const int t = t0 + ts*16 + n;
#pragma unroll
      for (int r = 0; r < 4; ++r) {
        const int o = ob + r;
        float v = acc[os][ts][r] + bias[o];
        v = v > 0.f ? v : 0.2f*v;
        const size_t gi = (size_t)o*TSAMP + t;
        hout[gi] = hin[gi] + v;
      }
    }
  }
}

// ------------------------------------------------------------------
// K3: per-batch sum / sumsq (f64 atomics)
__global__ __launch_bounds__(256) void k_stats(const float* __restrict__ h,
                                               double* __restrict__ sums) {
  const int b = blockIdx.y;
  const float* p = h + (size_t)b*CCH*TSAMP;
  double s = 0.0, s2 = 0.0;
  const size_t n = (size_t)CCH*TSAMP;
  for (size_t i = (size_t)blockIdx.x*256 + threadIdx.x; i < n; i += 64*256) {
    const double v = (double)p[i];
    s += v; s2 += v*v;
  }
  for (int d_ = 32; d_ > 0; d_ >>= 1) { s += __shfl_down(s, d_); s2 += __shfl_down(s2, d_); }
  if ((threadIdx.x & 63) == 0) {
    atomicAdd(&sums[b*2],   s);
    atomicAdd(&sums[b*2+1], s2);
  }
}

// K4: scale[b] = 1/(std_b + 1e-8)
__global__ void k_scale(const double* __restrict__ sums, float* __restrict__ scal) {
  const int b = threadIdx.x;
  if (b < NBATCH) {
    const double n = (double)CCH * (double)TSAMP;
    const double mean = sums[b*2] / n;
    double var = sums[b*2+1] / n - mean*mean;
    if (var < 0.0) var = 0.0;
    scal[b] = (float)(1.0 / (sqrt(var) + 1e-8));
  }
}

// K5: context[b,c] = scale_b * max_t h[b,c,t]
__global__ __launch_bounds__(256) void k_context(const float* __restrict__ h,
                                                 const float* __restrict__ scal,
                                                 float* __restrict__ ctx) {
  const int bc = blockIdx.x;
  const float* p = h + (size_t)bc*TSAMP;
  float m = -3.4e38f;
  for (int i = threadIdx.x; i < TSAMP; i += 256) m = fmaxf(m, p[i]);
  for (int d_ = 32; d_ > 0; d_ >>= 1) m = fmaxf(m, __shfl_down(m, d_));
  __shared__ float wm[4];
  if ((threadIdx.x & 63) == 0) wm[threadIdx.x >> 6] = m;
  __syncthreads();
  if (threadIdx.x == 0) {
    m = fmaxf(fmaxf(wm[0], wm[1]), fmaxf(wm[2], wm[3]));
    ctx[bc] = m * scal[bc >> 7];
  }
}

// K6: attn[b,t] = sigmoid(scale_b * sum_c h[b,c,t]*aw[c] + ab)
__global__ __launch_bounds__(256) void k_attn(const float* __restrict__ h,
                                              const float* __restrict__ scal,
                                              const float* __restrict__ aw,
                                              const float* __restrict__ ab,
                                              float* __restrict__ attn) {
  const int b = blockIdx.y;
  const int t = blockIdx.x*1024 + threadIdx.x*4;
  const float* p = h + (size_t)b*CCH*TSAMP + t;
  float a0=0,a1=0,a2=0,a3=0;
  for (int c = 0; c < CCH; ++c) {
    const float wc = aw[c];
    const float4 v = *(const float4*)(p + (size_t)c*TSAMP);
    a0 += wc*v.x; a1 += wc*v.y; a2 += wc*v.z; a3 += wc*v.w;
  }
  const float s = scal[b], bb = ab[0];
  float* o = attn + (size_t)b*TSAMP + t;
  o[0] = 1.f/(1.f+expf(-(a0*s+bb)));
  o[1] = 1.f/(1.f+expf(-(a1*s+bb)));
  o[2] = 1.f/(1.f+expf(-(a2*s+bb)));
  o[3] = 1.f/(1.f+expf(-(a3*s+bb)));
}

// ------------------------------------------------------------------
// K7a: per-4096-chunk top-32 (LDS-resident, masking argmax).
__global__ __launch_bounds__(256) void k_topk1(const float* __restrict__ attn,
                                               float* __restrict__ cv,
                                               int* __restrict__ cidx) {
  const int ch = blockIdx.x, b = blockIdx.y;
  const float* a = attn + (size_t)b*TSAMP + ch*4096;
  __shared__ float v[4096];
  __shared__ float rv[4]; __shared__ int ri[4];
  const int tid = threadIdx.x;
  for (int i = tid; i < 4096; i += 256) v[i] = a[i];
  __syncthreads();
  for (int e = 0; e < NEV; ++e) {
    float bv = -1e30f; int bi = 0;
    for (int i = tid; i < 4096; i += 256) {
      const float x = v[i];
      if (x > bv) { bv = x; bi = i; }
    }
    for (int s = 32; s; s >>= 1) {
      const float ov = __shfl_down(bv, s); const int oi = __shfl_down(bi, s);
      if (ov > bv || (ov == bv && oi < bi)) { bv = ov; bi = oi; }
    }
    if ((tid & 63) == 0) { rv[tid >> 6] = bv; ri[tid >> 6] = bi; }
    __syncthreads();
    if (tid == 0) {
      int bb = 0;
      for (int w2 = 1; w2 < 4; ++w2)
        if (rv[w2] > rv[bb] || (rv[w2] == rv[bb] && ri[w2] < ri[bb])) bb = w2;
      cv[(b*8 + ch)*NEV + e] = rv[bb];
      cidx[(b*8 + ch)*NEV + e] = ch*4096 + ri[bb];
      v[ri[bb]] = -1e30f;
    }
    __syncthreads();
  }
}

// K7b: final top-32 over 256 candidates
__global__ __launch_bounds__(256) void k_topk2(const float* __restrict__ cv,
                                               const int* __restrict__ ci_,
                                               float* __restrict__ vals,
                                               int* __restrict__ idxs) {
  const int b = blockIdx.x;
  const int tid = threadIdx.x;
  float my = cv[b*256 + tid];
  int   mi = ci_[b*256 + tid];
  __shared__ float rv[4]; __shared__ int ri[4];
  __shared__ float bvs; __shared__ int bis;
  for (int e = 0; e < NEV; ++e) {
    float bv = my; int bi = mi;
    for (int s = 32; s; s >>= 1) {
      const float ov = __shfl_down(bv, s); const int oi = __shfl_down(bi, s);
      if (ov > bv || (ov == bv && oi < bi)) { bv = ov; bi = oi; }
    }
    if ((tid & 63) == 0) { rv[tid >> 6] = bv; ri[tid >> 6] = bi; }
    __syncthreads();
    if (tid == 0) {
      int bb = 0;
      for (int w2 = 1; w2 < 4; ++w2)
        if (rv[w2] > rv[bb] || (rv[w2] == rv[bb] && ri[w2] < ri[bb])) bb = w2;
      vals[b*NEV + e] = rv[bb]; idxs[b*NEV + e] = ri[bb];
      bvs = rv[bb]; bis = ri[bb];
    }
    __syncthreads();
    if (mi == bis && my == bvs) my = -1e30f;
    __syncthreads();
  }
}

// ------------------------------------------------------------------
__device__ __forceinline__ float blk_max128(float v, float* red) {
  const int tid = threadIdx.x;
  red[tid] = v; __syncthreads();
  for (int s = 64; s > 0; s >>= 1) {
    if (tid < s) red[tid] = fmaxf(red[tid], red[tid + s]);
    __syncthreads();
  }
  const float r = red[0]; __syncthreads();
  return r;
}
__device__ __forceinline__ float blk_sum128(float v, float* red) {
  const int tid = threadIdx.x;
  red[tid] = v; __syncthreads();
  for (int s = 64; s > 0; s >>= 1) {
    if (tid < s) red[tid] += red[tid + s];
    __syncthreads();
  }
  const float r = red[0]; __syncthreads();
  return r;
}
__device__ __forceinline__ float mlp_hidden3(float latv, const float* __restrict__ hw,
                                             const float* __restrict__ hb, float* xa) {
  const int tid = threadIdx.x;
  float cur = latv;
  for (int i = 0; i < 3; ++i) {
    xa[tid] = cur; __syncthreads();
    const float* W = hw + (size_t)i*CCH*CCH;
    float acc = hb[i*CCH + tid];
    for (int c = 0; c < CCH; ++c) acc += xa[c] * W[c*CCH + tid];
    cur = acc > 0.f ? acc : 0.2f*acc;
    __syncthreads();
  }
  return cur;
}

// K8: lat + all three MLPs + softmaxes + amps. One 128-thread block per event.
__global__ __launch_bounds__(128) void k_mlp(
    const float* __restrict__ h, const float* __restrict__ scal,
    const float* __restrict__ vals, const int* __restrict__ idxs,
    const float* __restrict__ a_hw, const float* __restrict__ a_hb,
    const float* __restrict__ a_ow, const float* __restrict__ a_ob,
    const float* __restrict__ t_hw, const float* __restrict__ t_hb,
    const float* __restrict__ t_ow, const float* __restrict__ t_ob,
    const float* __restrict__ m_hw, const float* __restrict__ m_hb,
    const float* __restrict__ m_ow, const float* __restrict__ m_ob,
    float* __restrict__ p_atoms, float* __restrict__ p_trans, float* __restrict__ amps) {
  const int row = blockIdx.x;
  const int b = row >> 5;
  const int tid = threadIdx.x;
  __shared__ float xa[CCH];
  __shared__ float red[CCH];
  const int t = idxs[row];
  const float latv = h[((size_t)(b*CCH + tid))*TSAMP + t] * scal[b] * vals[row];

  {
    const float cur = mlp_hidden3(latv, a_hw, a_hb, xa);
    xa[tid] = cur; __syncthreads();
    float l0 = a_ob[tid], l1 = a_ob[tid+128], l2 = a_ob[tid+256], l3 = a_ob[tid+384];
    for (int c = 0; c < CCH; ++c) {
      const float xv = xa[c];
      const float* W = a_ow + (size_t)c*NATOMS + tid;
      l0 += xv*W[0]; l1 += xv*W[128]; l2 += xv*W[256]; l3 += xv*W[384];
    }
    const float mx = blk_max128(fmaxf(fmaxf(l0,l1), fmaxf(l2,l3)), red);
    const float e0 = expf(l0-mx), e1 = expf(l1-mx), e2 = expf(l2-mx), e3 = expf(l3-mx);
    const float inv = 1.f / blk_sum128(e0+e1+e2+e3, red);
    float* pa = p_atoms + (size_t)row*NATOMS;
    pa[tid] = e0*inv; pa[tid+128] = e1*inv; pa[tid+256] = e2*inv; pa[tid+384] = e3*inv;
  }
  {
    const float cur = mlp_hidden3(latv, t_hw, t_hb, xa);
    xa[tid] = cur; __syncthreads();
    float lg = -3.4e38f;
    if (tid < NTRANS) {
      float acc = t_ob[tid];
      for (int c = 0; c < CCH; ++c) acc += xa[c]*t_ow[c*NTRANS + tid];
      lg = acc;
    }
    const float mt = blk_max128(lg, red);
    const float et = (tid < NTRANS) ? expf(lg - mt) : 0.f;
    const float st = blk_sum128(et, red);
    if (tid < NTRANS) p_trans[(size_t)row*NTRANS + tid] = et/st;
  }
  {
    const float cur = mlp_hidden3(latv, m_hw, m_hb, xa);
    const float s = blk_sum128(cur * m_ow[tid], red);
    if (tid == 0) { const float v = s + m_ob[0]; amps[row] = v*v; }
  }
}

// K9: atoms_vec[row,:] = p_atoms[row] @ atoms_dict (512x512)
__global__ __launch_bounds__(256) void k_atoms_mm(const float* __restrict__ p_atoms,
                                                  const float* __restrict__ dict,
                                                  float* __restrict__ av) {
  const int row = blockIdx.x;
  __shared__ float p[NATOMS];
  for (int i = threadIdx.x; i < NATOMS; i += 256) p[i] = p_atoms[(size_t)row*NATOMS + i];
  __syncthreads();
  const int s0 = threadIdx.x*2;
  float a0=0, a1=0;
  for (int a = 0; a < NATOMS; ++a) {
    const float pa = p[a];
    const float2 dv = *(const float2*)(dict + (size_t)a*ASIZE + s0);
    a0 += pa*dv.x; a1 += pa*dv.y;
  }
  av[(size_t)row*ASIZE + s0] = a0; av[(size_t)row*ASIZE + s0 + 1] = a1;
}

// K10: transfers[row,:] = p_trans[row] @ transfer_dict (64x8192)
__global__ __launch_bounds__(256) void k_trans_mm(const float* __restrict__ p_trans,
                                                   const float* __restrict__ td,
                                                   float* __restrict__ trans) {
  const int row = blockIdx.y;
  const int t = blockIdx.x*2048 + threadIdx.x*8;
  __shared__ float p[NTRANS];
  if (threadIdx.x < NTRANS) p[threadIdx.x] = p_trans[(size_t)row*NTRANS + threadIdx.x];
  __syncthreads();
  float a0=0,a1=0,a2=0,a3=0,a4=0,a5=0,a6=0,a7=0;
  for (int j = 0; j < NTRANS; ++j) {
    const float pj = p[j];
    const float4 v0 = *(const float4*)(td + (size_t)j*TSIZE + t);
    const float4 v1 = *(const float4*)(td + (size_t)j*TSIZE + t + 4);
    a0 += pj*v0.x; a1 += pj*v0.y; a2 += pj*v0.z; a3 += pj*v0.w;
    a4 += pj*v1.x; a5 += pj*v1.y; a6 += pj*v1.z; a7 += pj*v1.w;
  }
  float* o = trans + (size_t)row*TSIZE + t;
  o[0]=a0; o[1]=a1; o[2]=a2; o[3]=a3; o[4]=a4; o[5]=a5; o[6]=a6; o[7]=a7;
}

// K11: ev[row,n] = (sum_{k<512} atoms[row,k]*transfers[row,n-k] + atoms_pad) * amp
__global__ __launch_bounds__(256) void k_ev(const float* __restrict__ trans,
                                            const float* __restrict__ av,
                                            const float* __restrict__ amps,
                                            float* __restrict__ ev) {
  const int row = blockIdx.y;
  const int t0 = blockIdx.x * 1024;
  __shared__ float al[512];
  __shared__ float tw[1536];
  for (int i = threadIdx.x; i < 512; i += 256) al[i] = av[(size_t)row*ASIZE + i];
  for (int i = threadIdx.x; i < 1536; i += 256) {
    const int g = t0 - 512 + i;
    tw[i] = (g >= 0) ? trans[(size_t)row*TSIZE + g] : 0.f;
  }
  __syncthreads();
  const int base = threadIdx.x*4 + 512;
  float a0=0,a1=0,a2=0,a3=0;
  float w0=tw[base], w1=tw[base+1], w2=tw[base+2], w3=tw[base+3];
#pragma unroll 8
  for (int k = 0; k < 512; ++k) {
    const float ak = al[k];
    a0 += ak*w0; a1 += ak*w1; a2 += ak*w2; a3 += ak*w3;
    w3 = w2; w2 = w1; w1 = w0; w0 = tw[base - k - 1];
  }
  const int n = t0 + threadIdx.x*4;
  const float amp = amps[row];
  float* e = ev + (size_t)row*TSIZE + n;
  e[0] = (a0 + (n+0 < 512 ? al[n+0] : 0.f)) * amp;
  e[1] = (a1 + (n+1 < 512 ? al[n+1] : 0.f)) * amp;
  e[2] = (a2 + (n+2 < 512 ? al[n+2] : 0.f)) * amp;
  e[3] = (a3 + (n+3 < 512 ? al[n+3] : 0.f)) * amp;
}

// K12: overlap-add gather, parallel over (t-chunk, row-slab); atomics into dry.
__global__ __launch_bounds__(256) void k_dry(const float* __restrict__ ev,
                                             const int* __restrict__ idxs,
                                             float* __restrict__ dry) {
  __shared__ int sidx[32];
  const int r0 = blockIdx.y * 32;
  if (threadIdx.x < 32) sidx[threadIdx.x] = idxs[r0 + threadIdx.x];
  __syncthreads();
  const int p = blockIdx.x*512 + threadIdx.x*2;
  float a0=0,a1=0;
  for (int r = 0; r < 32; ++r) {
    const int off = p - sidx[r];
    if (off >= -1 && off < TSIZE) {
      const float* er = ev + (size_t)(r0 + r)*TSIZE;
      if ((unsigned)(off  ) < TSIZE) a0 += er[off];
      if ((unsigned)(off+1) < TSIZE) a1 += er[off+1];
    }
  }
  atomicAdd(dry + p,     a0);
  atomicAdd(dry + p + 1, a1);
}

// K12b: split dry into f16 hi/lo, PRE-SCALED by 2^24 (dry ~1e-7 is f16-subnormal)
__global__ __launch_bounds__(256) void k_drysplit(const float* __restrict__ dry,
                                                  _Float16* __restrict__ dhi,
                                                  _Float16* __restrict__ dlo) {
  const int i = blockIdx.x*256 + threadIdx.x;
  if (i < TSAMP) {
    const float v = dry[i] * DRY_SCALE;
    const _Float16 hi = (_Float16)v;
    dhi[i] = hi;
    dlo[i] = (_Float16)(v - (float)hi);
  }
}

// K13: room softmax + wet/dry mix scalars
__global__ void k_room(const float* __restrict__ ctx, const float* __restrict__ room_w,
                       const float* __restrict__ room_b, const float* __restrict__ mix_w,
                       const float* __restrict__ mix_b, float* __restrict__ roomp,
                       float* __restrict__ mix) {
  const int b = threadIdx.x >> 3;
  const int r = threadIdx.x & 7;
  float acc = room_b[r];
  for (int c = 0; c < CCH; ++c) acc += ctx[b*CCH + c] * room_w[c*8 + r];
  float m = acc;
  for (int s = 1; s < 8; s <<= 1) m = fmaxf(m, __shfl_xor(m, s, 8));
  const float e = expf(acc - m);
  float ssum = e;
  for (int s = 1; s < 8; s <<= 1) ssum += __shfl_xor(ssum, s, 8);
  roomp[b*8 + r] = e / ssum;
  if (r == 0) {
    float a = mix_b[0];
    for (int c = 0; c < CCH; ++c) a += ctx[b*CCH + c] * mix_w[c];
    mix[b] = 1.f/(1.f+expf(-a));
  }
}

// K14: impulse[b,t] = sum_r roomp[b,r]*rooms[r,t], emitted as f16 hi/lo,
// PRE-SCALED by 2^6 so the lo residual stays in f16 normal range.
__global__ __launch_bounds__(256) void k_impulse(const float* __restrict__ roomp,
                                                 const float* __restrict__ rooms,
                                                 _Float16* __restrict__ ihi,
                                                 _Float16* __restrict__ ilo) {
  const int b = blockIdx.y;
  const int t = blockIdx.x*1024 + threadIdx.x*4;
  float a0=0,a1=0,a2=0,a3=0;
  for (int r = 0; r < 8; ++r) {
    const float pr = roomp[b*8 + r];
    const float4 v = *(const float4*)(rooms + (size_t)r*TSAMP + t);
    a0 += pr*v.x; a1 += pr*v.y; a2 += pr*v.z; a3 += pr*v.w;
  }
  a0 *= IMP_SCALE; a1 *= IMP_SCALE; a2 *= IMP_SCALE; a3 *= IMP_SCALE;
  _Float16* oh = ihi + (size_t)b*TSAMP + t;
  _Float16* ol = ilo + (size_t)b*TSAMP + t;
  const _Float16 h0=(_Float16)a0, h1=(_Float16)a1, h2=(_Float16)a2, h3=(_Float16)a3;
  oh[0]=h0; oh[1]=h1; oh[2]=h2; oh[3]=h3;
  ol[0]=(_Float16)(a0-(float)h0); ol[1]=(_Float16)(a1-(float)h1);
  ol[2]=(_Float16)(a2-(float)h2); ol[3]=(_Float16)(a3-(float)h3);
}

// K15: reverb conv via split-f16 MFMA (inputs pre-scaled; epilogue descales).
__global__ __launch_bounds__(256) void k_wet_mfma(
    const _Float16* __restrict__ dhi, const _Float16* __restrict__ dlo,
    const _Float16* __restrict__ ihi, const _Float16* __restrict__ ilo,
    float* __restrict__ wet) {
  const int t0 = blockIdx.x * 128;
  const int k0 = blockIdx.y * 8192;
  if (k0 > t0 + 127) return;
  __shared__ _Float16 rhi[8*648];          // phase copies of reversed dry window
  __shared__ _Float16 rlo[8*648];
  const int tid = threadIdx.x;
  const int wv = tid >> 6;
  const int lane = tid & 63;
  const int n16 = lane & 15;
  const int quad = lane >> 4;
  const int m = n16;                       // batch row (0..15, 8 used)

  f32x4 acc[2];
  acc[0] = (f32x4){0.f,0.f,0.f,0.f};
  acc[1] = (f32x4){0.f,0.f,0.f,0.f};

  const int kend = (k0 + 8192 < t0 + 128) ? k0 + 8192 : t0 + 128;
  for (int kc0 = k0; kc0 < kend; kc0 += 512) {
    // stage S_p[q] = R[q+p], R[w] = dry[t0+127-kc0-w], w in [0,640)
    const int D0 = t0 + 127 - kc0;
    for (int flat = tid; flat < 8*640; flat += 256) {
      const int p = flat / 640;
      const int q = flat - p*640;
      const int di = D0 - q - p;
      _Float16 hi = (_Float16)0.f, lo = (_Float16)0.f;
      if (di >= 0 && di < TSAMP) { hi = dhi[di]; lo = dlo[di]; }
      rhi[p*648 + q] = hi;
      rlo[p*648 + q] = lo;
    }
    __syncthreads();

    const int nnbase = wv*32;              // wave's output offset
#pragma unroll 4
    for (int kc = 0; kc < 16; ++kc) {
      const int kb = kc*32;
      const int jg = kc0 + kb + quad*8;    // global j for A fragment
      f16x8 ah, al;
      if (m < NBATCH) {
        const size_t ao = (size_t)m*TSAMP + jg;
        ah = *(const f16x8*)(ihi + ao);
        al = *(const f16x8*)(ilo + ao);
      } else {
        ah = (f16x8){0,0,0,0,0,0,0,0};
        al = (f16x8){0,0,0,0,0,0,0,0};
      }
#pragma unroll
      for (int ts = 0; ts < 2; ++ts) {
        const int nn = nnbase + ts*16 + n16;
        const int ph = 7 - (n16 & 7);
        const int q0 = kb + quad*8 + 120 - (nn & ~7);
        const int a = ph*648 + q0;
        const f16x8 bh = *(const f16x8*)(rhi + a);
        const f16x8 bl = *(const f16x8*)(rlo + a);
        acc[ts] = __builtin_amdgcn_mfma_f32_16x16x32_f16(ah, bh, acc[ts], 0, 0, 0);
        acc[ts] = __builtin_amdgcn_mfma_f32_16x16x32_f16(al, bh, acc[ts], 0, 0, 0);
        acc[ts] = __builtin_amdgcn_mfma_f32_16x16x32_f16(ah, bl, acc[ts], 0, 0, 0);
      }
    }
    __syncthreads();
  }

  // D: col=lane&15 -> n within 16, row=quad*4+r -> batch
#pragma unroll
  for (int ts = 0; ts < 2; ++ts) {
    const int t = t0 + wv*32 + ts*16 + n16;
#pragma unroll
    for (int r = 0; r < 4; ++r) {
      const int b = quad*4 + r;
      if (b < NBATCH)
        atomicAdd(wet + (size_t)b*TSAMP + t, acc[ts][r] * WET_DESCALE);
    }
  }
}

// K16: out = dry*(1-mix) + wet*mix
__global__ __launch_bounds__(256) void k_out(const float* __restrict__ dry,
                                             const float* __restrict__ wet,
                                             const float* __restrict__ mix,
                                             float* __restrict__ out) {
  const int b = blockIdx.y;
  const int t = blockIdx.x*1024 + threadIdx.x*4;
  const float m = mix[b];
  const float4 d = *(const float4*)(dry + t);
  const float4 w = *(const float4*)(wet + (size_t)b*TSAMP + t);
  float* o = out + (size_t)b*TSAMP + t;
  o[0] = d.x*(1.f-m) + w.x*m;
  o[1] = d.y*(1.f-m) + w.y*m;
  o[2] = d.z*(1.f-m) + w.z*m;
  o[3] = d.w*(1.f-m) + w.w*m;
}

// ------------------------------------------------------------------
extern "C" void kernel_launch(void* const* d_in, const int* in_sizes, int n_in,
                              void* d_out, int out_size, void* d_ws, size_t ws_size,
                              hipStream_t stream) {
  (void)in_sizes; (void)n_in; (void)out_size; (void)ws_size;
  const float* x      = (const float*)d_in[0];
  const float* bank   = (const float*)d_in[1];
  const float* w_net  = (const float*)d_in[2];
  const float* b_net  = (const float*)d_in[3];
  const float* attn_w = (const float*)d_in[4];
  const float* attn_b = (const float*)d_in[5];
  const float* a_hw = (const float*)d_in[6];
  const float* a_hb = (const float*)d_in[7];
  const float* a_ow = (const float*)d_in[8];
  const float* a_ob = (const float*)d_in[9];
  const float* t_hw = (const float*)d_in[10];
  const float* t_hb = (const float*)d_in[11];
  const float* t_ow = (const float*)d_in[12];
  const float* t_ob = (const float*)d_in[13];
  const float* m_hw = (const float*)d_in[14];
  const float* m_hb = (const float*)d_in[15];
  const float* m_ow = (const float*)d_in[16];
  const float* m_ob = (const float*)d_in[17];
  const float* atoms_dict    = (const float*)d_in[18];
  const float* transfer_dict = (const float*)d_in[19];
  const float* rooms  = (const float*)d_in[20];
  const float* room_w = (const float*)d_in[21];
  const float* room_b = (const float*)d_in[22];
  const float* mix_w  = (const float*)d_in[23];
  const float* mix_b  = (const float*)d_in[24];
  float* out = (float*)d_out;

  // ---- workspace layout (~203 MB): H | t1 | t2 | weights | scratch aliases t1/t2
  float* ws = (float*)d_ws;
  float* H  = ws;
  float* t1 = ws + (size_t)33554432;
  float* t2 = ws + (size_t)41943040;
  _Float16* whi = (_Float16*)(ws + (size_t)50331648);
  _Float16* wlo = (_Float16*)(ws + (size_t)50454528);
  _Float16* bhi = (_Float16*)(ws + (size_t)50577408);
  _Float16* blo = (_Float16*)(ws + (size_t)50610176);

  size_t off = 33554432;                            // scratch base (aliases t1)
  double* sums = (double*)(ws + off); off += 32;
  float* attn  = ws + off; off += (size_t)NBATCH*TSAMP;
  float* scal  = ws + off; off += 8;
  float* ctx   = ws + off; off += NBATCH*CCH;
  float* vals  = ws + off; off += NROWS;
  int*   idxs  = (int*)(ws + off); off += NROWS;
  float* p_atoms = ws + off; off += (size_t)NROWS*NATOMS;
  float* p_trans = ws + off; off += (size_t)NROWS*NTRANS;
  float* amps  = ws + off; off += NROWS;
  float* av    = ws + off; off += (size_t)NROWS*ASIZE;
  float* trans = ws + off; off += (size_t)NROWS*TSIZE;
  float* ev    = ws + off; off += (size_t)NROWS*TSIZE;
  float* dry   = ws + off; off += TSAMP;
  float* roomp = ws + off; off += 64;
  float* mix   = ws + off; off += 8;
  float* wet   = ws + off; off += (size_t)NBATCH*TSAMP;
  float* cand_v = ws + off; off += 2048;
  int*   cand_i = (int*)(ws + off); off += 2048;
  _Float16* imphi = (_Float16*)(ws + off); off += (size_t)NBATCH*TSAMP/2;
  _Float16* implo = (_Float16*)(ws + off); off += (size_t)NBATCH*TSAMP/2;
  _Float16* dryhi = (_Float16*)(ws + off); off += TSAMP/2;
  _Float16* drylo = (_Float16*)(ws + off); off += TSAMP/2;
  // scratch ends ~39.1M floats < 50.33M (whi) — disjoint from weights.

  k_wsplit<<<960, 256, 0, stream>>>(w_net, whi, wlo);
  k_bsplit<<<256, 256, 0, stream>>>(bank, bhi, blo);
  k_front_mfma<<<dim3(512, 8), 256, 0, stream>>>(x, bhi, blo, H);

  const int dil[5] = {1, 3, 9, 27, 1};
  const size_t S = (size_t)CCH * TSAMP;
  for (int p = 0; p < 4; ++p) {            // 2 batches per dispatch
    float* Hp = H + (size_t)(2*p) * S;
    float* io[6] = {Hp, t1, t2, t1, t2, Hp};
    for (int i = 0; i < 5; ++i) {
      const int d = dil[i];
      const size_t smem = (size_t)(64 + 2*d) * 544;  // 2 arrays x [twin][136] f16
      k_dil_mfma<<<dim3(512, 2), 256, smem, stream>>>(
          io[i], whi + (size_t)i*49152, wlo + (size_t)i*49152, b_net + i*CCH,
          io[i+1], d);
    }
  }

  k_zero<<<1024, 256, 0, stream>>>(wet, dry, sums);
  k_stats<<<dim3(64, 8), 256, 0, stream>>>(H, sums);
  k_scale<<<1, 64, 0, stream>>>(sums, scal);
  k_context<<<1024, 256, 0, stream>>>(H, scal, ctx);
  k_attn<<<dim3(32, 8), 256, 0, stream>>>(H, scal, attn_w, attn_b, attn);
  k_topk1<<<dim3(8, 8), 256, 0, stream>>>(attn, cand_v, cand_i);
  k_topk2<<<8, 256, 0, stream>>>(cand_v, cand_i, vals, idxs);
  k_mlp<<<256, 128, 0, stream>>>(H, scal, vals, idxs,
                                 a_hw, a_hb, a_ow, a_ob,
                                 t_hw, t_hb, t_ow, t_ob,
                                 m_hw, m_hb, m_ow, m_ob,
                                 p_atoms, p_trans, amps);
  k_atoms_mm<<<256, 256, 0, stream>>>(p_atoms, atoms_dict, av);
  k_trans_mm<<<dim3(4, 256), 256, 0, stream>>>(p_trans, transfer_dict, trans);
  k_ev<<<dim3(8, 256), 256, 0, stream>>>(trans, av, amps, ev);
  k_dry<<<dim3(64, 8), 256, 0, stream>>>(ev, idxs, dry);
  k_drysplit<<<128, 256, 0, stream>>>(dry, dryhi, drylo);
  k_room<<<1, 64, 0, stream>>>(ctx, room_w, room_b, mix_w, mix_b, roomp, mix);
  k_impulse<<<dim3(32, 8), 256, 0, stream>>>(roomp, rooms, imphi, implo);
  k_wet_mfma<<<dim3(256, 4), 256, 0, stream>>>(dryhi, drylo, imphi, implo, wet);
  k_out<<<dim3(32, 8), 256, 0, stream>>>(dry, wet, mix, out);
}

// Round 8
// 1482.671 us; speedup vs baseline: 5.9860x; 1.4923x over previous
//
#include <hip/hip_runtime.h>
#include <math.h>

#define TSAMP 32768
#define CCH 128
#define NBATCH 8
#define NEV 32
#define NROWS 256   // NBATCH*NEV
#define NATOMS 512
#define ASIZE 512
#define NTRANS 64
#define TSIZE 8192

// f16-range scaling for the reverb GEMM: dry ~1e-7 is f16-subnormal, so
// pre-scale dry by 2^24 and impulse by 2^6 (exact), descale acc by 2^-30.
#define DRY_SCALE 16777216.0f               // 2^24
#define IMP_SCALE 64.0f                     // 2^6
#define WET_DESCALE 9.313225746154785e-10f  // 2^-30

typedef _Float16 f16x8 __attribute__((ext_vector_type(8)));
typedef _Float16 f16x4 __attribute__((ext_vector_type(4)));
typedef float f32x4 __attribute__((ext_vector_type(4)));

// NOTE: activations H/t1/t2 are stored [B][T][C] (c contiguous) this round —
// conv staging becomes coalesced float4 copies, epilogues become float4 stores.

// ------------------------------------------------------------------
// K0: zero the atomic accumulators (wet + dry + f64 stat sums).
__global__ __launch_bounds__(256) void k_zero(float* __restrict__ wet,
                                              float* __restrict__ dry,
                                              double* __restrict__ sums) {
  int i = blockIdx.x * 256 + threadIdx.x;
  if (i < NBATCH * TSAMP) wet[i] = 0.f;
  if (i < TSAMP) dry[i] = 0.f;
  if (i < 16) sums[i] = 0.0;
}

// ------------------------------------------------------------------
// Kw: split conv weights into f16 hi/lo in layout [layer][k][o][ci]
__global__ __launch_bounds__(256) void k_wsplit(const float* __restrict__ wn,
                                                _Float16* __restrict__ whi,
                                                _Float16* __restrict__ wlo) {
  const int i = blockIdx.x * 256 + threadIdx.x;   // 5*3*128*128 = 245760
  if (i >= 245760) return;
  const int ci = i & 127;
  int r = i >> 7;
  const int o = r & 127;
  r >>= 7;
  const int k = r % 3;
  const int l = r / 3;
  const float w = wn[(((size_t)l*128 + o)*128 + ci)*3 + k];
  const _Float16 hi = (_Float16)w;
  whi[i] = hi;
  wlo[i] = (_Float16)(w - (float)hi);
}

// Kb: split filter bank into f16 hi/lo, layout [c][k]
__global__ __launch_bounds__(256) void k_bsplit(const float* __restrict__ bank,
                                                _Float16* __restrict__ bhi,
                                                _Float16* __restrict__ blo) {
  const int i = blockIdx.x * 256 + threadIdx.x;   // 128*512 = 65536
  if (i < 65536) {
    const float w = bank[i];
    const _Float16 hi = (_Float16)w;
    bhi[i] = hi;
    blo[i] = (_Float16)(w - (float)hi);
  }
}

// ------------------------------------------------------------------
// K1: front filter bank via split-f16 MFMA (phase-copy Toeplitz staging).
// Output layout [T][C]: D tile stores as float4 rows.
__global__ __launch_bounds__(256) void k_front_mfma(
    const float* __restrict__ x, const _Float16* __restrict__ bhi,
    const _Float16* __restrict__ blo, float* __restrict__ h) {
  __shared__ _Float16 shi[8*600];
  __shared__ _Float16 slo[8*600];
  const int t0 = blockIdx.x * 64;
  const int b  = blockIdx.y;
  const float* xb = x + (size_t)b*TSAMP;
  const int tid = threadIdx.x;

  for (int flat = tid; flat < 8*576; flat += 256) {
    const int p = flat / 576;
    const int q = flat - p*576;
    const int g = t0 - 256 + q + p;
    const float v = (g >= 0 && g < TSAMP) ? xb[g] : 0.f;
    const _Float16 hi = (_Float16)v;
    shi[p*600 + q] = hi;
    slo[p*600 + q] = (_Float16)(v - (float)hi);
  }
  __syncthreads();

  const int wv = tid >> 6;
  const int lane = tid & 63;
  const int n = lane & 15;
  const int quad = lane >> 4;
  const int c0 = wv * 32;
  const int ph = n & 7;
  const int nb = n & 8;

  f32x4 acc[2][4];
#pragma unroll
  for (int i = 0; i < 2; ++i)
#pragma unroll
    for (int j = 0; j < 4; ++j) acc[i][j] = (f32x4){0.f,0.f,0.f,0.f};

  for (int kc = 0; kc < 16; ++kc) {
    const int kb = kc*32 + quad*8;
    f16x8 ahi[2], alo[2];
#pragma unroll
    for (int os = 0; os < 2; ++os) {
      const size_t ao = (size_t)(c0 + os*16 + n)*512 + kb;
      ahi[os] = *(const f16x8*)(bhi + ao);
      alo[os] = *(const f16x8*)(blo + ao);
    }
    f16x8 xh[4], xl[4];
#pragma unroll
    for (int ts = 0; ts < 4; ++ts) {
      const int a = ph*600 + ts*16 + nb + kb;
      xh[ts] = *(const f16x8*)(shi + a);
      xl[ts] = *(const f16x8*)(slo + a);
    }
#pragma unroll
    for (int os = 0; os < 2; ++os)
#pragma unroll
      for (int ts = 0; ts < 4; ++ts) {
        acc[os][ts] = __builtin_amdgcn_mfma_f32_16x16x32_f16(ahi[os], xh[ts], acc[os][ts], 0, 0, 0);
        acc[os][ts] = __builtin_amdgcn_mfma_f32_16x16x32_f16(alo[os], xh[ts], acc[os][ts], 0, 0, 0);
        acc[os][ts] = __builtin_amdgcn_mfma_f32_16x16x32_f16(ahi[os], xl[ts], acc[os][ts], 0, 0, 0);
      }
  }

  // epilogue: [T][C] layout — 4 consecutive c per lane = one float4 store
  float* hb = h + (size_t)b*TSAMP*CCH;
#pragma unroll
  for (int os = 0; os < 2; ++os) {
    const int cb = c0 + os*16 + quad*4;
#pragma unroll
    for (int ts = 0; ts < 4; ++ts) {
      const int t = t0 + ts*16 + n;
      *(f32x4*)(hb + (size_t)t*CCH + cb) = acc[os][ts];
    }
  }
}

// ------------------------------------------------------------------
// K2: one residual dilated conv layer, TWO batches per dispatch (blockIdx.y).
// [T][C] layout: staging is a coalesced float4 copy, epilogue float4 stores.
__global__ __launch_bounds__(256) void k_dil_mfma(
    const float* __restrict__ hin0, const _Float16* __restrict__ whi,
    const _Float16* __restrict__ wlo, const float* __restrict__ bias,
    float* __restrict__ hout0, const int d) {
  extern __shared__ _Float16 sh[];          // xhi[twin][136] then xlo[twin][136]
  const int twin = 64 + 2*d;
  _Float16* shi = sh;
  _Float16* slo = sh + twin*136;
  const int t0 = blockIdx.x * 64;
  const size_t bs = (size_t)blockIdx.y * CCH * TSAMP;
  const float* __restrict__ hin = hin0 + bs;
  float* __restrict__ hout = hout0 + bs;
  const int tid = threadIdx.x;

  // stage: coalesced float4 global reads, conflict-free packed LDS writes
  for (int flat = tid; flat < twin*32; flat += 256) {
    const int tw = flat >> 5;
    const int c4 = (flat & 31) << 2;
    const int g = t0 - d + tw;
    float4 v = {0.f, 0.f, 0.f, 0.f};
    if (g >= 0 && g < TSAMP) v = *(const float4*)(hin + (size_t)g*CCH + c4);
    f16x4 hv, lv;
    hv[0] = (_Float16)v.x; hv[1] = (_Float16)v.y;
    hv[2] = (_Float16)v.z; hv[3] = (_Float16)v.w;
    lv[0] = (_Float16)(v.x - (float)hv[0]); lv[1] = (_Float16)(v.y - (float)hv[1]);
    lv[2] = (_Float16)(v.z - (float)hv[2]); lv[3] = (_Float16)(v.w - (float)hv[3]);
    *(f16x4*)(shi + tw*136 + c4) = hv;
    *(f16x4*)(slo + tw*136 + c4) = lv;
  }
  __syncthreads();

  const int wv = tid >> 6;
  const int lane = tid & 63;
  const int n = lane & 15;
  const int quad = lane >> 4;
  const int o0 = wv * 32;

  f32x4 acc[2][4];
#pragma unroll
  for (int i = 0; i < 2; ++i)
#pragma unroll
    for (int j = 0; j < 4; ++j) acc[i][j] = (f32x4){0.f,0.f,0.f,0.f};

  for (int k = 0; k < 3; ++k) {
    for (int kc = 0; kc < 4; ++kc) {
      const int cib = kc*32 + quad*8;
      f16x8 ahi[2], alo[2];
#pragma unroll
      for (int os = 0; os < 2; ++os) {
        const size_t wo = ((size_t)k*128 + (o0 + os*16 + n))*128 + cib;
        ahi[os] = *(const f16x8*)(whi + wo);
        alo[os] = *(const f16x8*)(wlo + wo);
      }
      f16x8 bhi[4], blo[4];
#pragma unroll
      for (int ts = 0; ts < 4; ++ts) {
        const int a = (ts*16 + n + k*d)*136 + cib;
        bhi[ts] = *(const f16x8*)(shi + a);
        blo[ts] = *(const f16x8*)(slo + a);
      }
#pragma unroll
      for (int os = 0; os < 2; ++os)
#pragma unroll
        for (int ts = 0; ts < 4; ++ts) {
          acc[os][ts] = __builtin_amdgcn_mfma_f32_16x16x32_f16(ahi[os], bhi[ts], acc[os][ts], 0, 0, 0);
          acc[os][ts] = __builtin_amdgcn_mfma_f32_16x16x32_f16(alo[os], bhi[ts], acc[os][ts], 0, 0, 0);
          acc[os][ts] = __builtin_amdgcn_mfma_f32_16x16x32_f16(ahi[os], blo[ts], acc[os][ts], 0, 0, 0);
        }
    }
  }

#pragma unroll
  for (int os = 0; os < 2; ++os) {
    const int ob = o0 + os*16 + quad*4;
    const f32x4 bs4 = *(const f32x4*)(bias + ob);
#pragma unroll
    for (int ts = 0; ts < 4; ++ts) {
      const int t = t0 + ts*16 + n;
      const size_t gi = (size_t)t*CCH + ob;
      const f32x4 prev = *(const f32x4*)(hin + gi);
      f32x4 res;
#pragma unroll
      for (int r = 0; r < 4; ++r) {
        float v = acc[os][ts][r] + bs4[r];
        v = v > 0.f ? v : 0.2f*v;
        res[r] = prev[r] + v;
      }
      *(f32x4*)(hout + gi) = res;
    }
  }
}

// ------------------------------------------------------------------
// K3-fused: one pass over H computing (a) f64 sum/sumsq, (b) raw attn logits,
// (c) per-(b,c) max partials. [T][C] layout: fully coalesced.
__global__ __launch_bounds__(256) void k_fuse(const float* __restrict__ h,
                                              const float* __restrict__ aw,
                                              double* __restrict__ sums,
                                              float* __restrict__ attnraw,
                                              float* __restrict__ pm) {
  const int b = blockIdx.y, slice = blockIdx.x;   // 64 slices of 512 t
  const int tid = threadIdx.x;
  const int lane = tid & 31;
  const int sub = tid >> 5;                       // 8 row-groups
  const float4 aw4 = *(const float4*)(aw + lane*4);
  const float* hb = h + ((size_t)b*TSAMP + (size_t)slice*512)*CCH;
  double s = 0.0, s2 = 0.0;
  float c0=-3.4e38f, c1=-3.4e38f, c2=-3.4e38f, c3=-3.4e38f;
  for (int r = 0; r < 64; ++r) {
    const int t = sub*64 + r;
    const float4 v = *(const float4*)(hb + (size_t)t*CCH + lane*4);
    s  += (double)v.x + (double)v.y + (double)v.z + (double)v.w;
    s2 += (double)v.x*v.x + (double)v.y*v.y + (double)v.z*v.z + (double)v.w*v.w;
    c0 = fmaxf(c0, v.x); c1 = fmaxf(c1, v.y);
    c2 = fmaxf(c2, v.z); c3 = fmaxf(c3, v.w);
    float dot = v.x*aw4.x + v.y*aw4.y + v.z*aw4.z + v.w*aw4.w;
    for (int sft = 16; sft; sft >>= 1) dot += __shfl_down(dot, sft, 32);
    if (lane == 0) attnraw[(size_t)b*TSAMP + slice*512 + t] = dot;
  }
  __shared__ float cl[8*128];
  cl[sub*128 + lane*4 + 0] = c0; cl[sub*128 + lane*4 + 1] = c1;
  cl[sub*128 + lane*4 + 2] = c2; cl[sub*128 + lane*4 + 3] = c3;
  __syncthreads();
  if (tid < 128) {
    float m = cl[tid];
    for (int ss = 1; ss < 8; ++ss) m = fmaxf(m, cl[ss*128 + tid]);
    pm[((size_t)b*64 + slice)*128 + tid] = m;
  }
  for (int sft = 32; sft; sft >>= 1) { s += __shfl_down(s, sft); s2 += __shfl_down(s2, sft); }
  __shared__ double sred[8];
  if ((tid & 63) == 0) { sred[(tid>>6)*2] = s; sred[(tid>>6)*2 + 1] = s2; }
  __syncthreads();
  if (tid == 0) {
    atomicAdd(&sums[b*2],     sred[0]+sred[2]+sred[4]+sred[6]);
    atomicAdd(&sums[b*2+1],   sred[1]+sred[3]+sred[5]+sred[7]);
  }
}

// K4: scale[b] = 1/(std_b + 1e-8)
__global__ void k_scale(const double* __restrict__ sums, float* __restrict__ scal) {
  const int b = threadIdx.x;
  if (b < NBATCH) {
    const double n = (double)CCH * (double)TSAMP;
    const double mean = sums[b*2] / n;
    double var = sums[b*2+1] / n - mean*mean;
    if (var < 0.0) var = 0.0;
    scal[b] = (float)(1.0 / (sqrt(var) + 1e-8));
  }
}

// K5b: finish context from partial maxes
__global__ void k_context2(const float* __restrict__ pm, const float* __restrict__ scal,
                           float* __restrict__ ctx) {
  const int b = blockIdx.x;
  const int c = threadIdx.x;   // 128
  float m = -3.4e38f;
  for (int s = 0; s < 64; ++s) m = fmaxf(m, pm[((size_t)b*64 + s)*128 + c]);
  ctx[b*128 + c] = m * scal[b];
}

// K6b: finish attn = sigmoid(raw*scal + ab)
__global__ __launch_bounds__(256) void k_attn2(const float* __restrict__ raw,
                                               const float* __restrict__ scal,
                                               const float* __restrict__ ab,
                                               float* __restrict__ attn) {
  const int b = blockIdx.y;
  const int i = blockIdx.x*1024 + threadIdx.x*4;
  const float s = scal[b], bb = ab[0];
  const float4 v = *(const float4*)(raw + (size_t)b*TSAMP + i);
  float* o = attn + (size_t)b*TSAMP + i;
  o[0] = 1.f/(1.f+expf(-(v.x*s+bb)));
  o[1] = 1.f/(1.f+expf(-(v.y*s+bb)));
  o[2] = 1.f/(1.f+expf(-(v.z*s+bb)));
  o[3] = 1.f/(1.f+expf(-(v.w*s+bb)));
}

// ------------------------------------------------------------------
// K7a: per-4096-chunk top-32 (LDS-resident, masking argmax).
__global__ __launch_bounds__(256) void k_topk1(const float* __restrict__ attn,
                                               float* __restrict__ cv,
                                               int* __restrict__ cidx) {
  const int ch = blockIdx.x, b = blockIdx.y;
  const float* a = attn + (size_t)b*TSAMP + ch*4096;
  __shared__ float v[4096];
  __shared__ float rv[4]; __shared__ int ri[4];
  const int tid = threadIdx.x;
  for (int i = tid; i < 4096; i += 256) v[i] = a[i];
  __syncthreads();
  for (int e = 0; e < NEV; ++e) {
    float bv = -1e30f; int bi = 0;
    for (int i = tid; i < 4096; i += 256) {
      const float x = v[i];
      if (x > bv) { bv = x; bi = i; }
    }
    for (int s = 32; s; s >>= 1) {
      const float ov = __shfl_down(bv, s); const int oi = __shfl_down(bi, s);
      if (ov > bv || (ov == bv && oi < bi)) { bv = ov; bi = oi; }
    }
    if ((tid & 63) == 0) { rv[tid >> 6] = bv; ri[tid >> 6] = bi; }
    __syncthreads();
    if (tid == 0) {
      int bb = 0;
      for (int w2 = 1; w2 < 4; ++w2)
        if (rv[w2] > rv[bb] || (rv[w2] == rv[bb] && ri[w2] < ri[bb])) bb = w2;
      cv[(b*8 + ch)*NEV + e] = rv[bb];
      cidx[(b*8 + ch)*NEV + e] = ch*4096 + ri[bb];
      v[ri[bb]] = -1e30f;
    }
    __syncthreads();
  }
}

// K7b: final top-32 over 256 candidates
__global__ __launch_bounds__(256) void k_topk2(const float* __restrict__ cv,
                                               const int* __restrict__ ci_,
                                               float* __restrict__ vals,
                                               int* __restrict__ idxs) {
  const int b = blockIdx.x;
  const int tid = threadIdx.x;
  float my = cv[b*256 + tid];
  int   mi = ci_[b*256 + tid];
  __shared__ float rv[4]; __shared__ int ri[4];
  __shared__ float bvs; __shared__ int bis;
  for (int e = 0; e < NEV; ++e) {
    float bv = my; int bi = mi;
    for (int s = 32; s; s >>= 1) {
      const float ov = __shfl_down(bv, s); const int oi = __shfl_down(bi, s);
      if (ov > bv || (ov == bv && oi < bi)) { bv = ov; bi = oi; }
    }
    if ((tid & 63) == 0) { rv[tid >> 6] = bv; ri[tid >> 6] = bi; }
    __syncthreads();
    if (tid == 0) {
      int bb = 0;
      for (int w2 = 1; w2 < 4; ++w2)
        if (rv[w2] > rv[bb] || (rv[w2] == rv[bb] && ri[w2] < ri[bb])) bb = w2;
      vals[b*NEV + e] = rv[bb]; idxs[b*NEV + e] = ri[bb];
      bvs = rv[bb]; bis = ri[bb];
    }
    __syncthreads();
    if (mi == bis && my == bvs) my = -1e30f;
    __syncthreads();
  }
}

// ------------------------------------------------------------------
__device__ __forceinline__ float blk_max128(float v, float* red) {
  const int tid = threadIdx.x;
  red[tid] = v; __syncthreads();
  for (int s = 64; s > 0; s >>= 1) {
    if (tid < s) red[tid] = fmaxf(red[tid], red[tid + s]);
    __syncthreads();
  }
  const float r = red[0]; __syncthreads();
  return r;
}
__device__ __forceinline__ float blk_sum128(float v, float* red) {
  const int tid = threadIdx.x;
  red[tid] = v; __syncthreads();
  for (int s = 64; s > 0; s >>= 1) {
    if (tid < s) red[tid] += red[tid + s];
    __syncthreads();
  }
  const float r = red[0]; __syncthreads();
  return r;
}
__device__ __forceinline__ float mlp_hidden3(float latv, const float* __restrict__ hw,
                                             const float* __restrict__ hb, float* xa) {
  const int tid = threadIdx.x;
  float cur = latv;
  for (int i = 0; i < 3; ++i) {
    xa[tid] = cur; __syncthreads();
    const float* W = hw + (size_t)i*CCH*CCH;
    float acc = hb[i*CCH + tid];
    for (int c = 0; c < CCH; ++c) acc += xa[c] * W[c*CCH + tid];
    cur = acc > 0.f ? acc : 0.2f*acc;
    __syncthreads();
  }
  return cur;
}

// K8: lat + all three MLPs + softmaxes + amps. One 128-thread block per event.
__global__ __launch_bounds__(128) void k_mlp(
    const float* __restrict__ h, const float* __restrict__ scal,
    const float* __restrict__ vals, const int* __restrict__ idxs,
    const float* __restrict__ a_hw, const float* __restrict__ a_hb,
    const float* __restrict__ a_ow, const float* __restrict__ a_ob,
    const float* __restrict__ t_hw, const float* __restrict__ t_hb,
    const float* __restrict__ t_ow, const float* __restrict__ t_ob,
    const float* __restrict__ m_hw, const float* __restrict__ m_hb,
    const float* __restrict__ m_ow, const float* __restrict__ m_ob,
    float* __restrict__ p_atoms, float* __restrict__ p_trans, float* __restrict__ amps) {
  const int row = blockIdx.x;
  const int b = row >> 5;
  const int tid = threadIdx.x;
  __shared__ float xa[CCH];
  __shared__ float red[CCH];
  const int t = idxs[row];
  // [T][C] layout: latent row is contiguous
  const float latv = h[((size_t)b*TSAMP + t)*CCH + tid] * scal[b] * vals[row];

  {
    const float cur = mlp_hidden3(latv, a_hw, a_hb, xa);
    xa[tid] = cur; __syncthreads();
    float l0 = a_ob[tid], l1 = a_ob[tid+128], l2 = a_ob[tid+256], l3 = a_ob[tid+384];
    for (int c = 0; c < CCH; ++c) {
      const float xv = xa[c];
      const float* W = a_ow + (size_t)c*NATOMS + tid;
      l0 += xv*W[0]; l1 += xv*W[128]; l2 += xv*W[256]; l3 += xv*W[384];
    }
    const float mx = blk_max128(fmaxf(fmaxf(l0,l1), fmaxf(l2,l3)), red);
    const float e0 = expf(l0-mx), e1 = expf(l1-mx), e2 = expf(l2-mx), e3 = expf(l3-mx);
    const float inv = 1.f / blk_sum128(e0+e1+e2+e3, red);
    float* pa = p_atoms + (size_t)row*NATOMS;
    pa[tid] = e0*inv; pa[tid+128] = e1*inv; pa[tid+256] = e2*inv; pa[tid+384] = e3*inv;
  }
  {
    const float cur = mlp_hidden3(latv, t_hw, t_hb, xa);
    xa[tid] = cur; __syncthreads();
    float lg = -3.4e38f;
    if (tid < NTRANS) {
      float acc = t_ob[tid];
      for (int c = 0; c < CCH; ++c) acc += xa[c]*t_ow[c*NTRANS + tid];
      lg = acc;
    }
    const float mt = blk_max128(lg, red);
    const float et = (tid < NTRANS) ? expf(lg - mt) : 0.f;
    const float st = blk_sum128(et, red);
    if (tid < NTRANS) p_trans[(size_t)row*NTRANS + tid] = et/st;
  }
  {
    const float cur = mlp_hidden3(latv, m_hw, m_hb, xa);
    const float s = blk_sum128(cur * m_ow[tid], red);
    if (tid == 0) { const float v = s + m_ob[0]; amps[row] = v*v; }
  }
}

// K9: atoms_vec[row,:] = p_atoms[row] @ atoms_dict (512x512)
__global__ __launch_bounds__(256) void k_atoms_mm(const float* __restrict__ p_atoms,
                                                  const float* __restrict__ dict,
                                                  float* __restrict__ av) {
  const int row = blockIdx.x;
  __shared__ float p[NATOMS];
  for (int i = threadIdx.x; i < NATOMS; i += 256) p[i] = p_atoms[(size_t)row*NATOMS + i];
  __syncthreads();
  const int s0 = threadIdx.x*2;
  float a0=0, a1=0;
  for (int a = 0; a < NATOMS; ++a) {
    const float pa = p[a];
    const float2 dv = *(const float2*)(dict + (size_t)a*ASIZE + s0);
    a0 += pa*dv.x; a1 += pa*dv.y;
  }
  av[(size_t)row*ASIZE + s0] = a0; av[(size_t)row*ASIZE + s0 + 1] = a1;
}

// K10: transfers[row,:] = p_trans[row] @ transfer_dict (64x8192)
__global__ __launch_bounds__(256) void k_trans_mm(const float* __restrict__ p_trans,
                                                   const float* __restrict__ td,
                                                   float* __restrict__ trans) {
  const int row = blockIdx.y;
  const int t = blockIdx.x*2048 + threadIdx.x*8;
  __shared__ float p[NTRANS];
  if (threadIdx.x < NTRANS) p[threadIdx.x] = p_trans[(size_t)row*NTRANS + threadIdx.x];
  __syncthreads();
  float a0=0,a1=0,a2=0,a3=0,a4=0,a5=0,a6=0,a7=0;
  for (int j = 0; j < NTRANS; ++j) {
    const float pj = p[j];
    const float4 v0 = *(const float4*)(td + (size_t)j*TSIZE + t);
    const float4 v1 = *(const float4*)(td + (size_t)j*TSIZE + t + 4);
    a0 += pj*v0.x; a1 += pj*v0.y; a2 += pj*v0.z; a3 += pj*v0.w;
    a4 += pj*v1.x; a5 += pj*v1.y; a6 += pj*v1.z; a7 += pj*v1.w;
  }
  float* o = trans + (size_t)row*TSIZE + t;
  o[0]=a0; o[1]=a1; o[2]=a2; o[3]=a3; o[4]=a4; o[5]=a5; o[6]=a6; o[7]=a7;
}

// K11: ev[row,n] = (sum_{k<512} atoms[row,k]*transfers[row,n-k] + atoms_pad) * amp
__global__ __launch_bounds__(256) void k_ev(const float* __restrict__ trans,
                                            const float* __restrict__ av,
                                            const float* __restrict__ amps,
                                            float* __restrict__ ev) {
  const int row = blockIdx.y;
  const int t0 = blockIdx.x * 1024;
  __shared__ float al[512];
  __shared__ float tw[1536];
  for (int i = threadIdx.x; i < 512; i += 256) al[i] = av[(size_t)row*ASIZE + i];
  for (int i = threadIdx.x; i < 1536; i += 256) {
    const int g = t0 - 512 + i;
    tw[i] = (g >= 0) ? trans[(size_t)row*TSIZE + g] : 0.f;
  }
  __syncthreads();
  const int base = threadIdx.x*4 + 512;
  float a0=0,a1=0,a2=0,a3=0;
  float w0=tw[base], w1=tw[base+1], w2=tw[base+2], w3=tw[base+3];
#pragma unroll 8
  for (int k = 0; k < 512; ++k) {
    const float ak = al[k];
    a0 += ak*w0; a1 += ak*w1; a2 += ak*w2; a3 += ak*w3;
    w3 = w2; w2 = w1; w1 = w0; w0 = tw[base - k - 1];
  }
  const int n = t0 + threadIdx.x*4;
  const float amp = amps[row];
  float* e = ev + (size_t)row*TSIZE + n;
  e[0] = (a0 + (n+0 < 512 ? al[n+0] : 0.f)) * amp;
  e[1] = (a1 + (n+1 < 512 ? al[n+1] : 0.f)) * amp;
  e[2] = (a2 + (n+2 < 512 ? al[n+2] : 0.f)) * amp;
  e[3] = (a3 + (n+3 < 512 ? al[n+3] : 0.f)) * amp;
}

// K12: overlap-add gather, parallel over (t-chunk, row-slab); atomics into dry.
__global__ __launch_bounds__(256) void k_dry(const float* __restrict__ ev,
                                             const int* __restrict__ idxs,
                                             float* __restrict__ dry) {
  __shared__ int sidx[32];
  const int r0 = blockIdx.y * 32;
  if (threadIdx.x < 32) sidx[threadIdx.x] = idxs[r0 + threadIdx.x];
  __syncthreads();
  const int p = blockIdx.x*512 + threadIdx.x*2;
  float a0=0,a1=0;
  for (int r = 0; r < 32; ++r) {
    const int off = p - sidx[r];
    if (off >= -1 && off < TSIZE) {
      const float* er = ev + (size_t)(r0 + r)*TSIZE;
      if ((unsigned)(off  ) < TSIZE) a0 += er[off];
      if ((unsigned)(off+1) < TSIZE) a1 += er[off+1];
    }
  }
  atomicAdd(dry + p,     a0);
  atomicAdd(dry + p + 1, a1);
}

// K12b: split dry into f16 hi/lo, PRE-SCALED by 2^24 (dry ~1e-7 is f16-subnormal)
__global__ __launch_bounds__(256) void k_drysplit(const float* __restrict__ dry,
                                                  _Float16* __restrict__ dhi,
                                                  _Float16* __restrict__ dlo) {
  const int i = blockIdx.x*256 + threadIdx.x;
  if (i < TSAMP) {
    const float v = dry[i] * DRY_SCALE;
    const _Float16 hi = (_Float16)v;
    dhi[i] = hi;
    dlo[i] = (_Float16)(v - (float)hi);
  }
}

// K13: room softmax + wet/dry mix scalars
__global__ void k_room(const float* __restrict__ ctx, const float* __restrict__ room_w,
                       const float* __restrict__ room_b, const float* __restrict__ mix_w,
                       const float* __restrict__ mix_b, float* __restrict__ roomp,
                       float* __restrict__ mix) {
  const int b = threadIdx.x >> 3;
  const int r = threadIdx.x & 7;
  float acc = room_b[r];
  for (int c = 0; c < CCH; ++c) acc += ctx[b*CCH + c] * room_w[c*8 + r];
  float m = acc;
  for (int s = 1; s < 8; s <<= 1) m = fmaxf(m, __shfl_xor(m, s, 8));
  const float e = expf(acc - m);
  float ssum = e;
  for (int s = 1; s < 8; s <<= 1) ssum += __shfl_xor(ssum, s, 8);
  roomp[b*8 + r] = e / ssum;
  if (r == 0) {
    float a = mix_b[0];
    for (int c = 0; c < CCH; ++c) a += ctx[b*CCH + c] * mix_w[c];
    mix[b] = 1.f/(1.f+expf(-a));
  }
}

// K14: impulse[b,t] = sum_r roomp[b,r]*rooms[r,t], emitted as f16 hi/lo ×2^6
__global__ __launch_bounds__(256) void k_impulse(const float* __restrict__ roomp,
                                                 const float* __restrict__ rooms,
                                                 _Float16* __restrict__ ihi,
                                                 _Float16* __restrict__ ilo) {
  const int b = blockIdx.y;
  const int t = blockIdx.x*1024 + threadIdx.x*4;
  float a0=0,a1=0,a2=0,a3=0;
  for (int r = 0; r < 8; ++r) {
    const float pr = roomp[b*8 + r];
    const float4 v = *(const float4*)(rooms + (size_t)r*TSAMP + t);
    a0 += pr*v.x; a1 += pr*v.y; a2 += pr*v.z; a3 += pr*v.w;
  }
  a0 *= IMP_SCALE; a1 *= IMP_SCALE; a2 *= IMP_SCALE; a3 *= IMP_SCALE;
  _Float16* oh = ihi + (size_t)b*TSAMP + t;
  _Float16* ol = ilo + (size_t)b*TSAMP + t;
  const _Float16 h0=(_Float16)a0, h1=(_Float16)a1, h2=(_Float16)a2, h3=(_Float16)a3;
  oh[0]=h0; oh[1]=h1; oh[2]=h2; oh[3]=h3;
  ol[0]=(_Float16)(a0-(float)h0); ol[1]=(_Float16)(a1-(float)h1);
  ol[2]=(_Float16)(a2-(float)h2); ol[3]=(_Float16)(a3-(float)h3);
}

// K15: reverb conv via split-f16 MFMA. N=256 per block (4 ts/wave), k-slab 4096:
// half the chunks/barriers of R7, 2x MFMA per staged byte.
__global__ __launch_bounds__(256) void k_wet_mfma(
    const _Float16* __restrict__ dhi, const _Float16* __restrict__ dlo,
    const _Float16* __restrict__ ihi, const _Float16* __restrict__ ilo,
    float* __restrict__ wet) {
  const int t0 = blockIdx.x * 256;
  const int k0 = blockIdx.y * 4096;
  if (k0 > t0 + 255) return;
  __shared__ _Float16 rhi[8*776];          // phase copies of reversed dry window
  __shared__ _Float16 rlo[8*776];
  const int tid = threadIdx.x;
  const int wv = tid >> 6;
  const int lane = tid & 63;
  const int n16 = lane & 15;
  const int quad = lane >> 4;
  const int m = n16;                       // batch row (0..15, 8 used)

  f32x4 acc[4];
#pragma unroll
  for (int j = 0; j < 4; ++j) acc[j] = (f32x4){0.f,0.f,0.f,0.f};

  const int kend = (k0 + 4096 < t0 + 256) ? k0 + 4096 : t0 + 256;
  const int ph = 7 - (n16 & 7);
  for (int kc0 = k0; kc0 < kend; kc0 += 512) {
    // stage S_p[q] = R[q+p], R[w] = dry[t0+255-kc0-w], w in [0,768)
    const int D0 = t0 + 255 - kc0;
    for (int flat = tid; flat < 8*768; flat += 256) {
      const int p = flat / 768;
      const int q = flat - p*768;
      const int di = D0 - q - p;
      _Float16 hi = (_Float16)0.f, lo = (_Float16)0.f;
      if (di >= 0 && di < TSAMP) { hi = dhi[di]; lo = dlo[di]; }
      rhi[p*776 + q] = hi;
      rlo[p*776 + q] = lo;
    }
    __syncthreads();

#pragma unroll 4
    for (int kc = 0; kc < 16; ++kc) {
      const int kb = kc*32;
      const int jg = kc0 + kb + quad*8;    // global j for A fragment (<=32767)
      f16x8 ah, al;
      if (m < NBATCH) {
        const size_t ao = (size_t)m*TSAMP + jg;
        ah = *(const f16x8*)(ihi + ao);
        al = *(const f16x8*)(ilo + ao);
      } else {
        ah = (f16x8){0,0,0,0,0,0,0,0};
        al = (f16x8){0,0,0,0,0,0,0,0};
      }
#pragma unroll
      for (int ts = 0; ts < 4; ++ts) {
        const int nn = wv*64 + ts*16 + n16;
        const int a = ph*776 + kb + quad*8 + 248 - (nn & ~7);
        const f16x8 bh = *(const f16x8*)(rhi + a);
        const f16x8 bl = *(const f16x8*)(rlo + a);
        acc[ts] = __builtin_amdgcn_mfma_f32_16x16x32_f16(ah, bh, acc[ts], 0, 0, 0);
        acc[ts] = __builtin_amdgcn_mfma_f32_16x16x32_f16(al, bh, acc[ts], 0, 0, 0);
        acc[ts] = __builtin_amdgcn_mfma_f32_16x16x32_f16(ah, bl, acc[ts], 0, 0, 0);
      }
    }
    __syncthreads();
  }

  // D: col=lane&15 -> n within 16, row=quad*4+r -> batch
#pragma unroll
  for (int ts = 0; ts < 4; ++ts) {
    const int t = t0 + wv*64 + ts*16 + n16;
#pragma unroll
    for (int r = 0; r < 4; ++r) {
      const int b = quad*4 + r;
      if (b < NBATCH)
        atomicAdd(wet + (size_t)b*TSAMP + t, acc[ts][r] * WET_DESCALE);
    }
  }
}

// K16: out = dry*(1-mix) + wet*mix
__global__ __launch_bounds__(256) void k_out(const float* __restrict__ dry,
                                             const float* __restrict__ wet,
                                             const float* __restrict__ mix,
                                             float* __restrict__ out) {
  const int b = blockIdx.y;
  const int t = blockIdx.x*1024 + threadIdx.x*4;
  const float m = mix[b];
  const float4 d = *(const float4*)(dry + t);
  const float4 w = *(const float4*)(wet + (size_t)b*TSAMP + t);
  float* o = out + (size_t)b*TSAMP + t;
  o[0] = d.x*(1.f-m) + w.x*m;
  o[1] = d.y*(1.f-m) + w.y*m;
  o[2] = d.z*(1.f-m) + w.z*m;
  o[3] = d.w*(1.f-m) + w.w*m;
}

// ------------------------------------------------------------------
extern "C" void kernel_launch(void* const* d_in, const int* in_sizes, int n_in,
                              void* d_out, int out_size, void* d_ws, size_t ws_size,
                              hipStream_t stream) {
  (void)in_sizes; (void)n_in; (void)out_size; (void)ws_size;
  const float* x      = (const float*)d_in[0];
  const float* bank   = (const float*)d_in[1];
  const float* w_net  = (const float*)d_in[2];
  const float* b_net  = (const float*)d_in[3];
  const float* attn_w = (const float*)d_in[4];
  const float* attn_b = (const float*)d_in[5];
  const float* a_hw = (const float*)d_in[6];
  const float* a_hb = (const float*)d_in[7];
  const float* a_ow = (const float*)d_in[8];
  const float* a_ob = (const float*)d_in[9];
  const float* t_hw = (const float*)d_in[10];
  const float* t_hb = (const float*)d_in[11];
  const float* t_ow = (const float*)d_in[12];
  const float* t_ob = (const float*)d_in[13];
  const float* m_hw = (const float*)d_in[14];
  const float* m_hb = (const float*)d_in[15];
  const float* m_ow = (const float*)d_in[16];
  const float* m_ob = (const float*)d_in[17];
  const float* atoms_dict    = (const float*)d_in[18];
  const float* transfer_dict = (const float*)d_in[19];
  const float* rooms  = (const float*)d_in[20];
  const float* room_w = (const float*)d_in[21];
  const float* room_b = (const float*)d_in[22];
  const float* mix_w  = (const float*)d_in[23];
  const float* mix_b  = (const float*)d_in[24];
  float* out = (float*)d_out;

  // ---- workspace layout (~203 MB): H | t1 | t2 | weights | scratch aliases t1/t2
  float* ws = (float*)d_ws;
  float* H  = ws;                                    // [B][T][C]
  float* t1 = ws + (size_t)33554432;
  float* t2 = ws + (size_t)41943040;
  _Float16* whi = (_Float16*)(ws + (size_t)50331648);
  _Float16* wlo = (_Float16*)(ws + (size_t)50454528);
  _Float16* bhi = (_Float16*)(ws + (size_t)50577408);
  _Float16* blo = (_Float16*)(ws + (size_t)50610176);

  size_t off = 33554432;                            // scratch base (aliases t1)
  double* sums = (double*)(ws + off); off += 32;
  float* attn  = ws + off; off += (size_t)NBATCH*TSAMP;
  float* attnraw = ws + off; off += (size_t)NBATCH*TSAMP;
  float* pm    = ws + off; off += (size_t)NBATCH*64*CCH;
  float* scal  = ws + off; off += 8;
  float* ctx   = ws + off; off += NBATCH*CCH;
  float* vals  = ws + off; off += NROWS;
  int*   idxs  = (int*)(ws + off); off += NROWS;
  float* p_atoms = ws + off; off += (size_t)NROWS*NATOMS;
  float* p_trans = ws + off; off += (size_t)NROWS*NTRANS;
  float* amps  = ws + off; off += NROWS;
  float* av    = ws + off; off += (size_t)NROWS*ASIZE;
  float* trans = ws + off; off += (size_t)NROWS*TSIZE;
  float* ev    = ws + off; off += (size_t)NROWS*TSIZE;
  float* dry   = ws + off; off += TSAMP;
  float* roomp = ws + off; off += 64;
  float* mix   = ws + off; off += 8;
  float* wet   = ws + off; off += (size_t)NBATCH*TSAMP;
  float* cand_v = ws + off; off += 2048;
  int*   cand_i = (int*)(ws + off); off += 2048;
  _Float16* imphi = (_Float16*)(ws + off); off += (size_t)NBATCH*TSAMP/2;
  _Float16* implo = (_Float16*)(ws + off); off += (size_t)NBATCH*TSAMP/2;
  _Float16* dryhi = (_Float16*)(ws + off); off += TSAMP/2;
  _Float16* drylo = (_Float16*)(ws + off); off += TSAMP/2;
  // scratch ends ~39.5M floats < 50.33M (whi) — disjoint from weights.

  k_wsplit<<<960, 256, 0, stream>>>(w_net, whi, wlo);
  k_bsplit<<<256, 256, 0, stream>>>(bank, bhi, blo);
  k_front_mfma<<<dim3(512, 8), 256, 0, stream>>>(x, bhi, blo, H);

  const int dil[5] = {1, 3, 9, 27, 1};
  const size_t S = (size_t)CCH * TSAMP;
  for (int p = 0; p < 4; ++p) {            // 2 batches per dispatch
    float* Hp = H + (size_t)(2*p) * S;
    float* io[6] = {Hp, t1, t2, t1, t2, Hp};
    for (int i = 0; i < 5; ++i) {
      const int d = dil[i];
      const size_t smem = (size_t)(64 + 2*d) * 544;  // 2 arrays x [twin][136] f16
      k_dil_mfma<<<dim3(512, 2), 256, smem, stream>>>(
          io[i], whi + (size_t)i*49152, wlo + (size_t)i*49152, b_net + i*CCH,
          io[i+1], d);
    }
  }

  k_zero<<<1024, 256, 0, stream>>>(wet, dry, sums);
  k_fuse<<<dim3(64, 8), 256, 0, stream>>>(H, attn_w, sums, attnraw, pm);
  k_scale<<<1, 64, 0, stream>>>(sums, scal);
  k_context2<<<8, 128, 0, stream>>>(pm, scal, ctx);
  k_attn2<<<dim3(32, 8), 256, 0, stream>>>(attnraw, scal, attn_b, attn);
  k_topk1<<<dim3(8, 8), 256, 0, stream>>>(attn, cand_v, cand_i);
  k_topk2<<<8, 256, 0, stream>>>(cand_v, cand_i, vals, idxs);
  k_mlp<<<256, 128, 0, stream>>>(H, scal, vals, idxs,
                                 a_hw, a_hb, a_ow, a_ob,
                                 t_hw, t_hb, t_ow, t_ob,
                                 m_hw, m_hb, m_ow, m_ob,
                                 p_atoms, p_trans, amps);
  k_atoms_mm<<<256, 256, 0, stream>>>(p_atoms, atoms_dict, av);
  k_trans_mm<<<dim3(4, 256), 256, 0, stream>>>(p_trans, transfer_dict, trans);
  k_ev<<<dim3(8, 256), 256, 0, stream>>>(trans, av, amps, ev);
  k_dry<<<dim3(64, 8), 256, 0, stream>>>(ev, idxs, dry);
  k_drysplit<<<128, 256, 0, stream>>>(dry, dryhi, drylo);
  k_room<<<1, 64, 0, stream>>>(ctx, room_w, room_b, mix_w, mix_b, roomp, mix);
  k_impulse<<<dim3(32, 8), 256, 0, stream>>>(roomp, rooms, imphi, implo);
  k_wet_mfma<<<dim3(128, 8), 256, 0, stream>>>(dryhi, drylo, imphi, implo, wet);
  k_out<<<dim3(32, 8), 256, 0, stream>>>(dry, wet, mix, out);
}

// Round 9
// 1472.202 us; speedup vs baseline: 6.0286x; 1.0071x over previous
//
#include <hip/hip_runtime.h>
#include <math.h>

#define TSAMP 32768
#define CCH 128
#define NBATCH 8
#define NEV 32
#define NROWS 256   // NBATCH*NEV
#define NATOMS 512
#define ASIZE 512
#define NTRANS 64
#define TSIZE 8192

// f16-range scaling for the reverb GEMM: dry ~1e-7 is f16-subnormal, so
// pre-scale dry by 2^24 and impulse by 2^6 (exact), descale acc by 2^-30.
#define DRY_SCALE 16777216.0f               // 2^24
#define IMP_SCALE 64.0f                     // 2^6
#define WET_DESCALE 9.313225746154785e-10f  // 2^-30

typedef _Float16 f16x8 __attribute__((ext_vector_type(8)));
typedef _Float16 f16x4 __attribute__((ext_vector_type(4)));
typedef float f32x4 __attribute__((ext_vector_type(4)));

// activations H/t1/t2 stored [B][T][C] (c contiguous).

// ------------------------------------------------------------------
// K0a: zero f64 stat sums (before conv stack; sums live in non-aliased space)
__global__ void k_zs(double* __restrict__ sums) {
  if (threadIdx.x < 16) sums[threadIdx.x] = 0.0;
}

// K0b: zero wet + dry accumulators (after conv; they alias conv ping-pong)
__global__ __launch_bounds__(256) void k_zero(float* __restrict__ wet,
                                              float* __restrict__ dry) {
  int i = blockIdx.x * 256 + threadIdx.x;
  if (i < NBATCH * TSAMP) wet[i] = 0.f;
  if (i < TSAMP) dry[i] = 0.f;
}

// ------------------------------------------------------------------
// Kw: split conv weights into f16 hi/lo in layout [layer][k][o][ci]
__global__ __launch_bounds__(256) void k_wsplit(const float* __restrict__ wn,
                                                _Float16* __restrict__ whi,
                                                _Float16* __restrict__ wlo) {
  const int i = blockIdx.x * 256 + threadIdx.x;   // 5*3*128*128 = 245760
  if (i >= 245760) return;
  const int ci = i & 127;
  int r = i >> 7;
  const int o = r & 127;
  r >>= 7;
  const int k = r % 3;
  const int l = r / 3;
  const float w = wn[(((size_t)l*128 + o)*128 + ci)*3 + k];
  const _Float16 hi = (_Float16)w;
  whi[i] = hi;
  wlo[i] = (_Float16)(w - (float)hi);
}

// Kb: split filter bank into f16 hi/lo, layout [c][k]
__global__ __launch_bounds__(256) void k_bsplit(const float* __restrict__ bank,
                                                _Float16* __restrict__ bhi,
                                                _Float16* __restrict__ blo) {
  const int i = blockIdx.x * 256 + threadIdx.x;   // 128*512 = 65536
  if (i < 65536) {
    const float w = bank[i];
    const _Float16 hi = (_Float16)w;
    bhi[i] = hi;
    blo[i] = (_Float16)(w - (float)hi);
  }
}

// ------------------------------------------------------------------
// K1: front filter bank via split-f16 MFMA, 128-t blocks (8 ts tiles/wave).
__global__ __launch_bounds__(256) void k_front_mfma(
    const float* __restrict__ x, const _Float16* __restrict__ bhi,
    const _Float16* __restrict__ blo, float* __restrict__ h) {
  __shared__ _Float16 shi[8*664];
  __shared__ _Float16 slo[8*664];
  const int t0 = blockIdx.x * 128;
  const int b  = blockIdx.y;
  const float* xb = x + (size_t)b*TSAMP;
  const int tid = threadIdx.x;

  // stage 8 phase copies of xwin[w] = x[t0-256+w], w in [0,639)
  for (int flat = tid; flat < 8*632; flat += 256) {
    const int p = flat / 632;
    const int q = flat - p*632;
    const int g = t0 - 256 + q + p;
    const float v = (g >= 0 && g < TSAMP) ? xb[g] : 0.f;
    const _Float16 hi = (_Float16)v;
    shi[p*664 + q] = hi;
    slo[p*664 + q] = (_Float16)(v - (float)hi);
  }
  __syncthreads();

  const int wv = tid >> 6;
  const int lane = tid & 63;
  const int n = lane & 15;
  const int quad = lane >> 4;
  const int c0 = wv * 32;
  const int ph = n & 7;
  const int nb = n & 8;

  f32x4 acc[2][8];
#pragma unroll
  for (int i = 0; i < 2; ++i)
#pragma unroll
    for (int j = 0; j < 8; ++j) acc[i][j] = (f32x4){0.f,0.f,0.f,0.f};

  for (int kc = 0; kc < 16; ++kc) {
    const int kb = kc*32 + quad*8;
    f16x8 ahi[2], alo[2];
#pragma unroll
    for (int os = 0; os < 2; ++os) {
      const size_t ao = (size_t)(c0 + os*16 + n)*512 + kb;
      ahi[os] = *(const f16x8*)(bhi + ao);
      alo[os] = *(const f16x8*)(blo + ao);
    }
#pragma unroll
    for (int tg = 0; tg < 2; ++tg) {
      f16x8 xh[4], xl[4];
#pragma unroll
      for (int u = 0; u < 4; ++u) {
        const int a = ph*664 + (tg*4 + u)*16 + nb + kb;
        xh[u] = *(const f16x8*)(shi + a);
        xl[u] = *(const f16x8*)(slo + a);
      }
#pragma unroll
      for (int os = 0; os < 2; ++os)
#pragma unroll
        for (int u = 0; u < 4; ++u) {
          f32x4 a4 = acc[os][tg*4 + u];
          a4 = __builtin_amdgcn_mfma_f32_16x16x32_f16(ahi[os], xh[u], a4, 0, 0, 0);
          a4 = __builtin_amdgcn_mfma_f32_16x16x32_f16(alo[os], xh[u], a4, 0, 0, 0);
          a4 = __builtin_amdgcn_mfma_f32_16x16x32_f16(ahi[os], xl[u], a4, 0, 0, 0);
          acc[os][tg*4 + u] = a4;
        }
    }
  }

  float* hb = h + (size_t)b*TSAMP*CCH;
#pragma unroll
  for (int os = 0; os < 2; ++os) {
    const int cb = c0 + os*16 + quad*4;
#pragma unroll
    for (int ts = 0; ts < 8; ++ts) {
      const int t = t0 + ts*16 + n;
      *(f32x4*)(hb + (size_t)t*CCH + cb) = acc[os][ts];
    }
  }
}

// ------------------------------------------------------------------
// K2: one residual dilated conv layer, TWO batches per dispatch.
// Residual term reconstructed from staged LDS (hi+lo) — no global re-read.
__global__ __launch_bounds__(256) void k_dil_mfma(
    const float* __restrict__ hin0, const _Float16* __restrict__ whi,
    const _Float16* __restrict__ wlo, const float* __restrict__ bias,
    float* __restrict__ hout0, const int d) {
  extern __shared__ _Float16 sh[];          // xhi[twin][136] then xlo[twin][136]
  const int twin = 64 + 2*d;
  _Float16* shi = sh;
  _Float16* slo = sh + twin*136;
  const int t0 = blockIdx.x * 64;
  const size_t bs = (size_t)blockIdx.y * CCH * TSAMP;
  const float* __restrict__ hin = hin0 + bs;
  float* __restrict__ hout = hout0 + bs;
  const int tid = threadIdx.x;

  for (int flat = tid; flat < twin*32; flat += 256) {
    const int tw = flat >> 5;
    const int c4 = (flat & 31) << 2;
    const int g = t0 - d + tw;
    float4 v = {0.f, 0.f, 0.f, 0.f};
    if (g >= 0 && g < TSAMP) v = *(const float4*)(hin + (size_t)g*CCH + c4);
    f16x4 hv, lv;
    hv[0] = (_Float16)v.x; hv[1] = (_Float16)v.y;
    hv[2] = (_Float16)v.z; hv[3] = (_Float16)v.w;
    lv[0] = (_Float16)(v.x - (float)hv[0]); lv[1] = (_Float16)(v.y - (float)hv[1]);
    lv[2] = (_Float16)(v.z - (float)hv[2]); lv[3] = (_Float16)(v.w - (float)hv[3]);
    *(f16x4*)(shi + tw*136 + c4) = hv;
    *(f16x4*)(slo + tw*136 + c4) = lv;
  }
  __syncthreads();

  const int wv = tid >> 6;
  const int lane = tid & 63;
  const int n = lane & 15;
  const int quad = lane >> 4;
  const int o0 = wv * 32;

  f32x4 acc[2][4];
#pragma unroll
  for (int i = 0; i < 2; ++i)
#pragma unroll
    for (int j = 0; j < 4; ++j) acc[i][j] = (f32x4){0.f,0.f,0.f,0.f};

  for (int k = 0; k < 3; ++k) {
    for (int kc = 0; kc < 4; ++kc) {
      const int cib = kc*32 + quad*8;
      f16x8 ahi[2], alo[2];
#pragma unroll
      for (int os = 0; os < 2; ++os) {
        const size_t wo = ((size_t)k*128 + (o0 + os*16 + n))*128 + cib;
        ahi[os] = *(const f16x8*)(whi + wo);
        alo[os] = *(const f16x8*)(wlo + wo);
      }
      f16x8 bhi[4], blo[4];
#pragma unroll
      for (int ts = 0; ts < 4; ++ts) {
        const int a = (ts*16 + n + k*d)*136 + cib;
        bhi[ts] = *(const f16x8*)(shi + a);
        blo[ts] = *(const f16x8*)(slo + a);
      }
#pragma unroll
      for (int os = 0; os < 2; ++os)
#pragma unroll
        for (int ts = 0; ts < 4; ++ts) {
          acc[os][ts] = __builtin_amdgcn_mfma_f32_16x16x32_f16(ahi[os], bhi[ts], acc[os][ts], 0, 0, 0);
          acc[os][ts] = __builtin_amdgcn_mfma_f32_16x16x32_f16(alo[os], bhi[ts], acc[os][ts], 0, 0, 0);
          acc[os][ts] = __builtin_amdgcn_mfma_f32_16x16x32_f16(ahi[os], blo[ts], acc[os][ts], 0, 0, 0);
        }
    }
  }

#pragma unroll
  for (int os = 0; os < 2; ++os) {
    const int ob = o0 + os*16 + quad*4;
    const f32x4 bs4 = *(const f32x4*)(bias + ob);
#pragma unroll
    for (int ts = 0; ts < 4; ++ts) {
      const int t = t0 + ts*16 + n;
      const int tw = ts*16 + n + d;
      const f16x4 phv = *(const f16x4*)(shi + tw*136 + ob);
      const f16x4 plv = *(const f16x4*)(slo + tw*136 + ob);
      f32x4 res;
#pragma unroll
      for (int r = 0; r < 4; ++r) {
        float v = acc[os][ts][r] + bs4[r];
        v = v > 0.f ? v : 0.2f*v;
        res[r] = (float)phv[r] + (float)plv[r] + v;
      }
      *(f32x4*)(hout + (size_t)t*CCH + ob) = res;
    }
  }
}

// ------------------------------------------------------------------
// K2b: LAST dilated layer — same conv, epilogue additionally computes
// f64 sum/sumsq, raw attn logits, and per-c max partials (block owns all C).
__global__ __launch_bounds__(256) void k_dil_last(
    const float* __restrict__ hin0, const _Float16* __restrict__ whi,
    const _Float16* __restrict__ wlo, const float* __restrict__ bias,
    float* __restrict__ hout0, const int d,
    const float* __restrict__ aw, double* __restrict__ sums,
    float* __restrict__ attnraw, float* __restrict__ pm, const int bb0) {
  extern __shared__ _Float16 sh[];
  const int twin = 64 + 2*d;
  _Float16* shi = sh;
  _Float16* slo = sh + twin*136;
  __shared__ float attl[4*64];
  __shared__ double sred[8];
  const int t0 = blockIdx.x * 64;
  const int b = bb0 + blockIdx.y;
  const size_t bs = (size_t)blockIdx.y * CCH * TSAMP;
  const float* __restrict__ hin = hin0 + bs;
  float* __restrict__ hout = hout0 + bs;
  const int tid = threadIdx.x;

  for (int flat = tid; flat < twin*32; flat += 256) {
    const int tw = flat >> 5;
    const int c4 = (flat & 31) << 2;
    const int g = t0 - d + tw;
    float4 v = {0.f, 0.f, 0.f, 0.f};
    if (g >= 0 && g < TSAMP) v = *(const float4*)(hin + (size_t)g*CCH + c4);
    f16x4 hv, lv;
    hv[0] = (_Float16)v.x; hv[1] = (_Float16)v.y;
    hv[2] = (_Float16)v.z; hv[3] = (_Float16)v.w;
    lv[0] = (_Float16)(v.x - (float)hv[0]); lv[1] = (_Float16)(v.y - (float)hv[1]);
    lv[2] = (_Float16)(v.z - (float)hv[2]); lv[3] = (_Float16)(v.w - (float)hv[3]);
    *(f16x4*)(shi + tw*136 + c4) = hv;
    *(f16x4*)(slo + tw*136 + c4) = lv;
  }
  __syncthreads();

  const int wv = tid >> 6;
  const int lane = tid & 63;
  const int n = lane & 15;
  const int quad = lane >> 4;
  const int o0 = wv * 32;

  f32x4 acc[2][4];
#pragma unroll
  for (int i = 0; i < 2; ++i)
#pragma unroll
    for (int j = 0; j < 4; ++j) acc[i][j] = (f32x4){0.f,0.f,0.f,0.f};

  for (int k = 0; k < 3; ++k) {
    for (int kc = 0; kc < 4; ++kc) {
      const int cib = kc*32 + quad*8;
      f16x8 ahi[2], alo[2];
#pragma unroll
      for (int os = 0; os < 2; ++os) {
        const size_t wo = ((size_t)k*128 + (o0 + os*16 + n))*128 + cib;
        ahi[os] = *(const f16x8*)(whi + wo);
        alo[os] = *(const f16x8*)(wlo + wo);
      }
      f16x8 bhi[4], blo[4];
#pragma unroll
      for (int ts = 0; ts < 4; ++ts) {
        const int a = (ts*16 + n + k*d)*136 + cib;
        bhi[ts] = *(const f16x8*)(shi + a);
        blo[ts] = *(const f16x8*)(slo + a);
      }
#pragma unroll
      for (int os = 0; os < 2; ++os)
#pragma unroll
        for (int ts = 0; ts < 4; ++ts) {
          acc[os][ts] = __builtin_amdgcn_mfma_f32_16x16x32_f16(ahi[os], bhi[ts], acc[os][ts], 0, 0, 0);
          acc[os][ts] = __builtin_amdgcn_mfma_f32_16x16x32_f16(alo[os], bhi[ts], acc[os][ts], 0, 0, 0);
          acc[os][ts] = __builtin_amdgcn_mfma_f32_16x16x32_f16(ahi[os], blo[ts], acc[os][ts], 0, 0, 0);
        }
    }
  }

  const f32x4 awq0 = *(const f32x4*)(aw + o0 + quad*4);
  const f32x4 awq1 = *(const f32x4*)(aw + o0 + 16 + quad*4);
  double s = 0.0, s2 = 0.0;
  float pa[4] = {0.f, 0.f, 0.f, 0.f};
  f32x4 cm[2];
  cm[0] = (f32x4){-3.4e38f, -3.4e38f, -3.4e38f, -3.4e38f};
  cm[1] = cm[0];

#pragma unroll
  for (int os = 0; os < 2; ++os) {
    const int ob = o0 + os*16 + quad*4;
    const f32x4 bs4 = *(const f32x4*)(bias + ob);
    const f32x4 awv = os ? awq1 : awq0;
#pragma unroll
    for (int ts = 0; ts < 4; ++ts) {
      const int t = t0 + ts*16 + n;
      const int tw = ts*16 + n + d;
      const f16x4 phv = *(const f16x4*)(shi + tw*136 + ob);
      const f16x4 plv = *(const f16x4*)(slo + tw*136 + ob);
      f32x4 res;
      float dotp = 0.f;
#pragma unroll
      for (int r = 0; r < 4; ++r) {
        float v = acc[os][ts][r] + bs4[r];
        v = v > 0.f ? v : 0.2f*v;
        const float hv = (float)phv[r] + (float)plv[r] + v;
        res[r] = hv;
        s += (double)hv; s2 += (double)hv*(double)hv;
        dotp += hv * awv[r];
        cm[os][r] = fmaxf(cm[os][r], hv);
      }
      pa[ts] += dotp;
      *(f32x4*)(hout + (size_t)t*CCH + ob) = res;
    }
  }

  // attn logits: reduce over o (quad bits 4,5 of lane), combine waves via LDS
#pragma unroll
  for (int ts = 0; ts < 4; ++ts) {
    pa[ts] += __shfl_xor(pa[ts], 16);
    pa[ts] += __shfl_xor(pa[ts], 32);
  }
  if (quad == 0) {
#pragma unroll
    for (int ts = 0; ts < 4; ++ts) attl[wv*64 + ts*16 + n] = pa[ts];
  }
  // per-c max: reduce over n (lane bits 0..3)
#pragma unroll
  for (int mk = 1; mk <= 8; mk <<= 1)
#pragma unroll
    for (int os = 0; os < 2; ++os)
#pragma unroll
      for (int r = 0; r < 4; ++r)
        cm[os][r] = fmaxf(cm[os][r], __shfl_xor(cm[os][r], mk));
  if (n == 0) {
#pragma unroll
    for (int os = 0; os < 2; ++os)
      *(f32x4*)(pm + ((size_t)b*512 + blockIdx.x)*128 + o0 + os*16 + quad*4) = cm[os];
  }
  // stats: wave reduce + block reduce
  for (int sft = 32; sft; sft >>= 1) { s += __shfl_down(s, sft); s2 += __shfl_down(s2, sft); }
  if (lane == 0) { sred[wv*2] = s; sred[wv*2+1] = s2; }
  __syncthreads();
  if (tid < 64)
    attnraw[(size_t)b*TSAMP + t0 + tid] =
        attl[tid] + attl[64 + tid] + attl[128 + tid] + attl[192 + tid];
  if (tid == 0) {
    atomicAdd(&sums[b*2],   sred[0] + sred[2] + sred[4] + sred[6]);
    atomicAdd(&sums[b*2+1], sred[1] + sred[3] + sred[5] + sred[7]);
  }
}

// ------------------------------------------------------------------
// K4: scale[b] = 1/(std_b + 1e-8)
__global__ void k_scale(const double* __restrict__ sums, float* __restrict__ scal) {
  const int b = threadIdx.x;
  if (b < NBATCH) {
    const double n = (double)CCH * (double)TSAMP;
    const double mean = sums[b*2] / n;
    double var = sums[b*2+1] / n - mean*mean;
    if (var < 0.0) var = 0.0;
    scal[b] = (float)(1.0 / (sqrt(var) + 1e-8));
  }
}

// K5b: finish context from 512 partial maxes per batch
__global__ void k_context2(const float* __restrict__ pm, const float* __restrict__ scal,
                           float* __restrict__ ctx) {
  const int b = blockIdx.x;
  const int c = threadIdx.x;   // 128
  float m = -3.4e38f;
  for (int s = 0; s < 512; ++s) m = fmaxf(m, pm[((size_t)b*512 + s)*128 + c]);
  ctx[b*128 + c] = m * scal[b];
}

// K6b: finish attn = sigmoid(raw*scal + ab)
__global__ __launch_bounds__(256) void k_attn2(const float* __restrict__ raw,
                                               const float* __restrict__ scal,
                                               const float* __restrict__ ab,
                                               float* __restrict__ attn) {
  const int b = blockIdx.y;
  const int i = blockIdx.x*1024 + threadIdx.x*4;
  const float s = scal[b], bb = ab[0];
  const float4 v = *(const float4*)(raw + (size_t)b*TSAMP + i);
  float* o = attn + (size_t)b*TSAMP + i;
  o[0] = 1.f/(1.f+expf(-(v.x*s+bb)));
  o[1] = 1.f/(1.f+expf(-(v.y*s+bb)));
  o[2] = 1.f/(1.f+expf(-(v.z*s+bb)));
  o[3] = 1.f/(1.f+expf(-(v.w*s+bb)));
}

// ------------------------------------------------------------------
// K7a: per-4096-chunk top-32 (LDS-resident, masking argmax).
__global__ __launch_bounds__(256) void k_topk1(const float* __restrict__ attn,
                                               float* __restrict__ cv,
                                               int* __restrict__ cidx) {
  const int ch = blockIdx.x, b = blockIdx.y;
  const float* a = attn + (size_t)b*TSAMP + ch*4096;
  __shared__ float v[4096];
  __shared__ float rv[4]; __shared__ int ri[4];
  const int tid = threadIdx.x;
  for (int i = tid; i < 4096; i += 256) v[i] = a[i];
  __syncthreads();
  for (int e = 0; e < NEV; ++e) {
    float bv = -1e30f; int bi = 0;
    for (int i = tid; i < 4096; i += 256) {
      const float x = v[i];
      if (x > bv) { bv = x; bi = i; }
    }
    for (int s = 32; s; s >>= 1) {
      const float ov = __shfl_down(bv, s); const int oi = __shfl_down(bi, s);
      if (ov > bv || (ov == bv && oi < bi)) { bv = ov; bi = oi; }
    }
    if ((tid & 63) == 0) { rv[tid >> 6] = bv; ri[tid >> 6] = bi; }
    __syncthreads();
    if (tid == 0) {
      int bb = 0;
      for (int w2 = 1; w2 < 4; ++w2)
        if (rv[w2] > rv[bb] || (rv[w2] == rv[bb] && ri[w2] < ri[bb])) bb = w2;
      cv[(b*8 + ch)*NEV + e] = rv[bb];
      cidx[(b*8 + ch)*NEV + e] = ch*4096 + ri[bb];
      v[ri[bb]] = -1e30f;
    }
    __syncthreads();
  }
}

// K7b: final top-32 over 256 candidates
__global__ __launch_bounds__(256) void k_topk2(const float* __restrict__ cv,
                                               const int* __restrict__ ci_,
                                               float* __restrict__ vals,
                                               int* __restrict__ idxs) {
  const int b = blockIdx.x;
  const int tid = threadIdx.x;
  float my = cv[b*256 + tid];
  int   mi = ci_[b*256 + tid];
  __shared__ float rv[4]; __shared__ int ri[4];
  __shared__ float bvs; __shared__ int bis;
  for (int e = 0; e < NEV; ++e) {
    float bv = my; int bi = mi;
    for (int s = 32; s; s >>= 1) {
      const float ov = __shfl_down(bv, s); const int oi = __shfl_down(bi, s);
      if (ov > bv || (ov == bv && oi < bi)) { bv = ov; bi = oi; }
    }
    if ((tid & 63) == 0) { rv[tid >> 6] = bv; ri[tid >> 6] = bi; }
    __syncthreads();
    if (tid == 0) {
      int bb = 0;
      for (int w2 = 1; w2 < 4; ++w2)
        if (rv[w2] > rv[bb] || (rv[w2] == rv[bb] && ri[w2] < ri[bb])) bb = w2;
      vals[b*NEV + e] = rv[bb]; idxs[b*NEV + e] = ri[bb];
      bvs = rv[bb]; bis = ri[bb];
    }
    __syncthreads();
    if (mi == bis && my == bvs) my = -1e30f;
    __syncthreads();
  }
}

// ------------------------------------------------------------------
__device__ __forceinline__ float blk_max128(float v, float* red) {
  const int tid = threadIdx.x;
  red[tid] = v; __syncthreads();
  for (int s = 64; s > 0; s >>= 1) {
    if (tid < s) red[tid] = fmaxf(red[tid], red[tid + s]);
    __syncthreads();
  }
  const float r = red[0]; __syncthreads();
  return r;
}
__device__ __forceinline__ float blk_sum128(float v, float* red) {
  const int tid = threadIdx.x;
  red[tid] = v; __syncthreads();
  for (int s = 64; s > 0; s >>= 1) {
    if (tid < s) red[tid] += red[tid + s];
    __syncthreads();
  }
  const float r = red[0]; __syncthreads();
  return r;
}
__device__ __forceinline__ float mlp_hidden3(float latv, const float* __restrict__ hw,
                                             const float* __restrict__ hb, float* xa) {
  const int tid = threadIdx.x;
  float cur = latv;
  for (int i = 0; i < 3; ++i) {
    xa[tid] = cur; __syncthreads();
    const float* W = hw + (size_t)i*CCH*CCH;
    float acc = hb[i*CCH + tid];
    for (int c = 0; c < CCH; ++c) acc += xa[c] * W[c*CCH + tid];
    cur = acc > 0.f ? acc : 0.2f*acc;
    __syncthreads();
  }
  return cur;
}

// K8: lat + all three MLPs + softmaxes + amps. One 128-thread block per event.
__global__ __launch_bounds__(128) void k_mlp(
    const float* __restrict__ h, const float* __restrict__ scal,
    const float* __restrict__ vals, const int* __restrict__ idxs,
    const float* __restrict__ a_hw, const float* __restrict__ a_hb,
    const float* __restrict__ a_ow, const float* __restrict__ a_ob,
    const float* __restrict__ t_hw, const float* __restrict__ t_hb,
    const float* __restrict__ t_ow, const float* __restrict__ t_ob,
    const float* __restrict__ m_hw, const float* __restrict__ m_hb,
    const float* __restrict__ m_ow, const float* __restrict__ m_ob,
    float* __restrict__ p_atoms, float* __restrict__ p_trans, float* __restrict__ amps) {
  const int row = blockIdx.x;
  const int b = row >> 5;
  const int tid = threadIdx.x;
  __shared__ float xa[CCH];
  __shared__ float red[CCH];
  const int t = idxs[row];
  const float latv = h[((size_t)b*TSAMP + t)*CCH + tid] * scal[b] * vals[row];

  {
    const float cur = mlp_hidden3(latv, a_hw, a_hb, xa);
    xa[tid] = cur; __syncthreads();
    float l0 = a_ob[tid], l1 = a_ob[tid+128], l2 = a_ob[tid+256], l3 = a_ob[tid+384];
    for (int c = 0; c < CCH; ++c) {
      const float xv = xa[c];
      const float* W = a_ow + (size_t)c*NATOMS + tid;
      l0 += xv*W[0]; l1 += xv*W[128]; l2 += xv*W[256]; l3 += xv*W[384];
    }
    const float mx = blk_max128(fmaxf(fmaxf(l0,l1), fmaxf(l2,l3)), red);
    const float e0 = expf(l0-mx), e1 = expf(l1-mx), e2 = expf(l2-mx), e3 = expf(l3-mx);
    const float inv = 1.f / blk_sum128(e0+e1+e2+e3, red);
    float* pa = p_atoms + (size_t)row*NATOMS;
    pa[tid] = e0*inv; pa[tid+128] = e1*inv; pa[tid+256] = e2*inv; pa[tid+384] = e3*inv;
  }
  {
    const float cur = mlp_hidden3(latv, t_hw, t_hb, xa);
    xa[tid] = cur; __syncthreads();
    float lg = -3.4e38f;
    if (tid < NTRANS) {
      float acc = t_ob[tid];
      for (int c = 0; c < CCH; ++c) acc += xa[c]*t_ow[c*NTRANS + tid];
      lg = acc;
    }
    const float mt = blk_max128(lg, red);
    const float et = (tid < NTRANS) ? expf(lg - mt) : 0.f;
    const float st = blk_sum128(et, red);
    if (tid < NTRANS) p_trans[(size_t)row*NTRANS + tid] = et/st;
  }
  {
    const float cur = mlp_hidden3(latv, m_hw, m_hb, xa);
    const float s = blk_sum128(cur * m_ow[tid], red);
    if (tid == 0) { const float v = s + m_ob[0]; amps[row] = v*v; }
  }
}

// K9: atoms_vec[row,:] = p_atoms[row] @ atoms_dict (512x512)
__global__ __launch_bounds__(256) void k_atoms_mm(const float* __restrict__ p_atoms,
                                                  const float* __restrict__ dict,
                                                  float* __restrict__ av) {
  const int row = blockIdx.x;
  __shared__ float p[NATOMS];
  for (int i = threadIdx.x; i < NATOMS; i += 256) p[i] = p_atoms[(size_t)row*NATOMS + i];
  __syncthreads();
  const int s0 = threadIdx.x*2;
  float a0=0, a1=0;
  for (int a = 0; a < NATOMS; ++a) {
    const float pa = p[a];
    const float2 dv = *(const float2*)(dict + (size_t)a*ASIZE + s0);
    a0 += pa*dv.x; a1 += pa*dv.y;
  }
  av[(size_t)row*ASIZE + s0] = a0; av[(size_t)row*ASIZE + s0 + 1] = a1;
}

// K10: transfers[row,:] = p_trans[row] @ transfer_dict (64x8192)
__global__ __launch_bounds__(256) void k_trans_mm(const float* __restrict__ p_trans,
                                                   const float* __restrict__ td,
                                                   float* __restrict__ trans) {
  const int row = blockIdx.y;
  const int t = blockIdx.x*2048 + threadIdx.x*8;
  __shared__ float p[NTRANS];
  if (threadIdx.x < NTRANS) p[threadIdx.x] = p_trans[(size_t)row*NTRANS + threadIdx.x];
  __syncthreads();
  float a0=0,a1=0,a2=0,a3=0,a4=0,a5=0,a6=0,a7=0;
  for (int j = 0; j < NTRANS; ++j) {
    const float pj = p[j];
    const float4 v0 = *(const float4*)(td + (size_t)j*TSIZE + t);
    const float4 v1 = *(const float4*)(td + (size_t)j*TSIZE + t + 4);
    a0 += pj*v0.x; a1 += pj*v0.y; a2 += pj*v0.z; a3 += pj*v0.w;
    a4 += pj*v1.x; a5 += pj*v1.y; a6 += pj*v1.z; a7 += pj*v1.w;
  }
  float* o = trans + (size_t)row*TSIZE + t;
  o[0]=a0; o[1]=a1; o[2]=a2; o[3]=a3; o[4]=a4; o[5]=a5; o[6]=a6; o[7]=a7;
}

// K11: ev[row,n] = (sum_{k<512} atoms[row,k]*transfers[row,n-k] + atoms_pad) * amp
__global__ __launch_bounds__(256) void k_ev(const float* __restrict__ trans,
                                            const float* __restrict__ av,
                                            const float* __restrict__ amps,
                                            float* __restrict__ ev) {
  const int row = blockIdx.y;
  const int t0 = blockIdx.x * 1024;
  __shared__ float al[512];
  __shared__ float tw[1536];
  for (int i = threadIdx.x; i < 512; i += 256) al[i] = av[(size_t)row*ASIZE + i];
  for (int i = threadIdx.x; i < 1536; i += 256) {
    const int g = t0 - 512 + i;
    tw[i] = (g >= 0) ? trans[(size_t)row*TSIZE + g] : 0.f;
  }
  __syncthreads();
  const int base = threadIdx.x*4 + 512;
  float a0=0,a1=0,a2=0,a3=0;
  float w0=tw[base], w1=tw[base+1], w2=tw[base+2], w3=tw[base+3];
#pragma unroll 8
  for (int k = 0; k < 512; ++k) {
    const float ak = al[k];
    a0 += ak*w0; a1 += ak*w1; a2 += ak*w2; a3 += ak*w3;
    w3 = w2; w2 = w1; w1 = w0; w0 = tw[base - k - 1];
  }
  const int n = t0 + threadIdx.x*4;
  const float amp = amps[row];
  float* e = ev + (size_t)row*TSIZE + n;
  e[0] = (a0 + (n+0 < 512 ? al[n+0] : 0.f)) * amp;
  e[1] = (a1 + (n+1 < 512 ? al[n+1] : 0.f)) * amp;
  e[2] = (a2 + (n+2 < 512 ? al[n+2] : 0.f)) * amp;
  e[3] = (a3 + (n+3 < 512 ? al[n+3] : 0.f)) * amp;
}

// K12: overlap-add gather, parallel over (t-chunk, row-slab); atomics into dry.
__global__ __launch_bounds__(256) void k_dry(const float* __restrict__ ev,
                                             const int* __restrict__ idxs,
                                             float* __restrict__ dry) {
  __shared__ int sidx[32];
  const int r0 = blockIdx.y * 32;
  if (threadIdx.x < 32) sidx[threadIdx.x] = idxs[r0 + threadIdx.x];
  __syncthreads();
  const int p = blockIdx.x*512 + threadIdx.x*2;
  float a0=0,a1=0;
  for (int r = 0; r < 32; ++r) {
    const int off = p - sidx[r];
    if (off >= -1 && off < TSIZE) {
      const float* er = ev + (size_t)(r0 + r)*TSIZE;
      if ((unsigned)(off  ) < TSIZE) a0 += er[off];
      if ((unsigned)(off+1) < TSIZE) a1 += er[off+1];
    }
  }
  atomicAdd(dry + p,     a0);
  atomicAdd(dry + p + 1, a1);
}

// K12b: reversed, scaled f16 dry with zero pad (contiguous staging for k_wet)
__global__ __launch_bounds__(256) void k_dryrev(const float* __restrict__ dry,
                                                _Float16* __restrict__ drev) {
  const int i = blockIdx.x*256 + threadIdx.x;
  if (i < TSAMP + 1088)
    drev[i] = (i < TSAMP) ? (_Float16)(dry[TSAMP-1-i] * DRY_SCALE) : (_Float16)0.f;
}

// K13: room softmax + wet/dry mix scalars
__global__ void k_room(const float* __restrict__ ctx, const float* __restrict__ room_w,
                       const float* __restrict__ room_b, const float* __restrict__ mix_w,
                       const float* __restrict__ mix_b, float* __restrict__ roomp,
                       float* __restrict__ mix) {
  const int b = threadIdx.x >> 3;
  const int r = threadIdx.x & 7;
  float acc = room_b[r];
  for (int c = 0; c < CCH; ++c) acc += ctx[b*CCH + c] * room_w[c*8 + r];
  float m = acc;
  for (int s = 1; s < 8; s <<= 1) m = fmaxf(m, __shfl_xor(m, s, 8));
  const float e = expf(acc - m);
  float ssum = e;
  for (int s = 1; s < 8; s <<= 1) ssum += __shfl_xor(ssum, s, 8);
  roomp[b*8 + r] = e / ssum;
  if (r == 0) {
    float a = mix_b[0];
    for (int c = 0; c < CCH; ++c) a += ctx[b*CCH + c] * mix_w[c];
    mix[b] = 1.f/(1.f+expf(-a));
  }
}

// K14: impulse[b,t] -> f16 hi only, ×2^6
__global__ __launch_bounds__(256) void k_impulse(const float* __restrict__ roomp,
                                                 const float* __restrict__ rooms,
                                                 _Float16* __restrict__ ihi) {
  const int b = blockIdx.y;
  const int t = blockIdx.x*1024 + threadIdx.x*4;
  float a0=0,a1=0,a2=0,a3=0;
  for (int r = 0; r < 8; ++r) {
    const float pr = roomp[b*8 + r];
    const float4 v = *(const float4*)(rooms + (size_t)r*TSAMP + t);
    a0 += pr*v.x; a1 += pr*v.y; a2 += pr*v.z; a3 += pr*v.w;
  }
  _Float16* oh = ihi + (size_t)b*TSAMP + t;
  oh[0] = (_Float16)(a0*IMP_SCALE); oh[1] = (_Float16)(a1*IMP_SCALE);
  oh[2] = (_Float16)(a2*IMP_SCALE); oh[3] = (_Float16)(a3*IMP_SCALE);
}

// K15: reverb conv via f16 MFMA (hi-only: wet rel err ~5e-4 << 2% tolerance).
// N=512/block, k-slab 4096; staging reads contiguous from reversed dry.
__global__ __launch_bounds__(256) void k_wet_mfma(
    const _Float16* __restrict__ drev, const _Float16* __restrict__ ihi,
    float* __restrict__ wet) {
  const int t0 = blockIdx.x * 512;
  const int k0 = blockIdx.y * 4096;
  if (k0 > t0 + 511) return;
  __shared__ _Float16 rhi[8*1048];
  const int tid = threadIdx.x;
  const int wv = tid >> 6;
  const int lane = tid & 63;
  const int n16 = lane & 15;
  const int quad = lane >> 4;
  const int m = n16;

  f32x4 acc[8];
#pragma unroll
  for (int j = 0; j < 8; ++j) acc[j] = (f32x4){0.f,0.f,0.f,0.f};

  const int kend = (k0 + 4096 < t0 + 512) ? k0 + 4096 : t0 + 512;
  const int ph = 7 - (n16 & 7);
  for (int kc0 = k0; kc0 < kend; kc0 += 512) {
    // S_p[q] = dry[D0 - p - q] = drev[RB + p + q], D0 = t0+511-kc0
    const int RB = TSAMP - 1 - (t0 + 511 - kc0);
    for (int flat = tid; flat < 8*1016; flat += 256) {
      const int p = flat / 1016;
      const int q = flat - p*1016;
      rhi[p*1048 + q] = drev[RB + p + q];
    }
    __syncthreads();

#pragma unroll 4
    for (int kc = 0; kc < 16; ++kc) {
      const int kb = kc*32;
      const int jg = kc0 + kb + quad*8;
      f16x8 ah;
      if (m < NBATCH) ah = *(const f16x8*)(ihi + (size_t)m*TSAMP + jg);
      else ah = (f16x8){0,0,0,0,0,0,0,0};
#pragma unroll
      for (int ts = 0; ts < 8; ++ts) {
        const int nn = wv*128 + ts*16 + n16;
        const int a = ph*1048 + kb + quad*8 + 504 - (nn & ~7);
        const f16x8 bh = *(const f16x8*)(rhi + a);
        acc[ts] = __builtin_amdgcn_mfma_f32_16x16x32_f16(ah, bh, acc[ts], 0, 0, 0);
      }
    }
    __syncthreads();
  }

#pragma unroll
  for (int ts = 0; ts < 8; ++ts) {
    const int t = t0 + wv*128 + ts*16 + n16;
#pragma unroll
    for (int r = 0; r < 4; ++r) {
      const int b = quad*4 + r;
      if (b < NBATCH)
        atomicAdd(wet + (size_t)b*TSAMP + t, acc[ts][r] * WET_DESCALE);
    }
  }
}

// K16: out = dry*(1-mix) + wet*mix
__global__ __launch_bounds__(256) void k_out(const float* __restrict__ dry,
                                             const float* __restrict__ wet,
                                             const float* __restrict__ mix,
                                             float* __restrict__ out) {
  const int b = blockIdx.y;
  const int t = blockIdx.x*1024 + threadIdx.x*4;
  const float m = mix[b];
  const float4 d = *(const float4*)(dry + t);
  const float4 w = *(const float4*)(wet + (size_t)b*TSAMP + t);
  float* o = out + (size_t)b*TSAMP + t;
  o[0] = d.x*(1.f-m) + w.x*m;
  o[1] = d.y*(1.f-m) + w.y*m;
  o[2] = d.z*(1.f-m) + w.z*m;
  o[3] = d.w*(1.f-m) + w.w*m;
}

// ------------------------------------------------------------------
extern "C" void kernel_launch(void* const* d_in, const int* in_sizes, int n_in,
                              void* d_out, int out_size, void* d_ws, size_t ws_size,
                              hipStream_t stream) {
  (void)in_sizes; (void)n_in; (void)out_size; (void)ws_size;
  const float* x      = (const float*)d_in[0];
  const float* bank   = (const float*)d_in[1];
  const float* w_net  = (const float*)d_in[2];
  const float* b_net  = (const float*)d_in[3];
  const float* attn_w = (const float*)d_in[4];
  const float* attn_b = (const float*)d_in[5];
  const float* a_hw = (const float*)d_in[6];
  const float* a_hb = (const float*)d_in[7];
  const float* a_ow = (const float*)d_in[8];
  const float* a_ob = (const float*)d_in[9];
  const float* t_hw = (const float*)d_in[10];
  const float* t_hb = (const float*)d_in[11];
  const float* t_ow = (const float*)d_in[12];
  const float* t_ob = (const float*)d_in[13];
  const float* m_hw = (const float*)d_in[14];
  const float* m_hb = (const float*)d_in[15];
  const float* m_ow = (const float*)d_in[16];
  const float* m_ob = (const float*)d_in[17];
  const float* atoms_dict    = (const float*)d_in[18];
  const float* transfer_dict = (const float*)d_in[19];
  const float* rooms  = (const float*)d_in[20];
  const float* room_w = (const float*)d_in[21];
  const float* room_b = (const float*)d_in[22];
  const float* mix_w  = (const float*)d_in[23];
  const float* mix_b  = (const float*)d_in[24];
  float* out = (float*)d_out;

  // ---- workspace (~206 MB): H | t1 | t2 | weights | stats(dedicated) ;
  // post-conv scratch aliases t1/t2.
  float* ws = (float*)d_ws;
  float* H  = ws;                                    // [B][T][C]
  float* t1 = ws + (size_t)33554432;
  float* t2 = ws + (size_t)41943040;
  _Float16* whi = (_Float16*)(ws + (size_t)50331648);
  _Float16* wlo = (_Float16*)(ws + (size_t)50454528);
  _Float16* bhi = (_Float16*)(ws + (size_t)50577408);
  _Float16* blo = (_Float16*)(ws + (size_t)50610176);
  double* sums  = (double*)(ws + (size_t)50642944);  // 16 doubles
  float* attnraw = ws + (size_t)50642976;            // 8*32768
  float* pm      = ws + (size_t)50905120;            // 8*512*128

  size_t off = 33554432;                             // scratch base (aliases t1)
  float* attn  = ws + off; off += (size_t)NBATCH*TSAMP;
  float* scal  = ws + off; off += 8;
  float* ctx   = ws + off; off += NBATCH*CCH;
  float* vals  = ws + off; off += NROWS;
  int*   idxs  = (int*)(ws + off); off += NROWS;
  float* p_atoms = ws + off; off += (size_t)NROWS*NATOMS;
  float* p_trans = ws + off; off += (size_t)NROWS*NTRANS;
  float* amps  = ws + off; off += NROWS;
  float* av    = ws + off; off += (size_t)NROWS*ASIZE;
  float* trans = ws + off; off += (size_t)NROWS*TSIZE;
  float* ev    = ws + off; off += (size_t)NROWS*TSIZE;
  float* dry   = ws + off; off += TSAMP;
  float* roomp = ws + off; off += 64;
  float* mix   = ws + off; off += 8;
  float* wet   = ws + off; off += (size_t)NBATCH*TSAMP;
  float* cand_v = ws + off; off += 2048;
  int*   cand_i = (int*)(ws + off); off += 2048;
  _Float16* imphi = (_Float16*)(ws + off); off += (size_t)NBATCH*TSAMP/2;
  _Float16* drev  = (_Float16*)(ws + off); off += (TSAMP + 1088)/2 + 4;
  // scratch ends ~38.9M floats < 50.33M — disjoint from weights/stats.

  k_zs<<<1, 64, 0, stream>>>(sums);
  k_wsplit<<<960, 256, 0, stream>>>(w_net, whi, wlo);
  k_bsplit<<<256, 256, 0, stream>>>(bank, bhi, blo);
  k_front_mfma<<<dim3(256, 8), 256, 0, stream>>>(x, bhi, blo, H);

  const int dil[5] = {1, 3, 9, 27, 1};
  const size_t S = (size_t)CCH * TSAMP;
  for (int p = 0; p < 4; ++p) {            // 2 batches per dispatch
    float* Hp = H + (size_t)(2*p) * S;
    float* io[6] = {Hp, t1, t2, t1, t2, Hp};
    for (int i = 0; i < 4; ++i) {
      const int d = dil[i];
      const size_t smem = (size_t)(64 + 2*d) * 544;
      k_dil_mfma<<<dim3(512, 2), 256, smem, stream>>>(
          io[i], whi + (size_t)i*49152, wlo + (size_t)i*49152, b_net + i*CCH,
          io[i+1], d);
    }
    {   // last layer: fused stats epilogue
      const int d = dil[4];
      const size_t smem = (size_t)(64 + 2*d) * 544;
      k_dil_last<<<dim3(512, 2), 256, smem, stream>>>(
          io[4], whi + (size_t)4*49152, wlo + (size_t)4*49152, b_net + 4*CCH,
          io[5], d, attn_w, sums, attnraw, pm, 2*p);
    }
  }

  k_zero<<<1024, 256, 0, stream>>>(wet, dry);
  k_scale<<<1, 64, 0, stream>>>(sums, scal);
  k_context2<<<8, 128, 0, stream>>>(pm, scal, ctx);
  k_attn2<<<dim3(32, 8), 256, 0, stream>>>(attnraw, scal, attn_b, attn);
  k_topk1<<<dim3(8, 8), 256, 0, stream>>>(attn, cand_v, cand_i);
  k_topk2<<<8, 256, 0, stream>>>(cand_v, cand_i, vals, idxs);
  k_mlp<<<256, 128, 0, stream>>>(H, scal, vals, idxs,
                                 a_hw, a_hb, a_ow, a_ob,
                                 t_hw, t_hb, t_ow, t_ob,
                                 m_hw, m_hb, m_ow, m_ob,
                                 p_atoms, p_trans, amps);
  k_atoms_mm<<<256, 256, 0, stream>>>(p_atoms, atoms_dict, av);
  k_trans_mm<<<dim3(4, 256), 256, 0, stream>>>(p_trans, transfer_dict, trans);
  k_ev<<<dim3(8, 256), 256, 0, stream>>>(trans, av, amps, ev);
  k_dry<<<dim3(64, 8), 256, 0, stream>>>(ev, idxs, dry);
  k_dryrev<<<133, 256, 0, stream>>>(dry, drev);
  k_room<<<1, 64, 0, stream>>>(ctx, room_w, room_b, mix_w, mix_b, roomp, mix);
  k_impulse<<<dim3(32, 8), 256, 0, stream>>>(roomp, rooms, imphi);
  k_wet_mfma<<<dim3(64, 8), 256, 0, stream>>>(drev, imphi, wet);
  k_out<<<dim3(32, 8), 256, 0, stream>>>(dry, wet, mix, out);
}

// Round 10
// 1210.043 us; speedup vs baseline: 7.3347x; 1.2167x over previous
//
#include <hip/hip_runtime.h>
#include <math.h>

#define TSAMP 32768
#define CCH 128
#define NBATCH 8
#define NEV 32
#define NROWS 256   // NBATCH*NEV
#define NATOMS 512
#define ASIZE 512
#define NTRANS 64
#define TSIZE 8192

#define DRY_SCALE 16777216.0f               // 2^24
#define IMP_SCALE 64.0f                     // 2^6
#define WET_DESCALE 9.313225746154785e-10f  // 2^-30

// LDS skew for stride-4 lane patterns: 8-way conflict -> 2-way (free)
#define EPAD(i) ((i) + ((i) >> 5))

typedef _Float16 f16x8 __attribute__((ext_vector_type(8)));
typedef _Float16 f16x4 __attribute__((ext_vector_type(4)));
typedef float f32x4 __attribute__((ext_vector_type(4)));

// activations H/t1/t2 stored [B][T][C] (c contiguous).

// ------------------------------------------------------------------
__global__ void k_zs(double* __restrict__ sums) {
  if (threadIdx.x < 16) sums[threadIdx.x] = 0.0;
}

__global__ __launch_bounds__(256) void k_zero(float* __restrict__ wet,
                                              float* __restrict__ dry) {
  int i = blockIdx.x * 256 + threadIdx.x;
  if (i < NBATCH * TSAMP) wet[i] = 0.f;
  if (i < TSAMP) dry[i] = 0.f;
}

// ------------------------------------------------------------------
// Kw: split conv weights into f16 hi/lo in layout [layer][k][o][ci]
__global__ __launch_bounds__(256) void k_wsplit(const float* __restrict__ wn,
                                                _Float16* __restrict__ whi,
                                                _Float16* __restrict__ wlo) {
  const int i = blockIdx.x * 256 + threadIdx.x;   // 5*3*128*128 = 245760
  if (i >= 245760) return;
  const int ci = i & 127;
  int r = i >> 7;
  const int o = r & 127;
  r >>= 7;
  const int k = r % 3;
  const int l = r / 3;
  const float w = wn[(((size_t)l*128 + o)*128 + ci)*3 + k];
  const _Float16 hi = (_Float16)w;
  whi[i] = hi;
  wlo[i] = (_Float16)(w - (float)hi);
}

// Kb: split filter bank into f16 hi/lo, layout [c][k]
__global__ __launch_bounds__(256) void k_bsplit(const float* __restrict__ bank,
                                                _Float16* __restrict__ bhi,
                                                _Float16* __restrict__ blo) {
  const int i = blockIdx.x * 256 + threadIdx.x;   // 128*512 = 65536
  if (i < 65536) {
    const float w = bank[i];
    const _Float16 hi = (_Float16)w;
    bhi[i] = hi;
    blo[i] = (_Float16)(w - (float)hi);
  }
}

// ------------------------------------------------------------------
// K1: front filter bank via split-f16 MFMA, 128-t blocks (8 ts tiles/wave).
__global__ __launch_bounds__(256) void k_front_mfma(
    const float* __restrict__ x, const _Float16* __restrict__ bhi,
    const _Float16* __restrict__ blo, float* __restrict__ h) {
  __shared__ _Float16 shi[8*664];
  __shared__ _Float16 slo[8*664];
  const int t0 = blockIdx.x * 128;
  const int b  = blockIdx.y;
  const float* xb = x + (size_t)b*TSAMP;
  const int tid = threadIdx.x;

  for (int flat = tid; flat < 8*632; flat += 256) {
    const int p = flat / 632;
    const int q = flat - p*632;
    const int g = t0 - 256 + q + p;
    const float v = (g >= 0 && g < TSAMP) ? xb[g] : 0.f;
    const _Float16 hi = (_Float16)v;
    shi[p*664 + q] = hi;
    slo[p*664 + q] = (_Float16)(v - (float)hi);
  }
  __syncthreads();

  const int wv = tid >> 6;
  const int lane = tid & 63;
  const int n = lane & 15;
  const int quad = lane >> 4;
  const int c0 = wv * 32;
  const int ph = n & 7;
  const int nb = n & 8;

  f32x4 acc[2][8];
#pragma unroll
  for (int i = 0; i < 2; ++i)
#pragma unroll
    for (int j = 0; j < 8; ++j) acc[i][j] = (f32x4){0.f,0.f,0.f,0.f};

  for (int kc = 0; kc < 16; ++kc) {
    const int kb = kc*32 + quad*8;
    f16x8 ahi[2], alo[2];
#pragma unroll
    for (int os = 0; os < 2; ++os) {
      const size_t ao = (size_t)(c0 + os*16 + n)*512 + kb;
      ahi[os] = *(const f16x8*)(bhi + ao);
      alo[os] = *(const f16x8*)(blo + ao);
    }
#pragma unroll
    for (int tg = 0; tg < 2; ++tg) {
      f16x8 xh[4], xl[4];
#pragma unroll
      for (int u = 0; u < 4; ++u) {
        const int a = ph*664 + (tg*4 + u)*16 + nb + kb;
        xh[u] = *(const f16x8*)(shi + a);
        xl[u] = *(const f16x8*)(slo + a);
      }
#pragma unroll
      for (int os = 0; os < 2; ++os)
#pragma unroll
        for (int u = 0; u < 4; ++u) {
          f32x4 a4 = acc[os][tg*4 + u];
          a4 = __builtin_amdgcn_mfma_f32_16x16x32_f16(ahi[os], xh[u], a4, 0, 0, 0);
          a4 = __builtin_amdgcn_mfma_f32_16x16x32_f16(alo[os], xh[u], a4, 0, 0, 0);
          a4 = __builtin_amdgcn_mfma_f32_16x16x32_f16(ahi[os], xl[u], a4, 0, 0, 0);
          acc[os][tg*4 + u] = a4;
        }
    }
  }

  float* hb = h + (size_t)b*TSAMP*CCH;
#pragma unroll
  for (int os = 0; os < 2; ++os) {
    const int cb = c0 + os*16 + quad*4;
#pragma unroll
    for (int ts = 0; ts < 8; ++ts) {
      const int t = t0 + ts*16 + n;
      *(f32x4*)(hb + (size_t)t*CCH + cb) = acc[os][ts];
    }
  }
}

// ------------------------------------------------------------------
// K2a: 64-t dilated conv layer (kept for d=27 where 128-t LDS would kill occ).
__global__ __launch_bounds__(256) void k_dil_mfma(
    const float* __restrict__ hin0, const _Float16* __restrict__ whi,
    const _Float16* __restrict__ wlo, const float* __restrict__ bias,
    float* __restrict__ hout0, const int d) {
  extern __shared__ _Float16 sh[];
  const int twin = 64 + 2*d;
  _Float16* shi = sh;
  _Float16* slo = sh + twin*136;
  const int t0 = blockIdx.x * 64;
  const size_t bs = (size_t)blockIdx.y * CCH * TSAMP;
  const float* __restrict__ hin = hin0 + bs;
  float* __restrict__ hout = hout0 + bs;
  const int tid = threadIdx.x;

  for (int flat = tid; flat < twin*32; flat += 256) {
    const int tw = flat >> 5;
    const int c4 = (flat & 31) << 2;
    const int g = t0 - d + tw;
    float4 v = {0.f, 0.f, 0.f, 0.f};
    if (g >= 0 && g < TSAMP) v = *(const float4*)(hin + (size_t)g*CCH + c4);
    f16x4 hv, lv;
    hv[0] = (_Float16)v.x; hv[1] = (_Float16)v.y;
    hv[2] = (_Float16)v.z; hv[3] = (_Float16)v.w;
    lv[0] = (_Float16)(v.x - (float)hv[0]); lv[1] = (_Float16)(v.y - (float)hv[1]);
    lv[2] = (_Float16)(v.z - (float)hv[2]); lv[3] = (_Float16)(v.w - (float)hv[3]);
    *(f16x4*)(shi + tw*136 + c4) = hv;
    *(f16x4*)(slo + tw*136 + c4) = lv;
  }
  __syncthreads();

  const int wv = tid >> 6;
  const int lane = tid & 63;
  const int n = lane & 15;
  const int quad = lane >> 4;
  const int o0 = wv * 32;

  f32x4 acc[2][4];
#pragma unroll
  for (int i = 0; i < 2; ++i)
#pragma unroll
    for (int j = 0; j < 4; ++j) acc[i][j] = (f32x4){0.f,0.f,0.f,0.f};

  for (int k = 0; k < 3; ++k) {
    for (int kc = 0; kc < 4; ++kc) {
      const int cib = kc*32 + quad*8;
      f16x8 ahi[2], alo[2];
#pragma unroll
      for (int os = 0; os < 2; ++os) {
        const size_t wo = ((size_t)k*128 + (o0 + os*16 + n))*128 + cib;
        ahi[os] = *(const f16x8*)(whi + wo);
        alo[os] = *(const f16x8*)(wlo + wo);
      }
      f16x8 bhi[4], blo[4];
#pragma unroll
      for (int ts = 0; ts < 4; ++ts) {
        const int a = (ts*16 + n + k*d)*136 + cib;
        bhi[ts] = *(const f16x8*)(shi + a);
        blo[ts] = *(const f16x8*)(slo + a);
      }
#pragma unroll
      for (int os = 0; os < 2; ++os)
#pragma unroll
        for (int ts = 0; ts < 4; ++ts) {
          acc[os][ts] = __builtin_amdgcn_mfma_f32_16x16x32_f16(ahi[os], bhi[ts], acc[os][ts], 0, 0, 0);
          acc[os][ts] = __builtin_amdgcn_mfma_f32_16x16x32_f16(alo[os], bhi[ts], acc[os][ts], 0, 0, 0);
          acc[os][ts] = __builtin_amdgcn_mfma_f32_16x16x32_f16(ahi[os], blo[ts], acc[os][ts], 0, 0, 0);
        }
    }
  }

#pragma unroll
  for (int os = 0; os < 2; ++os) {
    const int ob = o0 + os*16 + quad*4;
    const f32x4 bs4 = *(const f32x4*)(bias + ob);
#pragma unroll
    for (int ts = 0; ts < 4; ++ts) {
      const int t = t0 + ts*16 + n;
      const int tw = ts*16 + n + d;
      const f16x4 phv = *(const f16x4*)(shi + tw*136 + ob);
      const f16x4 plv = *(const f16x4*)(slo + tw*136 + ob);
      f32x4 res;
#pragma unroll
      for (int r = 0; r < 4; ++r) {
        float v = acc[os][ts][r] + bs4[r];
        v = v > 0.f ? v : 0.2f*v;
        res[r] = (float)phv[r] + (float)plv[r] + v;
      }
      *(f32x4*)(hout + (size_t)t*CCH + ob) = res;
    }
  }
}

// ------------------------------------------------------------------
// K2b: 128-t dilated conv layer (d<=9): 576 MFMA/wave, 8 acc chains.
__global__ __launch_bounds__(256) void k_dil128(
    const float* __restrict__ hin0, const _Float16* __restrict__ whi,
    const _Float16* __restrict__ wlo, const float* __restrict__ bias,
    float* __restrict__ hout0, const int d) {
  extern __shared__ _Float16 sh[];
  const int twin = 128 + 2*d;
  _Float16* shi = sh;
  _Float16* slo = sh + twin*136;
  const int t0 = blockIdx.x * 128;
  const size_t bs = (size_t)blockIdx.y * CCH * TSAMP;
  const float* __restrict__ hin = hin0 + bs;
  float* __restrict__ hout = hout0 + bs;
  const int tid = threadIdx.x;

  for (int flat = tid; flat < twin*32; flat += 256) {
    const int tw = flat >> 5;
    const int c4 = (flat & 31) << 2;
    const int g = t0 - d + tw;
    float4 v = {0.f, 0.f, 0.f, 0.f};
    if (g >= 0 && g < TSAMP) v = *(const float4*)(hin + (size_t)g*CCH + c4);
    f16x4 hv, lv;
    hv[0] = (_Float16)v.x; hv[1] = (_Float16)v.y;
    hv[2] = (_Float16)v.z; hv[3] = (_Float16)v.w;
    lv[0] = (_Float16)(v.x - (float)hv[0]); lv[1] = (_Float16)(v.y - (float)hv[1]);
    lv[2] = (_Float16)(v.z - (float)hv[2]); lv[3] = (_Float16)(v.w - (float)hv[3]);
    *(f16x4*)(shi + tw*136 + c4) = hv;
    *(f16x4*)(slo + tw*136 + c4) = lv;
  }
  __syncthreads();

  const int wv = tid >> 6;
  const int lane = tid & 63;
  const int n = lane & 15;
  const int quad = lane >> 4;
  const int o0 = wv * 32;

  f32x4 acc[2][8];
#pragma unroll
  for (int i = 0; i < 2; ++i)
#pragma unroll
    for (int j = 0; j < 8; ++j) acc[i][j] = (f32x4){0.f,0.f,0.f,0.f};

  for (int k = 0; k < 3; ++k) {
    for (int kc = 0; kc < 4; ++kc) {
      const int cib = kc*32 + quad*8;
      f16x8 ahi[2], alo[2];
#pragma unroll
      for (int os = 0; os < 2; ++os) {
        const size_t wo = ((size_t)k*128 + (o0 + os*16 + n))*128 + cib;
        ahi[os] = *(const f16x8*)(whi + wo);
        alo[os] = *(const f16x8*)(wlo + wo);
      }
#pragma unroll
      for (int tg = 0; tg < 2; ++tg) {
        f16x8 bh[4], bl[4];
#pragma unroll
        for (int u = 0; u < 4; ++u) {
          const int a = ((tg*4 + u)*16 + n + k*d)*136 + cib;
          bh[u] = *(const f16x8*)(shi + a);
          bl[u] = *(const f16x8*)(slo + a);
        }
#pragma unroll
        for (int os = 0; os < 2; ++os)
#pragma unroll
          for (int u = 0; u < 4; ++u) {
            f32x4 a4 = acc[os][tg*4 + u];
            a4 = __builtin_amdgcn_mfma_f32_16x16x32_f16(ahi[os], bh[u], a4, 0, 0, 0);
            a4 = __builtin_amdgcn_mfma_f32_16x16x32_f16(alo[os], bh[u], a4, 0, 0, 0);
            a4 = __builtin_amdgcn_mfma_f32_16x16x32_f16(ahi[os], bl[u], a4, 0, 0, 0);
            acc[os][tg*4 + u] = a4;
          }
      }
    }
  }

#pragma unroll
  for (int os = 0; os < 2; ++os) {
    const int ob = o0 + os*16 + quad*4;
    const f32x4 bs4 = *(const f32x4*)(bias + ob);
#pragma unroll
    for (int ts = 0; ts < 8; ++ts) {
      const int t = t0 + ts*16 + n;
      const int tw = ts*16 + n + d;
      const f16x4 phv = *(const f16x4*)(shi + tw*136 + ob);
      const f16x4 plv = *(const f16x4*)(slo + tw*136 + ob);
      f32x4 res;
#pragma unroll
      for (int r = 0; r < 4; ++r) {
        float v = acc[os][ts][r] + bs4[r];
        v = v > 0.f ? v : 0.2f*v;
        res[r] = (float)phv[r] + (float)plv[r] + v;
      }
      *(f32x4*)(hout + (size_t)t*CCH + ob) = res;
    }
  }
}

// ------------------------------------------------------------------
// K2c: LAST layer (d=1), 128-t, with fused stats/attn/context epilogue.
__global__ __launch_bounds__(256) void k_dil_last(
    const float* __restrict__ hin0, const _Float16* __restrict__ whi,
    const _Float16* __restrict__ wlo, const float* __restrict__ bias,
    float* __restrict__ hout0, const int d,
    const float* __restrict__ aw, double* __restrict__ sums,
    float* __restrict__ attnraw, float* __restrict__ pm, const int bb0) {
  extern __shared__ _Float16 sh[];
  const int twin = 128 + 2*d;
  _Float16* shi = sh;
  _Float16* slo = sh + twin*136;
  __shared__ float attl[4*128];
  __shared__ double sred[8];
  const int t0 = blockIdx.x * 128;
  const int b = bb0 + blockIdx.y;
  const size_t bs = (size_t)blockIdx.y * CCH * TSAMP;
  const float* __restrict__ hin = hin0 + bs;
  float* __restrict__ hout = hout0 + bs;
  const int tid = threadIdx.x;

  for (int flat = tid; flat < twin*32; flat += 256) {
    const int tw = flat >> 5;
    const int c4 = (flat & 31) << 2;
    const int g = t0 - d + tw;
    float4 v = {0.f, 0.f, 0.f, 0.f};
    if (g >= 0 && g < TSAMP) v = *(const float4*)(hin + (size_t)g*CCH + c4);
    f16x4 hv, lv;
    hv[0] = (_Float16)v.x; hv[1] = (_Float16)v.y;
    hv[2] = (_Float16)v.z; hv[3] = (_Float16)v.w;
    lv[0] = (_Float16)(v.x - (float)hv[0]); lv[1] = (_Float16)(v.y - (float)hv[1]);
    lv[2] = (_Float16)(v.z - (float)hv[2]); lv[3] = (_Float16)(v.w - (float)hv[3]);
    *(f16x4*)(shi + tw*136 + c4) = hv;
    *(f16x4*)(slo + tw*136 + c4) = lv;
  }
  __syncthreads();

  const int wv = tid >> 6;
  const int lane = tid & 63;
  const int n = lane & 15;
  const int quad = lane >> 4;
  const int o0 = wv * 32;

  f32x4 acc[2][8];
#pragma unroll
  for (int i = 0; i < 2; ++i)
#pragma unroll
    for (int j = 0; j < 8; ++j) acc[i][j] = (f32x4){0.f,0.f,0.f,0.f};

  for (int k = 0; k < 3; ++k) {
    for (int kc = 0; kc < 4; ++kc) {
      const int cib = kc*32 + quad*8;
      f16x8 ahi[2], alo[2];
#pragma unroll
      for (int os = 0; os < 2; ++os) {
        const size_t wo = ((size_t)k*128 + (o0 + os*16 + n))*128 + cib;
        ahi[os] = *(const f16x8*)(whi + wo);
        alo[os] = *(const f16x8*)(wlo + wo);
      }
#pragma unroll
      for (int tg = 0; tg < 2; ++tg) {
        f16x8 bh[4], bl[4];
#pragma unroll
        for (int u = 0; u < 4; ++u) {
          const int a = ((tg*4 + u)*16 + n + k*d)*136 + cib;
          bh[u] = *(const f16x8*)(shi + a);
          bl[u] = *(const f16x8*)(slo + a);
        }
#pragma unroll
        for (int os = 0; os < 2; ++os)
#pragma unroll
          for (int u = 0; u < 4; ++u) {
            f32x4 a4 = acc[os][tg*4 + u];
            a4 = __builtin_amdgcn_mfma_f32_16x16x32_f16(ahi[os], bh[u], a4, 0, 0, 0);
            a4 = __builtin_amdgcn_mfma_f32_16x16x32_f16(alo[os], bh[u], a4, 0, 0, 0);
            a4 = __builtin_amdgcn_mfma_f32_16x16x32_f16(ahi[os], bl[u], a4, 0, 0, 0);
            acc[os][tg*4 + u] = a4;
          }
      }
    }
  }

  const f32x4 awq0 = *(const f32x4*)(aw + o0 + quad*4);
  const f32x4 awq1 = *(const f32x4*)(aw + o0 + 16 + quad*4);
  double s = 0.0, s2 = 0.0;
  float pa[8] = {0.f,0.f,0.f,0.f,0.f,0.f,0.f,0.f};
  f32x4 cm[2];
  cm[0] = (f32x4){-3.4e38f, -3.4e38f, -3.4e38f, -3.4e38f};
  cm[1] = cm[0];

#pragma unroll
  for (int os = 0; os < 2; ++os) {
    const int ob = o0 + os*16 + quad*4;
    const f32x4 bs4 = *(const f32x4*)(bias + ob);
    const f32x4 awv = os ? awq1 : awq0;
#pragma unroll
    for (int ts = 0; ts < 8; ++ts) {
      const int t = t0 + ts*16 + n;
      const int tw = ts*16 + n + d;
      const f16x4 phv = *(const f16x4*)(shi + tw*136 + ob);
      const f16x4 plv = *(const f16x4*)(slo + tw*136 + ob);
      f32x4 res;
      float dotp = 0.f;
#pragma unroll
      for (int r = 0; r < 4; ++r) {
        float v = acc[os][ts][r] + bs4[r];
        v = v > 0.f ? v : 0.2f*v;
        const float hv = (float)phv[r] + (float)plv[r] + v;
        res[r] = hv;
        s += (double)hv; s2 += (double)hv*(double)hv;
        dotp += hv * awv[r];
        cm[os][r] = fmaxf(cm[os][r], hv);
      }
      pa[ts] += dotp;
      *(f32x4*)(hout + (size_t)t*CCH + ob) = res;
    }
  }

#pragma unroll
  for (int ts = 0; ts < 8; ++ts) {
    pa[ts] += __shfl_xor(pa[ts], 16);
    pa[ts] += __shfl_xor(pa[ts], 32);
  }
  if (quad == 0) {
#pragma unroll
    for (int ts = 0; ts < 8; ++ts) attl[wv*128 + ts*16 + n] = pa[ts];
  }
#pragma unroll
  for (int mk = 1; mk <= 8; mk <<= 1)
#pragma unroll
    for (int os = 0; os < 2; ++os)
#pragma unroll
      for (int r = 0; r < 4; ++r)
        cm[os][r] = fmaxf(cm[os][r], __shfl_xor(cm[os][r], mk));
  if (n == 0) {
#pragma unroll
    for (int os = 0; os < 2; ++os)
      *(f32x4*)(pm + ((size_t)b*256 + blockIdx.x)*128 + o0 + os*16 + quad*4) = cm[os];
  }
  for (int sft = 32; sft; sft >>= 1) { s += __shfl_down(s, sft); s2 += __shfl_down(s2, sft); }
  if (lane == 0) { sred[wv*2] = s; sred[wv*2+1] = s2; }
  __syncthreads();
  if (tid < 128)
    attnraw[(size_t)b*TSAMP + t0 + tid] =
        attl[tid] + attl[128 + tid] + attl[256 + tid] + attl[384 + tid];
  if (tid == 0) {
    atomicAdd(&sums[b*2],   sred[0] + sred[2] + sred[4] + sred[6]);
    atomicAdd(&sums[b*2+1], sred[1] + sred[3] + sred[5] + sred[7]);
  }
}

// ------------------------------------------------------------------
// K4: scale[b] = 1/(std_b + 1e-8)
__global__ void k_scale(const double* __restrict__ sums, float* __restrict__ scal) {
  const int b = threadIdx.x;
  if (b < NBATCH) {
    const double n = (double)CCH * (double)TSAMP;
    const double mean = sums[b*2] / n;
    double var = sums[b*2+1] / n - mean*mean;
    if (var < 0.0) var = 0.0;
    scal[b] = (float)(1.0 / (sqrt(var) + 1e-8));
  }
}

// K5b: finish context from 256 partial maxes per batch
__global__ void k_context2(const float* __restrict__ pm, const float* __restrict__ scal,
                           float* __restrict__ ctx) {
  const int b = blockIdx.x;
  const int c = threadIdx.x;   // 128
  float m = -3.4e38f;
  for (int s = 0; s < 256; ++s) m = fmaxf(m, pm[((size_t)b*256 + s)*128 + c]);
  ctx[b*128 + c] = m * scal[b];
}

// ------------------------------------------------------------------
// K7a: per-2048-chunk top-32. Sigmoid computed during staging (identical
// values/ties to the reference attn path); masking argmax per chunk.
__global__ __launch_bounds__(256) void k_topk1(const float* __restrict__ raw,
                                               const float* __restrict__ scal,
                                               const float* __restrict__ ab,
                                               float* __restrict__ cv,
                                               int* __restrict__ cidx) {
  const int ch = blockIdx.x, b = blockIdx.y;
  const float sc = scal[b], bb_ = ab[0];
  const float* a = raw + (size_t)b*TSAMP + ch*2048;
  __shared__ float v[2048];
  __shared__ float rv[4]; __shared__ int ri[4];
  const int tid = threadIdx.x;
  for (int i = tid; i < 2048; i += 256)
    v[i] = 1.f/(1.f+expf(-(a[i]*sc + bb_)));
  __syncthreads();
  for (int e = 0; e < NEV; ++e) {
    float bv = -1e30f; int bi = 0;
    for (int i = tid; i < 2048; i += 256) {
      const float x = v[i];
      if (x > bv) { bv = x; bi = i; }
    }
    for (int s = 32; s; s >>= 1) {
      const float ov = __shfl_down(bv, s); const int oi = __shfl_down(bi, s);
      if (ov > bv || (ov == bv && oi < bi)) { bv = ov; bi = oi; }
    }
    if ((tid & 63) == 0) { rv[tid >> 6] = bv; ri[tid >> 6] = bi; }
    __syncthreads();
    if (tid == 0) {
      int bb = 0;
      for (int w2 = 1; w2 < 4; ++w2)
        if (rv[w2] > rv[bb] || (rv[w2] == rv[bb] && ri[w2] < ri[bb])) bb = w2;
      cv[(b*16 + ch)*NEV + e] = rv[bb];
      cidx[(b*16 + ch)*NEV + e] = ch*2048 + ri[bb];
      v[ri[bb]] = -1e30f;
    }
    __syncthreads();
  }
}

// K7b: final top-32 over 512 candidates
__global__ __launch_bounds__(512) void k_topk2(const float* __restrict__ cv,
                                               const int* __restrict__ ci_,
                                               float* __restrict__ vals,
                                               int* __restrict__ idxs) {
  const int b = blockIdx.x;
  const int tid = threadIdx.x;
  float my = cv[b*512 + tid];
  int   mi = ci_[b*512 + tid];
  __shared__ float rv[8]; __shared__ int ri[8];
  __shared__ float bvs; __shared__ int bis;
  for (int e = 0; e < NEV; ++e) {
    float bv = my; int bi = mi;
    for (int s = 32; s; s >>= 1) {
      const float ov = __shfl_down(bv, s); const int oi = __shfl_down(bi, s);
      if (ov > bv || (ov == bv && oi < bi)) { bv = ov; bi = oi; }
    }
    if ((tid & 63) == 0) { rv[tid >> 6] = bv; ri[tid >> 6] = bi; }
    __syncthreads();
    if (tid == 0) {
      int bb = 0;
      for (int w2 = 1; w2 < 8; ++w2)
        if (rv[w2] > rv[bb] || (rv[w2] == rv[bb] && ri[w2] < ri[bb])) bb = w2;
      vals[b*NEV + e] = rv[bb]; idxs[b*NEV + e] = ri[bb];
      bvs = rv[bb]; bis = ri[bb];
    }
    __syncthreads();
    if (mi == bis && my == bvs) my = -1e30f;
    __syncthreads();
  }
}

// ------------------------------------------------------------------
__device__ __forceinline__ float blk_max128(float v, float* red) {
  const int tid = threadIdx.x;
  red[tid] = v; __syncthreads();
  for (int s = 64; s > 0; s >>= 1) {
    if (tid < s) red[tid] = fmaxf(red[tid], red[tid + s]);
    __syncthreads();
  }
  const float r = red[0]; __syncthreads();
  return r;
}
__device__ __forceinline__ float blk_sum128(float v, float* red) {
  const int tid = threadIdx.x;
  red[tid] = v; __syncthreads();
  for (int s = 64; s > 0; s >>= 1) {
    if (tid < s) red[tid] += red[tid + s];
    __syncthreads();
  }
  const float r = red[0]; __syncthreads();
  return r;
}
__device__ __forceinline__ float mlp_hidden3(float latv, const float* __restrict__ hw,
                                             const float* __restrict__ hb, float* xa) {
  const int tid = threadIdx.x;
  float cur = latv;
  for (int i = 0; i < 3; ++i) {
    xa[tid] = cur; __syncthreads();
    const float* W = hw + (size_t)i*CCH*CCH;
    float acc = hb[i*CCH + tid];
    for (int c = 0; c < CCH; ++c) acc += xa[c] * W[c*CCH + tid];
    cur = acc > 0.f ? acc : 0.2f*acc;
    __syncthreads();
  }
  return cur;
}

// K8: lat + all three MLPs + softmaxes + amps. One 128-thread block per event.
__global__ __launch_bounds__(128) void k_mlp(
    const float* __restrict__ h, const float* __restrict__ scal,
    const float* __restrict__ vals, const int* __restrict__ idxs,
    const float* __restrict__ a_hw, const float* __restrict__ a_hb,
    const float* __restrict__ a_ow, const float* __restrict__ a_ob,
    const float* __restrict__ t_hw, const float* __restrict__ t_hb,
    const float* __restrict__ t_ow, const float* __restrict__ t_ob,
    const float* __restrict__ m_hw, const float* __restrict__ m_hb,
    const float* __restrict__ m_ow, const float* __restrict__ m_ob,
    float* __restrict__ p_atoms, float* __restrict__ p_trans, float* __restrict__ amps) {
  const int row = blockIdx.x;
  const int b = row >> 5;
  const int tid = threadIdx.x;
  __shared__ float xa[CCH];
  __shared__ float red[CCH];
  const int t = idxs[row];
  const float latv = h[((size_t)b*TSAMP + t)*CCH + tid] * scal[b] * vals[row];

  {
    const float cur = mlp_hidden3(latv, a_hw, a_hb, xa);
    xa[tid] = cur; __syncthreads();
    float l0 = a_ob[tid], l1 = a_ob[tid+128], l2 = a_ob[tid+256], l3 = a_ob[tid+384];
    for (int c = 0; c < CCH; ++c) {
      const float xv = xa[c];
      const float* W = a_ow + (size_t)c*NATOMS + tid;
      l0 += xv*W[0]; l1 += xv*W[128]; l2 += xv*W[256]; l3 += xv*W[384];
    }
    const float mx = blk_max128(fmaxf(fmaxf(l0,l1), fmaxf(l2,l3)), red);
    const float e0 = expf(l0-mx), e1 = expf(l1-mx), e2 = expf(l2-mx), e3 = expf(l3-mx);
    const float inv = 1.f / blk_sum128(e0+e1+e2+e3, red);
    float* pa = p_atoms + (size_t)row*NATOMS;
    pa[tid] = e0*inv; pa[tid+128] = e1*inv; pa[tid+256] = e2*inv; pa[tid+384] = e3*inv;
  }
  {
    const float cur = mlp_hidden3(latv, t_hw, t_hb, xa);
    xa[tid] = cur; __syncthreads();
    float lg = -3.4e38f;
    if (tid < NTRANS) {
      float acc = t_ob[tid];
      for (int c = 0; c < CCH; ++c) acc += xa[c]*t_ow[c*NTRANS + tid];
      lg = acc;
    }
    const float mt = blk_max128(lg, red);
    const float et = (tid < NTRANS) ? expf(lg - mt) : 0.f;
    const float st = blk_sum128(et, red);
    if (tid < NTRANS) p_trans[(size_t)row*NTRANS + tid] = et/st;
  }
  {
    const float cur = mlp_hidden3(latv, m_hw, m_hb, xa);
    const float s = blk_sum128(cur * m_ow[tid], red);
    if (tid == 0) { const float v = s + m_ob[0]; amps[row] = v*v; }
  }
}

// K9: atoms_vec[row,:] = p_atoms[row] @ atoms_dict (512x512)
__global__ __launch_bounds__(256) void k_atoms_mm(const float* __restrict__ p_atoms,
                                                  const float* __restrict__ dict,
                                                  float* __restrict__ av) {
  const int row = blockIdx.x;
  __shared__ float p[NATOMS];
  for (int i = threadIdx.x; i < NATOMS; i += 256) p[i] = p_atoms[(size_t)row*NATOMS + i];
  __syncthreads();
  const int s0 = threadIdx.x*2;
  float a0=0, a1=0;
  for (int a = 0; a < NATOMS; ++a) {
    const float pa = p[a];
    const float2 dv = *(const float2*)(dict + (size_t)a*ASIZE + s0);
    a0 += pa*dv.x; a1 += pa*dv.y;
  }
  av[(size_t)row*ASIZE + s0] = a0; av[(size_t)row*ASIZE + s0 + 1] = a1;
}

// K10: transfers[row,:] = p_trans[row] @ transfer_dict (64x8192)
__global__ __launch_bounds__(256) void k_trans_mm(const float* __restrict__ p_trans,
                                                   const float* __restrict__ td,
                                                   float* __restrict__ trans) {
  const int row = blockIdx.y;
  const int t = blockIdx.x*2048 + threadIdx.x*8;
  __shared__ float p[NTRANS];
  if (threadIdx.x < NTRANS) p[threadIdx.x] = p_trans[(size_t)row*NTRANS + threadIdx.x];
  __syncthreads();
  float a0=0,a1=0,a2=0,a3=0,a4=0,a5=0,a6=0,a7=0;
  for (int j = 0; j < NTRANS; ++j) {
    const float pj = p[j];
    const float4 v0 = *(const float4*)(td + (size_t)j*TSIZE + t);
    const float4 v1 = *(const float4*)(td + (size_t)j*TSIZE + t + 4);
    a0 += pj*v0.x; a1 += pj*v0.y; a2 += pj*v0.z; a3 += pj*v0.w;
    a4 += pj*v1.x; a5 += pj*v1.y; a6 += pj*v1.z; a7 += pj*v1.w;
  }
  float* o = trans + (size_t)row*TSIZE + t;
  o[0]=a0; o[1]=a1; o[2]=a2; o[3]=a3; o[4]=a4; o[5]=a5; o[6]=a6; o[7]=a7;
}

// K11: ev conv; rolling window with EPAD skew (8-way -> 2-way LDS conflicts)
__global__ __launch_bounds__(256) void k_ev(const float* __restrict__ trans,
                                            const float* __restrict__ av,
                                            const float* __restrict__ amps,
                                            float* __restrict__ ev) {
  const int row = blockIdx.y;
  const int t0 = blockIdx.x * 1024;
  __shared__ float al[512];
  __shared__ float tw[1584];
  for (int i = threadIdx.x; i < 512; i += 256) al[i] = av[(size_t)row*ASIZE + i];
  for (int i = threadIdx.x; i < 1536; i += 256) {
    const int g = t0 - 512 + i;
    tw[EPAD(i)] = (g >= 0) ? trans[(size_t)row*TSIZE + g] : 0.f;
  }
  __syncthreads();
  const int base = threadIdx.x*4 + 512;
  float a0=0,a1=0,a2=0,a3=0;
  float w0=tw[EPAD(base)], w1=tw[EPAD(base+1)], w2=tw[EPAD(base+2)], w3=tw[EPAD(base+3)];
#pragma unroll 8
  for (int k = 0; k < 512; ++k) {
    const float ak = al[k];
    a0 += ak*w0; a1 += ak*w1; a2 += ak*w2; a3 += ak*w3;
    w3 = w2; w2 = w1; w1 = w0;
    const int p = base - k - 1;
    w0 = tw[EPAD(p)];
  }
  const int n = t0 + threadIdx.x*4;
  const float amp = amps[row];
  float* e = ev + (size_t)row*TSIZE + n;
  e[0] = (a0 + (n+0 < 512 ? al[n+0] : 0.f)) * amp;
  e[1] = (a1 + (n+1 < 512 ? al[n+1] : 0.f)) * amp;
  e[2] = (a2 + (n+2 < 512 ? al[n+2] : 0.f)) * amp;
  e[3] = (a3 + (n+3 < 512 ? al[n+3] : 0.f)) * amp;
}

// K12: overlap-add gather, parallel over (t-chunk, row-slab); atomics into dry.
__global__ __launch_bounds__(256) void k_dry(const float* __restrict__ ev,
                                             const int* __restrict__ idxs,
                                             float* __restrict__ dry) {
  __shared__ int sidx[32];
  const int r0 = blockIdx.y * 32;
  if (threadIdx.x < 32) sidx[threadIdx.x] = idxs[r0 + threadIdx.x];
  __syncthreads();
  const int p = blockIdx.x*512 + threadIdx.x*2;
  float a0=0,a1=0;
  for (int r = 0; r < 32; ++r) {
    const int off = p - sidx[r];
    if (off >= -1 && off < TSIZE) {
      const float* er = ev + (size_t)(r0 + r)*TSIZE;
      if ((unsigned)(off  ) < TSIZE) a0 += er[off];
      if ((unsigned)(off+1) < TSIZE) a1 += er[off+1];
    }
  }
  atomicAdd(dry + p,     a0);
  atomicAdd(dry + p + 1, a1);
}

// K12b: reversed, scaled f16 dry with zero pad (contiguous staging for k_wet)
__global__ __launch_bounds__(256) void k_dryrev(const float* __restrict__ dry,
                                                _Float16* __restrict__ drev) {
  const int i = blockIdx.x*256 + threadIdx.x;
  if (i < TSAMP + 1088)
    drev[i] = (i < TSAMP) ? (_Float16)(dry[TSAMP-1-i] * DRY_SCALE) : (_Float16)0.f;
}

// K13: room softmax + wet/dry mix scalars
__global__ void k_room(const float* __restrict__ ctx, const float* __restrict__ room_w,
                       const float* __restrict__ room_b, const float* __restrict__ mix_w,
                       const float* __restrict__ mix_b, float* __restrict__ roomp,
                       float* __restrict__ mix) {
  const int b = threadIdx.x >> 3;
  const int r = threadIdx.x & 7;
  float acc = room_b[r];
  for (int c = 0; c < CCH; ++c) acc += ctx[b*CCH + c] * room_w[c*8 + r];
  float m = acc;
  for (int s = 1; s < 8; s <<= 1) m = fmaxf(m, __shfl_xor(m, s, 8));
  const float e = expf(acc - m);
  float ssum = e;
  for (int s = 1; s < 8; s <<= 1) ssum += __shfl_xor(ssum, s, 8);
  roomp[b*8 + r] = e / ssum;
  if (r == 0) {
    float a = mix_b[0];
    for (int c = 0; c < CCH; ++c) a += ctx[b*CCH + c] * mix_w[c];
    mix[b] = 1.f/(1.f+expf(-a));
  }
}

// K14: impulse[b,t] -> f16 hi only, ×2^6
__global__ __launch_bounds__(256) void k_impulse(const float* __restrict__ roomp,
                                                 const float* __restrict__ rooms,
                                                 _Float16* __restrict__ ihi) {
  const int b = blockIdx.y;
  const int t = blockIdx.x*1024 + threadIdx.x*4;
  float a0=0,a1=0,a2=0,a3=0;
  for (int r = 0; r < 8; ++r) {
    const float pr = roomp[b*8 + r];
    const float4 v = *(const float4*)(rooms + (size_t)r*TSAMP + t);
    a0 += pr*v.x; a1 += pr*v.y; a2 += pr*v.z; a3 += pr*v.w;
  }
  _Float16* oh = ihi + (size_t)b*TSAMP + t;
  oh[0] = (_Float16)(a0*IMP_SCALE); oh[1] = (_Float16)(a1*IMP_SCALE);
  oh[2] = (_Float16)(a2*IMP_SCALE); oh[3] = (_Float16)(a3*IMP_SCALE);
}

// K15: reverb conv via f16 MFMA (hi-only), N=512/block, k-slab 4096.
__global__ __launch_bounds__(256) void k_wet_mfma(
    const _Float16* __restrict__ drev, const _Float16* __restrict__ ihi,
    float* __restrict__ wet) {
  const int t0 = blockIdx.x * 512;
  const int k0 = blockIdx.y * 4096;
  if (k0 > t0 + 511) return;
  __shared__ _Float16 rhi[8*1048];
  const int tid = threadIdx.x;
  const int wv = tid >> 6;
  const int lane = tid & 63;
  const int n16 = lane & 15;
  const int quad = lane >> 4;
  const int m = n16;

  f32x4 acc[8];
#pragma unroll
  for (int j = 0; j < 8; ++j) acc[j] = (f32x4){0.f,0.f,0.f,0.f};

  const int kend = (k0 + 4096 < t0 + 512) ? k0 + 4096 : t0 + 512;
  const int ph = 7 - (n16 & 7);
  for (int kc0 = k0; kc0 < kend; kc0 += 512) {
    const int RB = TSAMP - 1 - (t0 + 511 - kc0);
    for (int flat = tid; flat < 8*1016; flat += 256) {
      const int p = flat / 1016;
      const int q = flat - p*1016;
      rhi[p*1048 + q] = drev[RB + p + q];
    }
    __syncthreads();

#pragma unroll 4
    for (int kc = 0; kc < 16; ++kc) {
      const int kb = kc*32;
      const int jg = kc0 + kb + quad*8;
      f16x8 ah;
      if (m < NBATCH) ah = *(const f16x8*)(ihi + (size_t)m*TSAMP + jg);
      else ah = (f16x8){0,0,0,0,0,0,0,0};
#pragma unroll
      for (int ts = 0; ts < 8; ++ts) {
        const int nn = wv*128 + ts*16 + n16;
        const int a = ph*1048 + kb + quad*8 + 504 - (nn & ~7);
        const f16x8 bh = *(const f16x8*)(rhi + a);
        acc[ts] = __builtin_amdgcn_mfma_f32_16x16x32_f16(ah, bh, acc[ts], 0, 0, 0);
      }
    }
    __syncthreads();
  }

#pragma unroll
  for (int ts = 0; ts < 8; ++ts) {
    const int t = t0 + wv*128 + ts*16 + n16;
#pragma unroll
    for (int r = 0; r < 4; ++r) {
      const int b = quad*4 + r;
      if (b < NBATCH)
        atomicAdd(wet + (size_t)b*TSAMP + t, acc[ts][r] * WET_DESCALE);
    }
  }
}

// K16: out = dry*(1-mix) + wet*mix
__global__ __launch_bounds__(256) void k_out(const float* __restrict__ dry,
                                             const float* __restrict__ wet,
                                             const float* __restrict__ mix,
                                             float* __restrict__ out) {
  const int b = blockIdx.y;
  const int t = blockIdx.x*1024 + threadIdx.x*4;
  const float m = mix[b];
  const float4 d = *(const float4*)(dry + t);
  const float4 w = *(const float4*)(wet + (size_t)b*TSAMP + t);
  float* o = out + (size_t)b*TSAMP + t;
  o[0] = d.x*(1.f-m) + w.x*m;
  o[1] = d.y*(1.f-m) + w.y*m;
  o[2] = d.z*(1.f-m) + w.z*m;
  o[3] = d.w*(1.f-m) + w.w*m;
}

// ------------------------------------------------------------------
extern "C" void kernel_launch(void* const* d_in, const int* in_sizes, int n_in,
                              void* d_out, int out_size, void* d_ws, size_t ws_size,
                              hipStream_t stream) {
  (void)in_sizes; (void)n_in; (void)out_size; (void)ws_size;
  const float* x      = (const float*)d_in[0];
  const float* bank   = (const float*)d_in[1];
  const float* w_net  = (const float*)d_in[2];
  const float* b_net  = (const float*)d_in[3];
  const float* attn_w = (const float*)d_in[4];
  const float* attn_b = (const float*)d_in[5];
  const float* a_hw = (const float*)d_in[6];
  const float* a_hb = (const float*)d_in[7];
  const float* a_ow = (const float*)d_in[8];
  const float* a_ob = (const float*)d_in[9];
  const float* t_hw = (const float*)d_in[10];
  const float* t_hb = (const float*)d_in[11];
  const float* t_ow = (const float*)d_in[12];
  const float* t_ob = (const float*)d_in[13];
  const float* m_hw = (const float*)d_in[14];
  const float* m_hb = (const float*)d_in[15];
  const float* m_ow = (const float*)d_in[16];
  const float* m_ob = (const float*)d_in[17];
  const float* atoms_dict    = (const float*)d_in[18];
  const float* transfer_dict = (const float*)d_in[19];
  const float* rooms  = (const float*)d_in[20];
  const float* room_w = (const float*)d_in[21];
  const float* room_b = (const float*)d_in[22];
  const float* mix_w  = (const float*)d_in[23];
  const float* mix_b  = (const float*)d_in[24];
  float* out = (float*)d_out;

  // ---- workspace (~206 MB): H | t1 | t2 | weights | stats(dedicated)
  float* ws = (float*)d_ws;
  float* H  = ws;                                    // [B][T][C]
  float* t1 = ws + (size_t)33554432;
  float* t2 = ws + (size_t)41943040;
  _Float16* whi = (_Float16*)(ws + (size_t)50331648);
  _Float16* wlo = (_Float16*)(ws + (size_t)50454528);
  _Float16* bhi = (_Float16*)(ws + (size_t)50577408);
  _Float16* blo = (_Float16*)(ws + (size_t)50610176);
  double* sums  = (double*)(ws + (size_t)50642944);  // 16 doubles
  float* attnraw = ws + (size_t)50642976;            // 8*32768
  float* pm      = ws + (size_t)50905120;            // 8*256*128

  size_t off = 33554432;                             // scratch base (aliases t1)
  float* scal  = ws + off; off += 8;
  float* ctx   = ws + off; off += NBATCH*CCH;
  float* vals  = ws + off; off += NROWS;
  int*   idxs  = (int*)(ws + off); off += NROWS;
  float* p_atoms = ws + off; off += (size_t)NROWS*NATOMS;
  float* p_trans = ws + off; off += (size_t)NROWS*NTRANS;
  float* amps  = ws + off; off += NROWS;
  float* av    = ws + off; off += (size_t)NROWS*ASIZE;
  float* trans = ws + off; off += (size_t)NROWS*TSIZE;
  float* ev    = ws + off; off += (size_t)NROWS*TSIZE;
  float* dry   = ws + off; off += TSAMP;
  float* roomp = ws + off; off += 64;
  float* mix   = ws + off; off += 8;
  float* wet   = ws + off; off += (size_t)NBATCH*TSAMP;
  float* cand_v = ws + off; off += 4096;
  int*   cand_i = (int*)(ws + off); off += 4096;
  _Float16* imphi = (_Float16*)(ws + off); off += (size_t)NBATCH*TSAMP/2;
  _Float16* drev  = (_Float16*)(ws + off); off += (TSAMP + 1088)/2 + 4;
  // scratch ends ~38.7M floats < 50.33M — disjoint from weights/stats.

  k_zs<<<1, 64, 0, stream>>>(sums);
  k_wsplit<<<960, 256, 0, stream>>>(w_net, whi, wlo);
  k_bsplit<<<256, 256, 0, stream>>>(bank, bhi, blo);
  k_front_mfma<<<dim3(256, 8), 256, 0, stream>>>(x, bhi, blo, H);

  const int dil[5] = {1, 3, 9, 27, 1};
  const size_t S = (size_t)CCH * TSAMP;
  for (int p = 0; p < 4; ++p) {            // 2 batches per dispatch
    float* Hp = H + (size_t)(2*p) * S;
    float* io[6] = {Hp, t1, t2, t1, t2, Hp};
    for (int i = 0; i < 3; ++i) {          // d = 1, 3, 9: 128-t tiles
      const int d = dil[i];
      const size_t smem = (size_t)(128 + 2*d) * 544;
      k_dil128<<<dim3(256, 2), 256, smem, stream>>>(
          io[i], whi + (size_t)i*49152, wlo + (size_t)i*49152, b_net + i*CCH,
          io[i+1], d);
    }
    {                                      // d = 27: 64-t tiles
      const int d = dil[3];
      const size_t smem = (size_t)(64 + 2*d) * 544;
      k_dil_mfma<<<dim3(512, 2), 256, smem, stream>>>(
          io[3], whi + (size_t)3*49152, wlo + (size_t)3*49152, b_net + 3*CCH,
          io[4], d);
    }
    {                                      // last layer d=1: 128-t + stats
      const int d = dil[4];
      const size_t smem = (size_t)(128 + 2*d) * 544;
      k_dil_last<<<dim3(256, 2), 256, smem, stream>>>(
          io[4], whi + (size_t)4*49152, wlo + (size_t)4*49152, b_net + 4*CCH,
          io[5], d, attn_w, sums, attnraw, pm, 2*p);
    }
  }

  k_zero<<<1024, 256, 0, stream>>>(wet, dry);
  k_scale<<<1, 64, 0, stream>>>(sums, scal);
  k_context2<<<8, 128, 0, stream>>>(pm, scal, ctx);
  k_topk1<<<dim3(16, 8), 256, 0, stream>>>(attnraw, scal, attn_b, cand_v, cand_i);
  k_topk2<<<8, 512, 0, stream>>>(cand_v, cand_i, vals, idxs);
  k_mlp<<<256, 128, 0, stream>>>(H, scal, vals, idxs,
                                 a_hw, a_hb, a_ow, a_ob,
                                 t_hw, t_hb, t_ow, t_ob,
                                 m_hw, m_hb, m_ow, m_ob,
                                 p_atoms, p_trans, amps);
  k_atoms_mm<<<256, 256, 0, stream>>>(p_atoms, atoms_dict, av);
  k_trans_mm<<<dim3(4, 256), 256, 0, stream>>>(p_trans, transfer_dict, trans);
  k_ev<<<dim3(8, 256), 256, 0, stream>>>(trans, av, amps, ev);
  k_dry<<<dim3(64, 8), 256, 0, stream>>>(ev, idxs, dry);
  k_dryrev<<<133, 256, 0, stream>>>(dry, drev);
  k_room<<<1, 64, 0, stream>>>(ctx, room_w, room_b, mix_w, mix_b, roomp, mix);
  k_impulse<<<dim3(32, 8), 256, 0, stream>>>(roomp, rooms, imphi);
  k_wet_mfma<<<dim3(64, 8), 256, 0, stream>>>(drev, imphi, wet);
  k_out<<<dim3(32, 8), 256, 0, stream>>>(dry, wet, mix, out);
}

// Round 11
// 1204.748 us; speedup vs baseline: 7.3670x; 1.0044x over previous
//
#include <hip/hip_runtime.h>
#include <math.h>

#define TSAMP 32768
#define CCH 128
#define NBATCH 8
#define NEV 32
#define NROWS 256   // NBATCH*NEV
#define NATOMS 512
#define ASIZE 512
#define NTRANS 64
#define TSIZE 8192

#define DRY_SCALE 16777216.0f               // 2^24
#define IMP_SCALE 64.0f                     // 2^6
#define WET_DESCALE 9.313225746154785e-10f  // 2^-30

// LDS skew for stride-4 lane patterns: 8-way conflict -> 2-way (free)
#define EPAD(i) ((i) + ((i) >> 5))

typedef _Float16 f16x8 __attribute__((ext_vector_type(8)));
typedef _Float16 f16x4 __attribute__((ext_vector_type(4)));
typedef float f32x4 __attribute__((ext_vector_type(4)));

// activations stored [B][T][C] (c contiguous).

// ------------------------------------------------------------------
// K-prep: split conv weights ([layer][k][o][ci]) + filter bank ([c][k]) to
// f16 hi/lo, and zero the f64 stat sums. One dispatch.
__global__ __launch_bounds__(256) void k_prep(const float* __restrict__ wn,
                                              const float* __restrict__ bank,
                                              _Float16* __restrict__ whi,
                                              _Float16* __restrict__ wlo,
                                              _Float16* __restrict__ bhi,
                                              _Float16* __restrict__ blo,
                                              double* __restrict__ sums) {
  const int i = blockIdx.x * 256 + threadIdx.x;
  if (i < 16) sums[i] = 0.0;
  if (i < 245760) {
    const int ci = i & 127;
    int r = i >> 7;
    const int o = r & 127;
    r >>= 7;
    const int k = r % 3;
    const int l = r / 3;
    const float w = wn[(((size_t)l*128 + o)*128 + ci)*3 + k];
    const _Float16 hi = (_Float16)w;
    whi[i] = hi;
    wlo[i] = (_Float16)(w - (float)hi);
  } else if (i < 311296) {
    const int j = i - 245760;
    const float w = bank[j];
    const _Float16 hi = (_Float16)w;
    bhi[j] = hi;
    blo[j] = (_Float16)(w - (float)hi);
  }
}

// K0: zero wet accumulator + drev zero-pad tail
__global__ __launch_bounds__(256) void k_zero(float* __restrict__ wet,
                                              _Float16* __restrict__ drev) {
  int i = blockIdx.x * 256 + threadIdx.x;
  if (i < NBATCH * TSAMP) wet[i] = 0.f;
  if (i < 1088) drev[TSAMP + i] = (_Float16)0.f;
}

// ------------------------------------------------------------------
// K1: front filter bank via split-f16 MFMA, 128-t blocks (8 ts tiles/wave).
__global__ __launch_bounds__(256) void k_front_mfma(
    const float* __restrict__ x, const _Float16* __restrict__ bhi,
    const _Float16* __restrict__ blo, float* __restrict__ h) {
  __shared__ _Float16 shi[8*664];
  __shared__ _Float16 slo[8*664];
  const int t0 = blockIdx.x * 128;
  const int b  = blockIdx.y;
  const float* xb = x + (size_t)b*TSAMP;
  const int tid = threadIdx.x;

  for (int flat = tid; flat < 8*632; flat += 256) {
    const int p = flat / 632;
    const int q = flat - p*632;
    const int g = t0 - 256 + q + p;
    const float v = (g >= 0 && g < TSAMP) ? xb[g] : 0.f;
    const _Float16 hi = (_Float16)v;
    shi[p*664 + q] = hi;
    slo[p*664 + q] = (_Float16)(v - (float)hi);
  }
  __syncthreads();

  const int wv = tid >> 6;
  const int lane = tid & 63;
  const int n = lane & 15;
  const int quad = lane >> 4;
  const int c0 = wv * 32;
  const int ph = n & 7;
  const int nb = n & 8;

  f32x4 acc[2][8];
#pragma unroll
  for (int i = 0; i < 2; ++i)
#pragma unroll
    for (int j = 0; j < 8; ++j) acc[i][j] = (f32x4){0.f,0.f,0.f,0.f};

  for (int kc = 0; kc < 16; ++kc) {
    const int kb = kc*32 + quad*8;
    f16x8 ahi[2], alo[2];
#pragma unroll
    for (int os = 0; os < 2; ++os) {
      const size_t ao = (size_t)(c0 + os*16 + n)*512 + kb;
      ahi[os] = *(const f16x8*)(bhi + ao);
      alo[os] = *(const f16x8*)(blo + ao);
    }
#pragma unroll
    for (int tg = 0; tg < 2; ++tg) {
      f16x8 xh[4], xl[4];
#pragma unroll
      for (int u = 0; u < 4; ++u) {
        const int a = ph*664 + (tg*4 + u)*16 + nb + kb;
        xh[u] = *(const f16x8*)(shi + a);
        xl[u] = *(const f16x8*)(slo + a);
      }
#pragma unroll
      for (int os = 0; os < 2; ++os)
#pragma unroll
        for (int u = 0; u < 4; ++u) {
          f32x4 a4 = acc[os][tg*4 + u];
          a4 = __builtin_amdgcn_mfma_f32_16x16x32_f16(ahi[os], xh[u], a4, 0, 0, 0);
          a4 = __builtin_amdgcn_mfma_f32_16x16x32_f16(alo[os], xh[u], a4, 0, 0, 0);
          a4 = __builtin_amdgcn_mfma_f32_16x16x32_f16(ahi[os], xl[u], a4, 0, 0, 0);
          acc[os][tg*4 + u] = a4;
        }
    }
  }

  float* hb = h + (size_t)b*TSAMP*CCH;
#pragma unroll
  for (int os = 0; os < 2; ++os) {
    const int cb = c0 + os*16 + quad*4;
#pragma unroll
    for (int ts = 0; ts < 8; ++ts) {
      const int t = t0 + ts*16 + n;
      *(f32x4*)(hb + (size_t)t*CCH + cb) = acc[os][ts];
    }
  }
}

// ------------------------------------------------------------------
// K2a: 80-t dilated conv layer for d=27 (LDS 72.9 KB -> 2 blocks/CU).
__global__ __launch_bounds__(256) void k_dil80(
    const float* __restrict__ hin0, const _Float16* __restrict__ whi,
    const _Float16* __restrict__ wlo, const float* __restrict__ bias,
    float* __restrict__ hout0) {
  const int d = 27;
  extern __shared__ _Float16 sh[];
  const int twin = 80 + 2*d;              // 134
  _Float16* shi = sh;
  _Float16* slo = sh + twin*136;
  const int t0 = blockIdx.x * 80;
  const size_t bs = (size_t)blockIdx.y * CCH * TSAMP;
  const float* __restrict__ hin = hin0 + bs;
  float* __restrict__ hout = hout0 + bs;
  const int tid = threadIdx.x;

  for (int flat = tid; flat < twin*32; flat += 256) {
    const int tw = flat >> 5;
    const int c4 = (flat & 31) << 2;
    const int g = t0 - d + tw;
    float4 v = {0.f, 0.f, 0.f, 0.f};
    if (g >= 0 && g < TSAMP) v = *(const float4*)(hin + (size_t)g*CCH + c4);
    f16x4 hv, lv;
    hv[0] = (_Float16)v.x; hv[1] = (_Float16)v.y;
    hv[2] = (_Float16)v.z; hv[3] = (_Float16)v.w;
    lv[0] = (_Float16)(v.x - (float)hv[0]); lv[1] = (_Float16)(v.y - (float)hv[1]);
    lv[2] = (_Float16)(v.z - (float)hv[2]); lv[3] = (_Float16)(v.w - (float)hv[3]);
    *(f16x4*)(shi + tw*136 + c4) = hv;
    *(f16x4*)(slo + tw*136 + c4) = lv;
  }
  __syncthreads();

  const int wv = tid >> 6;
  const int lane = tid & 63;
  const int n = lane & 15;
  const int quad = lane >> 4;
  const int o0 = wv * 32;

  f32x4 acc[2][5];
#pragma unroll
  for (int i = 0; i < 2; ++i)
#pragma unroll
    for (int j = 0; j < 5; ++j) acc[i][j] = (f32x4){0.f,0.f,0.f,0.f};

  for (int k = 0; k < 3; ++k) {
    for (int kc = 0; kc < 4; ++kc) {
      const int cib = kc*32 + quad*8;
      f16x8 ahi[2], alo[2];
#pragma unroll
      for (int os = 0; os < 2; ++os) {
        const size_t wo = ((size_t)k*128 + (o0 + os*16 + n))*128 + cib;
        ahi[os] = *(const f16x8*)(whi + wo);
        alo[os] = *(const f16x8*)(wlo + wo);
      }
      f16x8 bh[5], bl[5];
#pragma unroll
      for (int ts = 0; ts < 5; ++ts) {
        const int a = (ts*16 + n + k*d)*136 + cib;
        bh[ts] = *(const f16x8*)(shi + a);
        bl[ts] = *(const f16x8*)(slo + a);
      }
#pragma unroll
      for (int os = 0; os < 2; ++os)
#pragma unroll
        for (int ts = 0; ts < 5; ++ts) {
          acc[os][ts] = __builtin_amdgcn_mfma_f32_16x16x32_f16(ahi[os], bh[ts], acc[os][ts], 0, 0, 0);
          acc[os][ts] = __builtin_amdgcn_mfma_f32_16x16x32_f16(alo[os], bh[ts], acc[os][ts], 0, 0, 0);
          acc[os][ts] = __builtin_amdgcn_mfma_f32_16x16x32_f16(ahi[os], bl[ts], acc[os][ts], 0, 0, 0);
        }
    }
  }

#pragma unroll
  for (int os = 0; os < 2; ++os) {
    const int ob = o0 + os*16 + quad*4;
    const f32x4 bs4 = *(const f32x4*)(bias + ob);
#pragma unroll
    for (int ts = 0; ts < 5; ++ts) {
      const int t = t0 + ts*16 + n;
      if (t < TSAMP) {
        const int tw = ts*16 + n + d;
        const f16x4 phv = *(const f16x4*)(shi + tw*136 + ob);
        const f16x4 plv = *(const f16x4*)(slo + tw*136 + ob);
        f32x4 res;
#pragma unroll
        for (int r = 0; r < 4; ++r) {
          float v = acc[os][ts][r] + bs4[r];
          v = v > 0.f ? v : 0.2f*v;
          res[r] = (float)phv[r] + (float)plv[r] + v;
        }
        *(f32x4*)(hout + (size_t)t*CCH + ob) = res;
      }
    }
  }
}

// ------------------------------------------------------------------
// K2b: 128-t dilated conv layer (d<=9): 576 MFMA/wave, 8 acc chains.
__global__ __launch_bounds__(256) void k_dil128(
    const float* __restrict__ hin0, const _Float16* __restrict__ whi,
    const _Float16* __restrict__ wlo, const float* __restrict__ bias,
    float* __restrict__ hout0, const int d) {
  extern __shared__ _Float16 sh[];
  const int twin = 128 + 2*d;
  _Float16* shi = sh;
  _Float16* slo = sh + twin*136;
  const int t0 = blockIdx.x * 128;
  const size_t bs = (size_t)blockIdx.y * CCH * TSAMP;
  const float* __restrict__ hin = hin0 + bs;
  float* __restrict__ hout = hout0 + bs;
  const int tid = threadIdx.x;

  for (int flat = tid; flat < twin*32; flat += 256) {
    const int tw = flat >> 5;
    const int c4 = (flat & 31) << 2;
    const int g = t0 - d + tw;
    float4 v = {0.f, 0.f, 0.f, 0.f};
    if (g >= 0 && g < TSAMP) v = *(const float4*)(hin + (size_t)g*CCH + c4);
    f16x4 hv, lv;
    hv[0] = (_Float16)v.x; hv[1] = (_Float16)v.y;
    hv[2] = (_Float16)v.z; hv[3] = (_Float16)v.w;
    lv[0] = (_Float16)(v.x - (float)hv[0]); lv[1] = (_Float16)(v.y - (float)hv[1]);
    lv[2] = (_Float16)(v.z - (float)hv[2]); lv[3] = (_Float16)(v.w - (float)hv[3]);
    *(f16x4*)(shi + tw*136 + c4) = hv;
    *(f16x4*)(slo + tw*136 + c4) = lv;
  }
  __syncthreads();

  const int wv = tid >> 6;
  const int lane = tid & 63;
  const int n = lane & 15;
  const int quad = lane >> 4;
  const int o0 = wv * 32;

  f32x4 acc[2][8];
#pragma unroll
  for (int i = 0; i < 2; ++i)
#pragma unroll
    for (int j = 0; j < 8; ++j) acc[i][j] = (f32x4){0.f,0.f,0.f,0.f};

  for (int k = 0; k < 3; ++k) {
    for (int kc = 0; kc < 4; ++kc) {
      const int cib = kc*32 + quad*8;
      f16x8 ahi[2], alo[2];
#pragma unroll
      for (int os = 0; os < 2; ++os) {
        const size_t wo = ((size_t)k*128 + (o0 + os*16 + n))*128 + cib;
        ahi[os] = *(const f16x8*)(whi + wo);
        alo[os] = *(const f16x8*)(wlo + wo);
      }
#pragma unroll
      for (int tg = 0; tg < 2; ++tg) {
        f16x8 bh[4], bl[4];
#pragma unroll
        for (int u = 0; u < 4; ++u) {
          const int a = ((tg*4 + u)*16 + n + k*d)*136 + cib;
          bh[u] = *(const f16x8*)(shi + a);
          bl[u] = *(const f16x8*)(slo + a);
        }
#pragma unroll
        for (int os = 0; os < 2; ++os)
#pragma unroll
          for (int u = 0; u < 4; ++u) {
            f32x4 a4 = acc[os][tg*4 + u];
            a4 = __builtin_amdgcn_mfma_f32_16x16x32_f16(ahi[os], bh[u], a4, 0, 0, 0);
            a4 = __builtin_amdgcn_mfma_f32_16x16x32_f16(alo[os], bh[u], a4, 0, 0, 0);
            a4 = __builtin_amdgcn_mfma_f32_16x16x32_f16(ahi[os], bl[u], a4, 0, 0, 0);
            acc[os][tg*4 + u] = a4;
          }
      }
    }
  }

#pragma unroll
  for (int os = 0; os < 2; ++os) {
    const int ob = o0 + os*16 + quad*4;
    const f32x4 bs4 = *(const f32x4*)(bias + ob);
#pragma unroll
    for (int ts = 0; ts < 8; ++ts) {
      const int t = t0 + ts*16 + n;
      const int tw = ts*16 + n + d;
      const f16x4 phv = *(const f16x4*)(shi + tw*136 + ob);
      const f16x4 plv = *(const f16x4*)(slo + tw*136 + ob);
      f32x4 res;
#pragma unroll
      for (int r = 0; r < 4; ++r) {
        float v = acc[os][ts][r] + bs4[r];
        v = v > 0.f ? v : 0.2f*v;
        res[r] = (float)phv[r] + (float)plv[r] + v;
      }
      *(f32x4*)(hout + (size_t)t*CCH + ob) = res;
    }
  }
}

// ------------------------------------------------------------------
// K2c: LAST layer (d=1), 128-t, with fused stats/attn/context epilogue.
__global__ __launch_bounds__(256) void k_dil_last(
    const float* __restrict__ hin0, const _Float16* __restrict__ whi,
    const _Float16* __restrict__ wlo, const float* __restrict__ bias,
    float* __restrict__ hout0, const int d,
    const float* __restrict__ aw, double* __restrict__ sums,
    float* __restrict__ attnraw, float* __restrict__ pm, const int bb0) {
  extern __shared__ _Float16 sh[];
  const int twin = 128 + 2*d;
  _Float16* shi = sh;
  _Float16* slo = sh + twin*136;
  __shared__ float attl[4*128];
  __shared__ double sred[8];
  const int t0 = blockIdx.x * 128;
  const int b = bb0 + blockIdx.y;
  const size_t bs = (size_t)blockIdx.y * CCH * TSAMP;
  const float* __restrict__ hin = hin0 + bs;
  float* __restrict__ hout = hout0 + bs;
  const int tid = threadIdx.x;

  for (int flat = tid; flat < twin*32; flat += 256) {
    const int tw = flat >> 5;
    const int c4 = (flat & 31) << 2;
    const int g = t0 - d + tw;
    float4 v = {0.f, 0.f, 0.f, 0.f};
    if (g >= 0 && g < TSAMP) v = *(const float4*)(hin + (size_t)g*CCH + c4);
    f16x4 hv, lv;
    hv[0] = (_Float16)v.x; hv[1] = (_Float16)v.y;
    hv[2] = (_Float16)v.z; hv[3] = (_Float16)v.w;
    lv[0] = (_Float16)(v.x - (float)hv[0]); lv[1] = (_Float16)(v.y - (float)hv[1]);
    lv[2] = (_Float16)(v.z - (float)hv[2]); lv[3] = (_Float16)(v.w - (float)hv[3]);
    *(f16x4*)(shi + tw*136 + c4) = hv;
    *(f16x4*)(slo + tw*136 + c4) = lv;
  }
  __syncthreads();

  const int wv = tid >> 6;
  const int lane = tid & 63;
  const int n = lane & 15;
  const int quad = lane >> 4;
  const int o0 = wv * 32;

  f32x4 acc[2][8];
#pragma unroll
  for (int i = 0; i < 2; ++i)
#pragma unroll
    for (int j = 0; j < 8; ++j) acc[i][j] = (f32x4){0.f,0.f,0.f,0.f};

  for (int k = 0; k < 3; ++k) {
    for (int kc = 0; kc < 4; ++kc) {
      const int cib = kc*32 + quad*8;
      f16x8 ahi[2], alo[2];
#pragma unroll
      for (int os = 0; os < 2; ++os) {
        const size_t wo = ((size_t)k*128 + (o0 + os*16 + n))*128 + cib;
        ahi[os] = *(const f16x8*)(whi + wo);
        alo[os] = *(const f16x8*)(wlo + wo);
      }
#pragma unroll
      for (int tg = 0; tg < 2; ++tg) {
        f16x8 bh[4], bl[4];
#pragma unroll
        for (int u = 0; u < 4; ++u) {
          const int a = ((tg*4 + u)*16 + n + k*d)*136 + cib;
          bh[u] = *(const f16x8*)(shi + a);
          bl[u] = *(const f16x8*)(slo + a);
        }
#pragma unroll
        for (int os = 0; os < 2; ++os)
#pragma unroll
          for (int u = 0; u < 4; ++u) {
            f32x4 a4 = acc[os][tg*4 + u];
            a4 = __builtin_amdgcn_mfma_f32_16x16x32_f16(ahi[os], bh[u], a4, 0, 0, 0);
            a4 = __builtin_amdgcn_mfma_f32_16x16x32_f16(alo[os], bh[u], a4, 0, 0, 0);
            a4 = __builtin_amdgcn_mfma_f32_16x16x32_f16(ahi[os], bl[u], a4, 0, 0, 0);
            acc[os][tg*4 + u] = a4;
          }
      }
    }
  }

  const f32x4 awq0 = *(const f32x4*)(aw + o0 + quad*4);
  const f32x4 awq1 = *(const f32x4*)(aw + o0 + 16 + quad*4);
  double s = 0.0, s2 = 0.0;
  float pa[8] = {0.f,0.f,0.f,0.f,0.f,0.f,0.f,0.f};
  f32x4 cm[2];
  cm[0] = (f32x4){-3.4e38f, -3.4e38f, -3.4e38f, -3.4e38f};
  cm[1] = cm[0];

#pragma unroll
  for (int os = 0; os < 2; ++os) {
    const int ob = o0 + os*16 + quad*4;
    const f32x4 bs4 = *(const f32x4*)(bias + ob);
    const f32x4 awv = os ? awq1 : awq0;
#pragma unroll
    for (int ts = 0; ts < 8; ++ts) {
      const int t = t0 + ts*16 + n;
      const int tw = ts*16 + n + d;
      const f16x4 phv = *(const f16x4*)(shi + tw*136 + ob);
      const f16x4 plv = *(const f16x4*)(slo + tw*136 + ob);
      f32x4 res;
      float dotp = 0.f;
#pragma unroll
      for (int r = 0; r < 4; ++r) {
        float v = acc[os][ts][r] + bs4[r];
        v = v > 0.f ? v : 0.2f*v;
        const float hv = (float)phv[r] + (float)plv[r] + v;
        res[r] = hv;
        s += (double)hv; s2 += (double)hv*(double)hv;
        dotp += hv * awv[r];
        cm[os][r] = fmaxf(cm[os][r], hv);
      }
      pa[ts] += dotp;
      *(f32x4*)(hout + (size_t)t*CCH + ob) = res;
    }
  }

#pragma unroll
  for (int ts = 0; ts < 8; ++ts) {
    pa[ts] += __shfl_xor(pa[ts], 16);
    pa[ts] += __shfl_xor(pa[ts], 32);
  }
  if (quad == 0) {
#pragma unroll
    for (int ts = 0; ts < 8; ++ts) attl[wv*128 + ts*16 + n] = pa[ts];
  }
#pragma unroll
  for (int mk = 1; mk <= 8; mk <<= 1)
#pragma unroll
    for (int os = 0; os < 2; ++os)
#pragma unroll
      for (int r = 0; r < 4; ++r)
        cm[os][r] = fmaxf(cm[os][r], __shfl_xor(cm[os][r], mk));
  if (n == 0) {
#pragma unroll
    for (int os = 0; os < 2; ++os)
      *(f32x4*)(pm + ((size_t)b*256 + blockIdx.x)*128 + o0 + os*16 + quad*4) = cm[os];
  }
  for (int sft = 32; sft; sft >>= 1) { s += __shfl_down(s, sft); s2 += __shfl_down(s2, sft); }
  if (lane == 0) { sred[wv*2] = s; sred[wv*2+1] = s2; }
  __syncthreads();
  if (tid < 128)
    attnraw[(size_t)b*TSAMP + t0 + tid] =
        attl[tid] + attl[128 + tid] + attl[256 + tid] + attl[384 + tid];
  if (tid == 0) {
    atomicAdd(&sums[b*2],   sred[0] + sred[2] + sred[4] + sred[6]);
    atomicAdd(&sums[b*2+1], sred[1] + sred[3] + sred[5] + sred[7]);
  }
}

// ------------------------------------------------------------------
// K-finish: per-batch scale + context (LDS only) + room softmax + mix.
// One block per batch, 128 threads.
__global__ __launch_bounds__(128) void k_finish(
    const double* __restrict__ sums, const float* __restrict__ pm,
    const float* __restrict__ room_w, const float* __restrict__ room_b,
    const float* __restrict__ mix_w, const float* __restrict__ mix_b,
    float* __restrict__ scal, float* __restrict__ roomp, float* __restrict__ mix) {
  const int b = blockIdx.x;
  const int tid = threadIdx.x;
  __shared__ float bs;
  __shared__ float ctx[128];
  if (tid == 0) {
    const double nn = (double)CCH * (double)TSAMP;
    const double mean = sums[b*2] / nn;
    double var = sums[b*2+1] / nn - mean*mean;
    if (var < 0.0) var = 0.0;
    const float sc = (float)(1.0 / (sqrt(var) + 1e-8));
    bs = sc;
    scal[b] = sc;
  }
  __syncthreads();
  float m = -3.4e38f;
  for (int s = 0; s < 256; ++s) m = fmaxf(m, pm[((size_t)b*256 + s)*128 + tid]);
  ctx[tid] = m * bs;
  __syncthreads();
  if (tid < 8) {
    const int r = tid;
    float acc = room_b[r];
    for (int c = 0; c < CCH; ++c) acc += ctx[c] * room_w[c*8 + r];
    float mm = acc;
    for (int s = 1; s < 8; s <<= 1) mm = fmaxf(mm, __shfl_xor(mm, s, 8));
    const float e = expf(acc - mm);
    float ss = e;
    for (int s = 1; s < 8; s <<= 1) ss += __shfl_xor(ss, s, 8);
    roomp[b*8 + r] = e / ss;
  } else if (tid == 8) {
    float a = mix_b[0];
    for (int c = 0; c < CCH; ++c) a += ctx[c] * mix_w[c];
    mix[b] = 1.f/(1.f+expf(-a));
  }
}

// ------------------------------------------------------------------
// K7a: per-2048-chunk top-32 (sigmoid fused into staging).
__global__ __launch_bounds__(256) void k_topk1(const float* __restrict__ raw,
                                               const float* __restrict__ scal,
                                               const float* __restrict__ ab,
                                               float* __restrict__ cv,
                                               int* __restrict__ cidx) {
  const int ch = blockIdx.x, b = blockIdx.y;
  const float sc = scal[b], bb_ = ab[0];
  const float* a = raw + (size_t)b*TSAMP + ch*2048;
  __shared__ float v[2048];
  __shared__ float rv[4]; __shared__ int ri[4];
  const int tid = threadIdx.x;
  for (int i = tid; i < 2048; i += 256)
    v[i] = 1.f/(1.f+expf(-(a[i]*sc + bb_)));
  __syncthreads();
  for (int e = 0; e < NEV; ++e) {
    float bv = -1e30f; int bi = 0;
    for (int i = tid; i < 2048; i += 256) {
      const float x = v[i];
      if (x > bv) { bv = x; bi = i; }
    }
    for (int s = 32; s; s >>= 1) {
      const float ov = __shfl_down(bv, s); const int oi = __shfl_down(bi, s);
      if (ov > bv || (ov == bv && oi < bi)) { bv = ov; bi = oi; }
    }
    if ((tid & 63) == 0) { rv[tid >> 6] = bv; ri[tid >> 6] = bi; }
    __syncthreads();
    if (tid == 0) {
      int bb = 0;
      for (int w2 = 1; w2 < 4; ++w2)
        if (rv[w2] > rv[bb] || (rv[w2] == rv[bb] && ri[w2] < ri[bb])) bb = w2;
      cv[(b*16 + ch)*NEV + e] = rv[bb];
      cidx[(b*16 + ch)*NEV + e] = ch*2048 + ri[bb];
      v[ri[bb]] = -1e30f;
    }
    __syncthreads();
  }
}

// K7b: final top-32 over 512 candidates
__global__ __launch_bounds__(512) void k_topk2(const float* __restrict__ cv,
                                               const int* __restrict__ ci_,
                                               float* __restrict__ vals,
                                               int* __restrict__ idxs) {
  const int b = blockIdx.x;
  const int tid = threadIdx.x;
  float my = cv[b*512 + tid];
  int   mi = ci_[b*512 + tid];
  __shared__ float rv[8]; __shared__ int ri[8];
  __shared__ float bvs; __shared__ int bis;
  for (int e = 0; e < NEV; ++e) {
    float bv = my; int bi = mi;
    for (int s = 32; s; s >>= 1) {
      const float ov = __shfl_down(bv, s); const int oi = __shfl_down(bi, s);
      if (ov > bv || (ov == bv && oi < bi)) { bv = ov; bi = oi; }
    }
    if ((tid & 63) == 0) { rv[tid >> 6] = bv; ri[tid >> 6] = bi; }
    __syncthreads();
    if (tid == 0) {
      int bb = 0;
      for (int w2 = 1; w2 < 8; ++w2)
        if (rv[w2] > rv[bb] || (rv[w2] == rv[bb] && ri[w2] < ri[bb])) bb = w2;
      vals[b*NEV + e] = rv[bb]; idxs[b*NEV + e] = ri[bb];
      bvs = rv[bb]; bis = ri[bb];
    }
    __syncthreads();
    if (mi == bis && my == bvs) my = -1e30f;
    __syncthreads();
  }
}

// ------------------------------------------------------------------
__device__ __forceinline__ float blk_max128(float v, float* red) {
  const int tid = threadIdx.x;
  red[tid] = v; __syncthreads();
  for (int s = 64; s > 0; s >>= 1) {
    if (tid < s) red[tid] = fmaxf(red[tid], red[tid + s]);
    __syncthreads();
  }
  const float r = red[0]; __syncthreads();
  return r;
}
__device__ __forceinline__ float blk_sum128(float v, float* red) {
  const int tid = threadIdx.x;
  red[tid] = v; __syncthreads();
  for (int s = 64; s > 0; s >>= 1) {
    if (tid < s) red[tid] += red[tid + s];
    __syncthreads();
  }
  const float r = red[0]; __syncthreads();
  return r;
}
__device__ __forceinline__ float mlp_hidden3(float latv, const float* __restrict__ hw,
                                             const float* __restrict__ hb, float* xa) {
  const int tid = threadIdx.x;
  float cur = latv;
  for (int i = 0; i < 3; ++i) {
    xa[tid] = cur; __syncthreads();
    const float* W = hw + (size_t)i*CCH*CCH;
    float acc = hb[i*CCH + tid];
    for (int c = 0; c < CCH; ++c) acc += xa[c] * W[c*CCH + tid];
    cur = acc > 0.f ? acc : 0.2f*acc;
    __syncthreads();
  }
  return cur;
}

// K8: lat + all three MLPs + softmaxes + amps. One 128-thread block per event.
__global__ __launch_bounds__(128) void k_mlp(
    const float* __restrict__ h, const float* __restrict__ scal,
    const float* __restrict__ vals, const int* __restrict__ idxs,
    const float* __restrict__ a_hw, const float* __restrict__ a_hb,
    const float* __restrict__ a_ow, const float* __restrict__ a_ob,
    const float* __restrict__ t_hw, const float* __restrict__ t_hb,
    const float* __restrict__ t_ow, const float* __restrict__ t_ob,
    const float* __restrict__ m_hw, const float* __restrict__ m_hb,
    const float* __restrict__ m_ow, const float* __restrict__ m_ob,
    float* __restrict__ p_atoms, float* __restrict__ p_trans, float* __restrict__ amps) {
  const int row = blockIdx.x;
  const int b = row >> 5;
  const int tid = threadIdx.x;
  __shared__ float xa[CCH];
  __shared__ float red[CCH];
  const int t = idxs[row];
  const float latv = h[((size_t)b*TSAMP + t)*CCH + tid] * scal[b] * vals[row];

  {
    const float cur = mlp_hidden3(latv, a_hw, a_hb, xa);
    xa[tid] = cur; __syncthreads();
    float l0 = a_ob[tid], l1 = a_ob[tid+128], l2 = a_ob[tid+256], l3 = a_ob[tid+384];
    for (int c = 0; c < CCH; ++c) {
      const float xv = xa[c];
      const float* W = a_ow + (size_t)c*NATOMS + tid;
      l0 += xv*W[0]; l1 += xv*W[128]; l2 += xv*W[256]; l3 += xv*W[384];
    }
    const float mx = blk_max128(fmaxf(fmaxf(l0,l1), fmaxf(l2,l3)), red);
    const float e0 = expf(l0-mx), e1 = expf(l1-mx), e2 = expf(l2-mx), e3 = expf(l3-mx);
    const float inv = 1.f / blk_sum128(e0+e1+e2+e3, red);
    float* pa = p_atoms + (size_t)row*NATOMS;
    pa[tid] = e0*inv; pa[tid+128] = e1*inv; pa[tid+256] = e2*inv; pa[tid+384] = e3*inv;
  }
  {
    const float cur = mlp_hidden3(latv, t_hw, t_hb, xa);
    xa[tid] = cur; __syncthreads();
    float lg = -3.4e38f;
    if (tid < NTRANS) {
      float acc = t_ob[tid];
      for (int c = 0; c < CCH; ++c) acc += xa[c]*t_ow[c*NTRANS + tid];
      lg = acc;
    }
    const float mt = blk_max128(lg, red);
    const float et = (tid < NTRANS) ? expf(lg - mt) : 0.f;
    const float st = blk_sum128(et, red);
    if (tid < NTRANS) p_trans[(size_t)row*NTRANS + tid] = et/st;
  }
  {
    const float cur = mlp_hidden3(latv, m_hw, m_hb, xa);
    const float s = blk_sum128(cur * m_ow[tid], red);
    if (tid == 0) { const float v = s + m_ob[0]; amps[row] = v*v; }
  }
}

// K9: atoms_vec[row,:] = p_atoms[row] @ atoms_dict (512x512)
__global__ __launch_bounds__(256) void k_atoms_mm(const float* __restrict__ p_atoms,
                                                  const float* __restrict__ dict,
                                                  float* __restrict__ av) {
  const int row = blockIdx.x;
  __shared__ float p[NATOMS];
  for (int i = threadIdx.x; i < NATOMS; i += 256) p[i] = p_atoms[(size_t)row*NATOMS + i];
  __syncthreads();
  const int s0 = threadIdx.x*2;
  float a0=0, a1=0;
  for (int a = 0; a < NATOMS; ++a) {
    const float pa = p[a];
    const float2 dv = *(const float2*)(dict + (size_t)a*ASIZE + s0);
    a0 += pa*dv.x; a1 += pa*dv.y;
  }
  av[(size_t)row*ASIZE + s0] = a0; av[(size_t)row*ASIZE + s0 + 1] = a1;
}

// K10: transfers[row,:] = p_trans[row] @ transfer_dict (64x8192)
__global__ __launch_bounds__(256) void k_trans_mm(const float* __restrict__ p_trans,
                                                   const float* __restrict__ td,
                                                   float* __restrict__ trans) {
  const int row = blockIdx.y;
  const int t = blockIdx.x*2048 + threadIdx.x*8;
  __shared__ float p[NTRANS];
  if (threadIdx.x < NTRANS) p[threadIdx.x] = p_trans[(size_t)row*NTRANS + threadIdx.x];
  __syncthreads();
  float a0=0,a1=0,a2=0,a3=0,a4=0,a5=0,a6=0,a7=0;
  for (int j = 0; j < NTRANS; ++j) {
    const float pj = p[j];
    const float4 v0 = *(const float4*)(td + (size_t)j*TSIZE + t);
    const float4 v1 = *(const float4*)(td + (size_t)j*TSIZE + t + 4);
    a0 += pj*v0.x; a1 += pj*v0.y; a2 += pj*v0.z; a3 += pj*v0.w;
    a4 += pj*v1.x; a5 += pj*v1.y; a6 += pj*v1.z; a7 += pj*v1.w;
  }
  float* o = trans + (size_t)row*TSIZE + t;
  o[0]=a0; o[1]=a1; o[2]=a2; o[3]=a3; o[4]=a4; o[5]=a5; o[6]=a6; o[7]=a7;
}

// K11: ev conv; rolling window with EPAD skew
__global__ __launch_bounds__(256) void k_ev(const float* __restrict__ trans,
                                            const float* __restrict__ av,
                                            const float* __restrict__ amps,
                                            float* __restrict__ ev) {
  const int row = blockIdx.y;
  const int t0 = blockIdx.x * 1024;
  __shared__ float al[512];
  __shared__ float tw[1584];
  for (int i = threadIdx.x; i < 512; i += 256) al[i] = av[(size_t)row*ASIZE + i];
  for (int i = threadIdx.x; i < 1536; i += 256) {
    const int g = t0 - 512 + i;
    tw[EPAD(i)] = (g >= 0) ? trans[(size_t)row*TSIZE + g] : 0.f;
  }
  __syncthreads();
  const int base = threadIdx.x*4 + 512;
  float a0=0,a1=0,a2=0,a3=0;
  float w0=tw[EPAD(base)], w1=tw[EPAD(base+1)], w2=tw[EPAD(base+2)], w3=tw[EPAD(base+3)];
#pragma unroll 8
  for (int k = 0; k < 512; ++k) {
    const float ak = al[k];
    a0 += ak*w0; a1 += ak*w1; a2 += ak*w2; a3 += ak*w3;
    w3 = w2; w2 = w1; w1 = w0;
    const int p = base - k - 1;
    w0 = tw[EPAD(p)];
  }
  const int n = t0 + threadIdx.x*4;
  const float amp = amps[row];
  float* e = ev + (size_t)row*TSIZE + n;
  e[0] = (a0 + (n+0 < 512 ? al[n+0] : 0.f)) * amp;
  e[1] = (a1 + (n+1 < 512 ? al[n+1] : 0.f)) * amp;
  e[2] = (a2 + (n+2 < 512 ? al[n+2] : 0.f)) * amp;
  e[3] = (a3 + (n+3 < 512 ? al[n+3] : 0.f)) * amp;
}

// K12: overlap-add gather, atomics-free: each block owns a 256-t strip over
// ALL 256 rows; writes dry and the reversed-scaled f16 drev directly.
__global__ __launch_bounds__(256) void k_dry(const float* __restrict__ ev,
                                             const int* __restrict__ idxs,
                                             float* __restrict__ dry,
                                             _Float16* __restrict__ drev) {
  __shared__ int sidx[NROWS];
  if (threadIdx.x < NROWS) sidx[threadIdx.x] = idxs[threadIdx.x];
  __syncthreads();
  const int p = blockIdx.x*256 + threadIdx.x;
  float a = 0.f;
  for (int r = 0; r < NROWS; ++r) {
    const int off = p - sidx[r];
    if ((unsigned)off < TSIZE) a += ev[(size_t)r*TSIZE + off];
  }
  dry[p] = a;
  drev[TSAMP - 1 - p] = (_Float16)(a * DRY_SCALE);
}

// K14: impulse[b,t] -> f16 hi only, ×2^6
__global__ __launch_bounds__(256) void k_impulse(const float* __restrict__ roomp,
                                                 const float* __restrict__ rooms,
                                                 _Float16* __restrict__ ihi) {
  const int b = blockIdx.y;
  const int t = blockIdx.x*1024 + threadIdx.x*4;
  float a0=0,a1=0,a2=0,a3=0;
  for (int r = 0; r < 8; ++r) {
    const float pr = roomp[b*8 + r];
    const float4 v = *(const float4*)(rooms + (size_t)r*TSAMP + t);
    a0 += pr*v.x; a1 += pr*v.y; a2 += pr*v.z; a3 += pr*v.w;
  }
  _Float16* oh = ihi + (size_t)b*TSAMP + t;
  oh[0] = (_Float16)(a0*IMP_SCALE); oh[1] = (_Float16)(a1*IMP_SCALE);
  oh[2] = (_Float16)(a2*IMP_SCALE); oh[3] = (_Float16)(a3*IMP_SCALE);
}

// K15: reverb conv via f16 MFMA (hi-only), N=512/block, k-slab 4096.
__global__ __launch_bounds__(256) void k_wet_mfma(
    const _Float16* __restrict__ drev, const _Float16* __restrict__ ihi,
    float* __restrict__ wet) {
  const int t0 = blockIdx.x * 512;
  const int k0 = blockIdx.y * 4096;
  if (k0 > t0 + 511) return;
  __shared__ _Float16 rhi[8*1048];
  const int tid = threadIdx.x;
  const int wv = tid >> 6;
  const int lane = tid & 63;
  const int n16 = lane & 15;
  const int quad = lane >> 4;
  const int m = n16;

  f32x4 acc[8];
#pragma unroll
  for (int j = 0; j < 8; ++j) acc[j] = (f32x4){0.f,0.f,0.f,0.f};

  const int kend = (k0 + 4096 < t0 + 512) ? k0 + 4096 : t0 + 512;
  const int ph = 7 - (n16 & 7);
  for (int kc0 = k0; kc0 < kend; kc0 += 512) {
    const int RB = TSAMP - 1 - (t0 + 511 - kc0);
    for (int flat = tid; flat < 8*1016; flat += 256) {
      const int p = flat / 1016;
      const int q = flat - p*1016;
      rhi[p*1048 + q] = drev[RB + p + q];
    }
    __syncthreads();

#pragma unroll 4
    for (int kc = 0; kc < 16; ++kc) {
      const int kb = kc*32;
      const int jg = kc0 + kb + quad*8;
      f16x8 ah;
      if (m < NBATCH) ah = *(const f16x8*)(ihi + (size_t)m*TSAMP + jg);
      else ah = (f16x8){0,0,0,0,0,0,0,0};
#pragma unroll
      for (int ts = 0; ts < 8; ++ts) {
        const int nn = wv*128 + ts*16 + n16;
        const int a = ph*1048 + kb + quad*8 + 504 - (nn & ~7);
        const f16x8 bh = *(const f16x8*)(rhi + a);
        acc[ts] = __builtin_amdgcn_mfma_f32_16x16x32_f16(ah, bh, acc[ts], 0, 0, 0);
      }
    }
    __syncthreads();
  }

#pragma unroll
  for (int ts = 0; ts < 8; ++ts) {
    const int t = t0 + wv*128 + ts*16 + n16;
#pragma unroll
    for (int r = 0; r < 4; ++r) {
      const int b = quad*4 + r;
      if (b < NBATCH)
        atomicAdd(wet + (size_t)b*TSAMP + t, acc[ts][r] * WET_DESCALE);
    }
  }
}

// K16: out = dry*(1-mix) + wet*mix
__global__ __launch_bounds__(256) void k_out(const float* __restrict__ dry,
                                             const float* __restrict__ wet,
                                             const float* __restrict__ mix,
                                             float* __restrict__ out) {
  const int b = blockIdx.y;
  const int t = blockIdx.x*1024 + threadIdx.x*4;
  const float m = mix[b];
  const float4 d = *(const float4*)(dry + t);
  const float4 w = *(const float4*)(wet + (size_t)b*TSAMP + t);
  float* o = out + (size_t)b*TSAMP + t;
  o[0] = d.x*(1.f-m) + w.x*m;
  o[1] = d.y*(1.f-m) + w.y*m;
  o[2] = d.z*(1.f-m) + w.z*m;
  o[3] = d.w*(1.f-m) + w.w*m;
}

// ------------------------------------------------------------------
extern "C" void kernel_launch(void* const* d_in, const int* in_sizes, int n_in,
                              void* d_out, int out_size, void* d_ws, size_t ws_size,
                              hipStream_t stream) {
  (void)in_sizes; (void)n_in; (void)out_size;
  const float* x      = (const float*)d_in[0];
  const float* bank   = (const float*)d_in[1];
  const float* w_net  = (const float*)d_in[2];
  const float* b_net  = (const float*)d_in[3];
  const float* attn_w = (const float*)d_in[4];
  const float* attn_b = (const float*)d_in[5];
  const float* a_hw = (const float*)d_in[6];
  const float* a_hb = (const float*)d_in[7];
  const float* a_ow = (const float*)d_in[8];
  const float* a_ob = (const float*)d_in[9];
  const float* t_hw = (const float*)d_in[10];
  const float* t_hb = (const float*)d_in[11];
  const float* t_ow = (const float*)d_in[12];
  const float* t_ob = (const float*)d_in[13];
  const float* m_hw = (const float*)d_in[14];
  const float* m_hb = (const float*)d_in[15];
  const float* m_ow = (const float*)d_in[16];
  const float* m_ob = (const float*)d_in[17];
  const float* atoms_dict    = (const float*)d_in[18];
  const float* transfer_dict = (const float*)d_in[19];
  const float* rooms  = (const float*)d_in[20];
  const float* room_w = (const float*)d_in[21];
  const float* room_b = (const float*)d_in[22];
  const float* mix_w  = (const float*)d_in[23];
  const float* mix_b  = (const float*)d_in[24];
  float* out = (float*)d_out;

  // ---- workspace: H | t1 | t2 | weights | stats.  Two layouts:
  //  NB=4 (271.8 MB needed): t1/t2 hold 4 batches each.
  //  NB=2 (204 MB): current layout.  Selected by ws_size (constant per session).
  float* ws = (float*)d_ws;
  const size_t need4 = (size_t)67944480 * 4;   // bytes
  const int NB = (ws_size >= need4) ? 4 : 2;
  const size_t S = (size_t)CCH * TSAMP;        // 4,194,304 floats per batch
  float* H  = ws;                               // [B][T][C]
  float* t1 = ws + (size_t)33554432;
  float* t2 = ws + 33554432 + NB*S;
  const size_t w_off = 33554432 + 2*(size_t)NB*S;
  _Float16* whi = (_Float16*)(ws + w_off);
  _Float16* wlo = whi + 245760;
  _Float16* bhi = wlo + 245760;
  _Float16* blo = bhi + 65536;
  double* sums  = (double*)(ws + w_off + 311296);   // 16 doubles
  float* attnraw = ws + w_off + 311296 + 32;        // 8*32768
  float* pm      = attnraw + (size_t)NBATCH*TSAMP;  // 8*256*128

  size_t off = 33554432;                       // scratch base (aliases t1)
  float* scal  = ws + off; off += 8;
  float* vals  = ws + off; off += NROWS;
  int*   idxs  = (int*)(ws + off); off += NROWS;
  float* p_atoms = ws + off; off += (size_t)NROWS*NATOMS;
  float* p_trans = ws + off; off += (size_t)NROWS*NTRANS;
  float* amps  = ws + off; off += NROWS;
  float* av    = ws + off; off += (size_t)NROWS*ASIZE;
  float* trans = ws + off; off += (size_t)NROWS*TSIZE;
  float* ev    = ws + off; off += (size_t)NROWS*TSIZE;
  float* dry   = ws + off; off += TSAMP;
  float* roomp = ws + off; off += 64;
  float* mix   = ws + off; off += 8;
  float* wet   = ws + off; off += (size_t)NBATCH*TSAMP;
  float* cand_v = ws + off; off += 4096;
  int*   cand_i = (int*)(ws + off); off += 4096;
  _Float16* imphi = (_Float16*)(ws + off); off += (size_t)NBATCH*TSAMP/2;
  _Float16* drev  = (_Float16*)(ws + off); off += (TSAMP + 1088)/2 + 4;
  // scratch ends ~38.6M floats < t2 start in both modes — disjoint.

  k_prep<<<1216, 256, 0, stream>>>(w_net, bank, whi, wlo, bhi, blo, sums);
  k_front_mfma<<<dim3(256, 8), 256, 0, stream>>>(x, bhi, blo, H);

  const int dil[5] = {1, 3, 9, 27, 1};
  const int npairs = 8 / NB;
  for (int p = 0; p < npairs; ++p) {
    float* Hp = H + (size_t)(NB*p) * S;
    float* io[6] = {Hp, t1, t2, t1, t2, Hp};
    for (int i = 0; i < 3; ++i) {          // d = 1, 3, 9: 128-t tiles
      const int d = dil[i];
      const size_t smem = (size_t)(128 + 2*d) * 544;
      k_dil128<<<dim3(256, NB), 256, smem, stream>>>(
          io[i], whi + (size_t)i*49152, wlo + (size_t)i*49152, b_net + i*CCH,
          io[i+1], d);
    }
    {                                      // d = 27: 80-t tiles
      const size_t smem = (size_t)134 * 544;
      k_dil80<<<dim3(410, NB), 256, smem, stream>>>(
          io[3], whi + (size_t)3*49152, wlo + (size_t)3*49152, b_net + 3*CCH,
          io[4]);
    }
    {                                      // last layer d=1: 128-t + stats
      const int d = dil[4];
      const size_t smem = (size_t)(128 + 2*d) * 544;
      k_dil_last<<<dim3(256, NB), 256, smem, stream>>>(
          io[4], whi + (size_t)4*49152, wlo + (size_t)4*49152, b_net + 4*CCH,
          io[5], d, attn_w, sums, attnraw, pm, NB*p);
    }
  }

  k_zero<<<1024, 256, 0, stream>>>(wet, drev);
  k_finish<<<8, 128, 0, stream>>>(sums, pm, room_w, room_b, mix_w, mix_b,
                                  scal, roomp, mix);
  k_topk1<<<dim3(16, 8), 256, 0, stream>>>(attnraw, scal, attn_b, cand_v, cand_i);
  k_topk2<<<8, 512, 0, stream>>>(cand_v, cand_i, vals, idxs);
  k_mlp<<<256, 128, 0, stream>>>(H, scal, vals, idxs,
                                 a_hw, a_hb, a_ow, a_ob,
                                 t_hw, t_hb, t_ow, t_ob,
                                 m_hw, m_hb, m_ow, m_ob,
                                 p_atoms, p_trans, amps);
  k_atoms_mm<<<256, 256, 0, stream>>>(p_atoms, atoms_dict, av);
  k_trans_mm<<<dim3(4, 256), 256, 0, stream>>>(p_trans, transfer_dict, trans);
  k_ev<<<dim3(8, 256), 256, 0, stream>>>(trans, av, amps, ev);
  k_dry<<<128, 256, 0, stream>>>(ev, idxs, dry, drev);
  k_impulse<<<dim3(32, 8), 256, 0, stream>>>(roomp, rooms, imphi);
  k_wet_mfma<<<dim3(64, 8), 256, 0, stream>>>(drev, imphi, wet);
  k_out<<<dim3(32, 8), 256, 0, stream>>>(dry, wet, mix, out);
}